// Round 11
// baseline (968.715 us; speedup 1.0000x reference)
//
#include <hip/hip_runtime.h>

#define NBATCH 16
#define NN 128
#define NH 128
#define NL 127
#define NDX 11
#define NDE 4
#define LDA 132
#define LDB 129
#define LDT 132
#define WS_STRIDE 66560  // floats per batch in wsG

// per-batch workspace float offsets
#define OFF_AREF 0
#define OFF_Q0   16384
#define OFF_Q1   32768
#define OFF_S    49152
#define OFF_DV   65536
#define OFF_EV   65664
#define OFF_TAU  65792
#define OFF_ORG  65920
#define OFF_META 66048   // 512 floats of int metadata

// ---------------- LAPACK fp32 helper ports ----------------
#define EPS32 5.9604645e-8f
#define EPS232 3.5527137e-15f
#define SAFMIN32 1.17549435e-38f

__device__ __forceinline__ float ssign_(float a, float b) {
  return (b >= 0.0f) ? fabsf(a) : -fabsf(a);
}
__device__ __forceinline__ float slapy2_(float x, float y) {
  float ax = fabsf(x), ay = fabsf(y);
  float w = fmaxf(ax, ay), z = fminf(ax, ay);
  if (z == 0.0f) return w;
  float q = z / w;
  return w * sqrtf(1.0f + q * q);
}

// broadcast-read lane `src`'s value of v (uniform src -> v_readlane, scalar pipe)
__device__ __forceinline__ float rdl(float v, int src) {
  return __int_as_float(__builtin_amdgcn_readlane(__float_as_int(v), src));
}

__device__ void slartg_(float f, float g, float* c, float* s, float* r) {
  if (g == 0.0f) { *c = 1.0f; *s = 0.0f; *r = f; }
  else if (f == 0.0f) { *c = 0.0f; *s = (g >= 0.0f) ? 1.0f : -1.0f; *r = fabsf(g); }
  else {
    float d = sqrtf(f * f + g * g);
    d = (f >= 0.0f) ? d : -d;
    *c = f / d; *s = g / d; *r = d;
  }
}

__device__ void slaev2_(float a, float b, float c0, float* rt1, float* rt2,
                        float* cs1, float* sn1) {
  float sm = a + c0, df = a - c0, adf = fabsf(df), tb = b + b, ab = fabsf(tb);
  float acmx, acmn;
  if (fabsf(a) > fabsf(c0)) { acmx = a; acmn = c0; } else { acmx = c0; acmn = a; }
  float rt;
  if (adf > ab) { float q = ab / adf; rt = adf * sqrtf(1.0f + q * q); }
  else if (adf < ab) { float q = adf / ab; rt = ab * sqrtf(1.0f + q * q); }
  else rt = ab * sqrtf(2.0f);
  int sgn1;
  if (sm < 0.0f) { *rt1 = 0.5f * (sm - rt); sgn1 = -1; *rt2 = (acmx / *rt1) * acmn - (b / *rt1) * b; }
  else if (sm > 0.0f) { *rt1 = 0.5f * (sm + rt); sgn1 = 1; *rt2 = (acmx / *rt1) * acmn - (b / *rt1) * b; }
  else { *rt1 = 0.5f * rt; *rt2 = -0.5f * rt; sgn1 = 1; }
  int sgn2; float cs;
  if (df >= 0.0f) { cs = df + rt; sgn2 = 1; } else { cs = df - rt; sgn2 = -1; }
  float acs = fabsf(cs);
  if (acs > ab) { float ct = -tb / cs; *sn1 = 1.0f / sqrtf(1.0f + ct * ct); *cs1 = ct * (*sn1); }
  else {
    if (ab == 0.0f) { *cs1 = 1.0f; *sn1 = 0.0f; }
    else { float tn = -cs / tb; *cs1 = 1.0f / sqrtf(1.0f + tn * tn); *sn1 = tn * (*cs1); }
  }
  if (sgn1 == sgn2) { float tn = *cs1; *cs1 = -(*sn1); *sn1 = tn; }
}

// ============ K1: Laplacian build + ssytd2 tridiagonalization ============
// v8: 1024 threads (R9's 4-waves/SIMD latency hiding) + R10's cheap shfl
// readbacks (xp[lane&31]+5 shfl; red_[lane&15]+4 shfl). R9 barrier schedule
// (4/iter) and LDA=132 layout, both harness-verified.
__global__ __launch_bounds__(1024) void k_tridiag(const float* __restrict__ A_in,
                                                  float* __restrict__ wsG) {
  const int b = blockIdx.x, t = threadIdx.x;
  float* Aref = wsG + (size_t)b * WS_STRIDE;
  float* dv = Aref + OFF_DV;
  float* ev = Aref + OFF_EV;
  float* tg = Aref + OFF_TAU;
  float* og = Aref + OFF_ORG;
  extern __shared__ float As[];  // [128][LDA], LDA=132
  __shared__ unsigned int maskp[128][8];
  __shared__ unsigned int Dp[128][8];
  __shared__ unsigned long long adj0_[128], adj1_[128];
  __shared__ float Dd_[128], tDs_[128];
  __shared__ float d_[128], e_[128], tau_[128];
  __shared__ alignas(16) float v_[128];
  __shared__ alignas(16) float w_[128];
  __shared__ float pmat[8][128];
  __shared__ alignas(16) float red_[16];
  __shared__ float xp[32];

  const int wid = t >> 6;        // wave id 0..15
  const int lane = t & 63;
  // ---- adjacency build: 8 threads per row, 16 m's each ----
  {
    const int r8 = t >> 3, s8 = t & 7;
    const float4* Arow = (const float4*)(A_in + (size_t)(b * 128 + r8) * 128 * 4);
    unsigned int mloc = 0; unsigned int cnt = 0;
    const int m0 = s8 * 16;
    #pragma unroll 4
    for (int mm = 0; mm < 16; ++mm) {
      float4 a = Arow[m0 + mm];
      if (a.x != 0.f || a.y != 0.f || a.z != 0.f || a.w != 0.f) { mloc |= 1u << mm; cnt++; }
    }
    maskp[r8][s8] = mloc; Dp[r8][s8] = cnt;
  }
  __syncthreads();
  if (t < 128) {
    unsigned long long b0 = 0ull, b1 = 0ull; unsigned int D = 0;
    #pragma unroll
    for (int s = 0; s < 4; ++s) { b0 |= (unsigned long long)maskp[t][s] << (16 * s); D += Dp[t][s]; }
    #pragma unroll
    for (int s = 0; s < 4; ++s) { b1 |= (unsigned long long)maskp[t][s + 4] << (16 * s); D += Dp[t][s + 4]; }
    adj0_[t] = b0; adj1_[t] = b1;
    float Df = (float)D;
    Dd_[t] = Df;
    tDs_[t] = 1.0f / sqrtf(fmaxf(Df, 1.0f));
  }
  __syncthreads();
  for (int idx = t; idx < 16384; idx += 1024) {
    int r = idx >> 7, c = idx & 127;
    if (c <= r) {
      float adj = (float)((c < 64 ? (adj0_[r] >> c) : (adj1_[r] >> (c - 64))) & 1ull);
      float Lrc = ((c == r) ? Dd_[r] : 0.0f) - adj;
      float val = (tDs_[c] * Lrc) * tDs_[r];
      As[r * LDA + c] = val;
      As[c * LDA + r] = val;
    }
  }
  __syncthreads();

  const int rmv = t & 127;   // matvec row
  const int smv = t >> 7;    // matvec segment 0..7 (16 cols each)
  const int ucg = t & 31;    // update col-group (4 cols)
  const int urs = t >> 5;    // update row stripe 0..31

  bool usexp = false;
  for (int i = 0; i < 127; ++i) {
    const int lo = i + 1;
    // ---- xnorm2 of column i below subdiagonal ----
    float xnorm2;
    if (!usexp) {           // uniform fallback path (iter 0 / after taui==0)
      float part = 0.0f;
      if (t < 128 && t >= i + 2) { float x = As[t * LDA + i]; part = x * x; }
      if (wid < 2) {
        #pragma unroll
        for (int m = 1; m < 64; m <<= 1) part += __shfl_xor(part, m);
        if (lane == 0) red_[wid] = part;
      }
      __syncthreads();   // S1 (fallback only)
      xnorm2 = red_[0] + red_[1];
    } else {               // piggybacked: 1 LDS read + shfl tree (sum of 32)
      float s = xp[lane & 31];
      #pragma unroll
      for (int m = 1; m < 32; m <<= 1) s += __shfl_xor(s, m);
      xnorm2 = s;
    }
    float alpha = As[lo * LDA + i];   // row lo never written in phase B
    float beta, taui, scal;
    if (xnorm2 == 0.0f) { taui = 0.0f; beta = alpha; scal = 0.0f; }
    else {
      float xn = sqrtf(xnorm2);
      beta = -ssign_(slapy2_(alpha, xn), alpha);
      taui = (beta - alpha) / beta;
      scal = 1.0f / (alpha - beta);
    }
    if (t == 0) { e_[i] = beta; tau_[i] = taui; }
    if (taui != 0.0f) {    // uniform branch
      // ---- phase B: single-writer v construction ----
      if (t < 128) {
        float vv = 0.0f;
        if (t == lo) vv = 1.0f;
        else if (t > lo) { float xi = As[t * LDA + i]; vv = xi * scal; As[t * LDA + i] = vv; }
        v_[t] = vv;
      }
      __syncthreads();   // S2
      // ---- phase C: matvec partials (16-col chunk) + vpdot partial ----
      const int c0 = smv * 16;
      float acc = 0.0f;
      if (c0 + 15 >= lo && rmv >= lo) {
        const float4* Ar = (const float4*)&As[rmv * LDA + c0];
        const float4* Vr = (const float4*)&v_[c0];
        #pragma unroll
        for (int k = 0; k < 4; ++k) {
          float4 a = Ar[k], v4 = Vr[k];
          acc += a.x * v4.x + a.y * v4.y + a.z * v4.z + a.w * v4.w;
        }
      }
      pmat[smv][rmv] = acc;
      float p2 = v_[rmv] * acc;
      #pragma unroll
      for (int m = 1; m < 64; m <<= 1) p2 += __shfl_xor(p2, m);
      if (lane == 0) red_[wid] = p2;
      __syncthreads();   // S3
      // ---- phase D: w = taui*(Av); a2 via shfl-sum of red_[0..15] ----
      float vpr = red_[lane & 15];
      #pragma unroll
      for (int m = 1; m < 16; m <<= 1) vpr += __shfl_xor(vpr, m);
      float a2 = -0.5f * taui * (taui * vpr);
      if (t < 128) {
        float pv = 0.0f;
        #pragma unroll
        for (int s = 0; s < 8; ++s) pv += pmat[s][t];
        w_[t] = taui * pv;
      }
      __syncthreads();   // S4
      // ---- phase E: rank-2 update + next-xnorm piggyback ----
      const int uc0 = ucg * 4;
      if (uc0 + 3 >= lo) {
        float4 vc = *(const float4*)&v_[uc0];
        float4 wc = *(const float4*)&w_[uc0];
        float pcx = wc.x + a2 * vc.x;
        float pcy = wc.y + a2 * vc.y;
        float pcz = wc.z + a2 * vc.z;
        float pcw = wc.w + a2 * vc.w;
        if (uc0 < lo) {   // partial chunk: neutralize components left of lo
          if (uc0 + 0 < lo) { vc.x = 0.f; pcx = 0.f; }
          if (uc0 + 1 < lo) { vc.y = 0.f; pcy = 0.f; }
          if (uc0 + 2 < lo) { vc.z = 0.f; pcz = 0.f; }
        }
        const bool isxcol = (ucg == (lo >> 2));
        const int xc = lo & 3;
        float xpacc = 0.0f;
        #pragma unroll
        for (int k = 0; k < 4; ++k) {
          int r = urs + 32 * k;
          if (r >= lo) {
            float vr = v_[r];
            float pr = w_[r] + a2 * vr;
            float4 a = *(const float4*)&As[r * LDA + uc0];
            a.x -= vr * pcx + pr * vc.x;
            a.y -= vr * pcy + pr * vc.y;
            a.z -= vr * pcz + pr * vc.z;
            a.w -= vr * pcw + pr * vc.w;
            *(float4*)&As[r * LDA + uc0] = a;
            if (isxcol && r >= lo + 2) {
              float nc = (xc == 0) ? a.x : ((xc == 1) ? a.y : ((xc == 2) ? a.z : a.w));
              xpacc += nc * nc;
            }
          }
        }
        if (isxcol) xp[urs] = xpacc;
      }
    }
    __syncthreads();   // S5
    usexp = (taui != 0.0f);
  }
  if (t < 128) d_[t] = As[t * LDA + t];
  __syncthreads();

  {
    float mx = 0.0f;
    if (t < 128) mx = fabsf(d_[t]);
    if (t < 127) mx = fmaxf(mx, fabsf(e_[t]));
    if (wid < 2) {
      #pragma unroll
      for (int m = 1; m < 64; m <<= 1) mx = fmaxf(mx, __shfl_xor(mx, m));
      if (lane == 0) red_[wid] = mx;
    }
    __syncthreads();
  }
  float orgnrm = fmaxf(red_[0], red_[1]);
  if (orgnrm == 0.0f) orgnrm = 1.0f;
  float invnrm = 1.0f / orgnrm;
  if (t < 128) d_[t] *= invnrm;
  if (t < 127) e_[t] *= invnrm;
  __syncthreads();
  if (t == 0) {
    for (int bm = 16; bm < 128; bm += 16) {
      float ae = fabsf(e_[bm - 1]);
      d_[bm - 1] -= ae; d_[bm] -= ae;
    }
  }
  __syncthreads();
  for (int idx = t; idx < 16384; idx += 1024)
    Aref[idx] = As[(idx >> 7) * LDA + (idx & 127)];
  if (t < 128) { dv[t] = d_[t]; tg[t] = tau_[t]; }
  if (t < 127) ev[t] = e_[t];
  if (t == 0) og[0] = orgnrm;
}

// ============ K2: 8 leaves x 16 batches, one block each ============
// v3: lane-register ssteqr (readlane broadcasts); band-limited Q0 write.
__global__ __launch_bounds__(64) void k_leaves(float* __restrict__ wsG) {
  int b = blockIdx.x >> 3, lf = blockIdx.x & 7;
  float* base = wsG + (size_t)b * WS_STRIDE;
  float* Qg = base + OFF_Q0;
  float* dv = base + OFF_DV;
  float* ev = base + OFF_EV;
  const int ln = threadIdx.x;
  __shared__ float zsh[16 * 17];

  const int n = 16;
  float dreg = (ln < 16) ? dv[lf * 16 + ln] : 0.f;
  float ereg = (ln < 15) ? ev[lf * 16 + ln] : 0.f;
  float csreg = 0.f, snreg = 0.f;
  float zr[16];
  #pragma unroll
  for (int c = 0; c < 16; ++c) zr[c] = (ln == c) ? 1.0f : 0.0f;

  {
    const float eps = EPS32, eps2 = EPS232, safmin = SAFMIN32;
    int nmaxit = n * 30, jtot = 0;
    int l1 = 0;
    while (l1 <= n - 1) {
      if (l1 > 0 && ln == l1 - 1) ereg = 0.0f;
      int m;
      for (m = l1; m <= n - 2; ++m) {
        float tst = fabsf(rdl(ereg, m));
        if (tst == 0.0f) break;
        if (tst <= (sqrtf(fabsf(rdl(dreg, m))) * sqrtf(fabsf(rdl(dreg, m + 1)))) * eps) {
          if (ln == m) ereg = 0.0f;
          break;
        }
      }
      int l = l1, lend = m;
      l1 = m + 1;
      if (lend == l) continue;
      {
        float an = 0.0f;
        for (int i = l; i <= lend; ++i) an = fmaxf(an, fabsf(rdl(dreg, i)));
        for (int i = l; i <= lend - 1; ++i) an = fmaxf(an, fabsf(rdl(ereg, i)));
        if (an == 0.0f) continue;
      }
      if (fabsf(rdl(dreg, lend)) < fabsf(rdl(dreg, l))) { int tsw = l; l = lend; lend = tsw; }
      if (lend > l) {
        while (true) {  // QL
          int m2;
          if (l != lend) {
            for (m2 = l; m2 <= lend - 1; ++m2) {
              float em = rdl(ereg, m2);
              float tst = em * em;
              if (tst <= (eps2 * fabsf(rdl(dreg, m2))) * fabsf(rdl(dreg, m2 + 1)) + safmin) break;
            }
          } else m2 = lend;
          if (m2 < lend && ln == m2) ereg = 0.0f;
          float p = rdl(dreg, l);
          if (m2 == l) { l++; if (l <= lend) continue; else break; }
          if (m2 == l + 1) {
            float rt1, rt2, c, s;
            slaev2_(rdl(dreg, l), rdl(ereg, l), rdl(dreg, l + 1), &rt1, &rt2, &c, &s);
            #pragma unroll
            for (int j = 0; j < 15; ++j) {
              if (j == l) {
                float t1 = zr[j + 1];
                zr[j + 1] = c * t1 - s * zr[j];
                zr[j] = s * t1 + c * zr[j];
              }
            }
            if (ln == l) { dreg = rt1; ereg = 0.0f; }
            if (ln == l + 1) dreg = rt2;
            l += 2; if (l <= lend) continue; else break;
          }
          if (jtot == nmaxit) break;
          jtot++;
          float g = (rdl(dreg, l + 1) - p) / (2.0f * rdl(ereg, l));
          float r = slapy2_(g, 1.0f);
          g = rdl(dreg, m2) - p + rdl(ereg, l) / (g + ssign_(r, g));
          float s = 1.0f, c = 1.0f; p = 0.0f;
          for (int i = m2 - 1; i >= l; --i) {
            float ei = rdl(ereg, i);
            float f = s * ei, bb = c * ei;
            slartg_(g, f, &c, &s, &r);
            if (i != m2 - 1 && ln == i + 1) ereg = r;
            g = rdl(dreg, i + 1) - p;
            r = (rdl(dreg, i) - g) * s + 2.0f * c * bb;
            p = s * r;
            if (ln == i + 1) dreg = g + p;
            g = c * r - bb;
            if (ln == i) { csreg = c; snreg = -s; }
          }
          #pragma unroll
          for (int j = 14; j >= 0; --j) {
            if (j <= m2 - 1 && j >= l) {
              float cj = rdl(csreg, j), sj = rdl(snreg, j);
              float t1 = zr[j + 1];
              zr[j + 1] = cj * t1 - sj * zr[j];
              zr[j] = sj * t1 + cj * zr[j];
            }
          }
          if (ln == l) { dreg = dreg - p; ereg = g; }
        }
      } else {
        while (true) {  // QR
          int m2;
          if (l != lend) {
            for (m2 = l; m2 >= lend + 1; --m2) {
              float em = rdl(ereg, m2 - 1);
              float tst = em * em;
              if (tst <= (eps2 * fabsf(rdl(dreg, m2))) * fabsf(rdl(dreg, m2 - 1)) + safmin) break;
            }
          } else m2 = lend;
          if (m2 > lend && ln == m2 - 1) ereg = 0.0f;
          float p = rdl(dreg, l);
          if (m2 == l) { l--; if (l >= lend) continue; else break; }
          if (m2 == l - 1) {
            float rt1, rt2, c, s;
            slaev2_(rdl(dreg, l - 1), rdl(ereg, l - 1), rdl(dreg, l), &rt1, &rt2, &c, &s);
            #pragma unroll
            for (int j = 0; j < 15; ++j) {
              if (j == l - 1) {
                float t1 = zr[j + 1];
                zr[j + 1] = c * t1 - s * zr[j];
                zr[j] = s * t1 + c * zr[j];
              }
            }
            if (ln == l - 1) { dreg = rt1; ereg = 0.0f; }
            if (ln == l) dreg = rt2;
            l -= 2; if (l >= lend) continue; else break;
          }
          if (jtot == nmaxit) break;
          jtot++;
          float g = (rdl(dreg, l - 1) - p) / (2.0f * rdl(ereg, l - 1));
          float r = slapy2_(g, 1.0f);
          g = rdl(dreg, m2) - p + rdl(ereg, l - 1) / (g + ssign_(r, g));
          float s = 1.0f, c = 1.0f; p = 0.0f;
          for (int i = m2; i <= l - 1; ++i) {
            float ei = rdl(ereg, i);
            float f = s * ei, bb = c * ei;
            slartg_(g, f, &c, &s, &r);
            if (i != m2 && ln == i - 1) ereg = r;
            g = rdl(dreg, i) - p;
            r = (rdl(dreg, i + 1) - g) * s + 2.0f * c * bb;
            p = s * r;
            if (ln == i) dreg = g + p;
            g = c * r - bb;
            if (ln == i) { csreg = c; snreg = s; }
          }
          #pragma unroll
          for (int j = 0; j <= 14; ++j) {
            if (j >= m2 && j <= l - 1) {
              float cj = rdl(csreg, j), sj = rdl(snreg, j);
              float t1 = zr[j + 1];
              zr[j + 1] = cj * t1 - sj * zr[j];
              zr[j] = sj * t1 + cj * zr[j];
            }
          }
          if (ln == l) dreg = dreg - p;
          if (ln == l - 1) ereg = g;
        }
      }
    }
  }

  // stage z rows to LDS for sort + band write
  if (ln < 16) {
    #pragma unroll
    for (int c = 0; c < 16; ++c) zsh[ln * 17 + c] = zr[c];
  }
  __syncthreads();
  // selection sort: d in lane registers, z column swaps row-parallel in LDS
  for (int ii = 1; ii <= n - 1; ++ii) {
    int i = ii - 1, k = i;
    float p = rdl(dreg, i);
    for (int j = ii; j <= n - 1; ++j) {
      float dj = rdl(dreg, j);
      if (dj < p) { k = j; p = dj; }
    }
    if (k != i) {
      float di = rdl(dreg, i);
      if (ln == k) dreg = di;
      if (ln == i) dreg = p;
      if (ln < 16) {
        float t1 = zsh[ln * 17 + i];
        zsh[ln * 17 + i] = zsh[ln * 17 + k];
        zsh[ln * 17 + k] = t1;
      }
    }
  }
  __syncthreads();
  if (ln < 16) dv[lf * 16 + ln] = dreg;
  // write only the 32-col merge band: cols bo..bo+31 where bo=(lf>>1)*32
  {
    const int bo = (lf >> 1) * 32;
    const int cofs = (lf & 1) * 16;   // local col offset of this leaf in band
    for (int idx = ln; idx < 16 * 32; idx += 64) {
      int rr = idx >> 5, c = idx & 31;
      int cl = c - cofs;
      float v = (cl >= 0 && cl < 16) ? zsh[rr * 17 + cl] : 0.f;
      Qg[(size_t)(lf * 16 + rr) * 128 + bo + c] = v;
    }
  }
}

// ============ K3a: merge metadata/secular per (batch, merge) ============
// v3: register bisection 36 iters (48 was below fp32 noise floor already).
template <int LVL>
__global__ __launch_bounds__(1024) void k_mergeA(float* __restrict__ wsG, int qoff) {
  constexpr int sh = 2 - LVL;
  constexpr int nm = 32 << LVL;     // merged size n
  constexpr int LPR = 1024 / nm;    // lanes per root: 32/16/8
  constexpr int NCH = nm / LPR;     // chunk regs per lane: 1/4/16
  int b = blockIdx.x >> sh;
  int mg = blockIdx.x & ((1 << sh) - 1);
  int bo = mg * nm, n1 = nm >> 1, n = nm;
  const int t = threadIdx.x;
  float* base = wsG + (size_t)b * WS_STRIDE;
  float* Qin = base + qoff;
  float* dvg = base + OFF_DV;
  float* evg = base + OFF_EV;
  float* Sg  = base + OFF_S;
  int* meta = (int*)(base + OFF_META);
  int* undG = meta; int* idxpG = meta + 128; int* finG = meta + 256; int* KfG = meta + 384;

  __shared__ float d_[128], z_[128], dl_[128], w_[128], zh_[128], lam_[128], tauv_[128], dnew_[128];
  __shared__ int srt_[128], indxp_[128], und_[128], anc_[128], fin_[128];
  __shared__ int gp_[128], gq_[128];
  __shared__ float gc_[128], gs_[128];
  __shared__ int sci[4];

  if (t < n) d_[t] = dvg[bo + t];
  float rho_in = evg[bo + n1 - 1];
  if (t < n) {
    float zv = (t < n1) ? Qin[(size_t)(bo + n1 - 1) * 128 + bo + t]
                        : Qin[(size_t)(bo + n1) * 128 + bo + t];
    if (rho_in < 0.0f && t >= n1) zv = -zv;
    z_[t] = zv * 0.70710678f;
  }
  __syncthreads();
  float rho = fabsf(2.0f * rho_in);
  if (t == 0) {
    int i1 = 0, i2 = n1, k = 0;
    while (i1 < n1 && i2 < n) {
      if (d_[i1] <= d_[i2]) srt_[k++] = i1++; else srt_[k++] = i2++;
    }
    while (i1 < n1) srt_[k++] = i1++;
    while (i2 < n) srt_[k++] = i2++;
    float zmax = 0.0f, dmax = 0.0f;
    for (int i = 0; i < n; ++i) {
      zmax = fmaxf(zmax, fabsf(z_[i]));
      dmax = fmaxf(dmax, fabsf(d_[i]));
    }
    float tol = 8.0f * EPS32 * fmaxf(dmax, zmax);
    int K = 0, k2 = n, full = 0, ngiv = 0;
    if (rho * zmax <= tol) full = 1;
    else {
      int pj = -1, jj = 0;
      for (; jj < n; ++jj) {
        int nj = srt_[jj];
        if (rho * fabsf(z_[nj]) <= tol) { k2--; indxp_[k2] = nj; }
        else { pj = nj; break; }
      }
      if (pj < 0) full = 1;
      else {
        for (jj = jj + 1; jj < n; ++jj) {
          int nj = srt_[jj];
          if (rho * fabsf(z_[nj]) <= tol) { k2--; indxp_[k2] = nj; }
          else {
            float s = z_[pj], c = z_[nj];
            float tauq = slapy2_(c, s);
            float tdf = d_[nj] - d_[pj];
            c /= tauq; s = -s / tauq;
            if (fabsf(tdf * c * s) <= tol) {
              z_[nj] = tauq; z_[pj] = 0.0f;
              gp_[ngiv] = pj; gq_[ngiv] = nj; gc_[ngiv] = c; gs_[ngiv] = s; ngiv++;
              float tt2 = d_[pj] * c * c + d_[nj] * s * s;
              d_[nj] = d_[pj] * s * s + d_[nj] * c * c;
              d_[pj] = tt2;
              k2--;
              int pos = k2;
              while (pos + 1 <= n - 1 && d_[pj] < d_[indxp_[pos + 1]]) {
                indxp_[pos] = indxp_[pos + 1]; pos++;
              }
              indxp_[pos] = pj;
              pj = nj;
            } else {
              dl_[K] = d_[pj]; w_[K] = z_[pj]; und_[K] = pj; K++;
              pj = nj;
            }
          }
        }
        dl_[K] = d_[pj]; w_[K] = z_[pj]; und_[K] = pj; K++;
      }
    }
    sci[0] = K; sci[1] = full; sci[2] = ngiv;
  }
  __syncthreads();
  int K = sci[0], full = sci[1], ngiv = sci[2];
  if (!full) {
    // Givens rotations applied row-parallel to global Q (same per-row op order)
    if (t < n) {
      size_t rowoff = (size_t)(bo + t) * 128 + bo;
      for (int g = 0; g < ngiv; ++g) {
        float c = gc_[g], s = gs_[g];
        float xq = Qin[rowoff + gp_[g]], yq = Qin[rowoff + gq_[g]];
        Qin[rowoff + gp_[g]] = c * xq + s * yq;
        Qin[rowoff + gq_[g]] = c * yq - s * xq;
      }
    }
    // ---- lane-group secular solve: root j = t/LPR, sub-lane sub = t%LPR ----
    const int j = t / LPR;
    const int sub = t % LPR;
    const bool act = (j < K);
    float dl_loc[NCH], w2_loc[NCH];
    float tauj_reg = 0.0f; float da_reg = 0.0f;
    if (act) {
      #pragma unroll
      for (int k = 0; k < NCH; ++k) {
        int i = sub + k * LPR;
        if (i < K) { dl_loc[k] = dl_[i]; float wi = w_[i]; w2_loc[k] = rho * wi * wi; }
        else { dl_loc[k] = 3.0e38f; w2_loc[k] = 0.0f; }   // term -> 0, no NaN
      }
      // zsum (already rho-scaled)
      float zs = 0.0f;
      #pragma unroll
      for (int k = 0; k < NCH; ++k) zs += w2_loc[k];
      #pragma unroll
      for (int m = 1; m < LPR; m <<= 1) zs += __shfl_xor(zs, m);
      // anchor decision
      int a; float lo2, hi2;
      if (j < K - 1) {
        float dj = dl_[j];
        float tm = 0.5f * (dl_[j + 1] - dj);
        float fm = 0.0f;
        #pragma unroll
        for (int k = 0; k < NCH; ++k) fm += w2_loc[k] / ((dl_loc[k] - dj) - tm);
        #pragma unroll
        for (int m = 1; m < LPR; m <<= 1) fm += __shfl_xor(fm, m);
        fm += 1.0f;
        if (fm >= 0.0f) { a = j; lo2 = 0.0f; hi2 = tm; }
        else { a = j + 1; lo2 = -tm; hi2 = 0.0f; }
      } else { a = K - 1; lo2 = 0.0f; hi2 = zs + 1e-30f; }
      float da = dl_[a];
      float sdl[NCH];
      #pragma unroll
      for (int k = 0; k < NCH; ++k) sdl[k] = dl_loc[k] - da;
      for (int it2 = 0; it2 < 36; ++it2) {
        float tc = 0.5f * (lo2 + hi2);
        float f = 0.0f;
        #pragma unroll
        for (int k = 0; k < NCH; ++k) f += w2_loc[k] / (sdl[k] - tc);
        #pragma unroll
        for (int m = 1; m < LPR; m <<= 1) f += __shfl_xor(f, m);
        f += 1.0f;
        if (f >= 0.0f) hi2 = tc; else lo2 = tc;
      }
      tauj_reg = 0.5f * (lo2 + hi2);
      da_reg = da;
      if (sub == 0) { lam_[j] = da + tauj_reg; tauv_[j] = tauj_reg; anc_[j] = a; }
    }
    __syncthreads();
    // Gu's sign-preserving z-hat (root i = j of this octet; chunk over jj)
    if (act) {
      float di = dl_[j];
      float pp = 1.0f;
      #pragma unroll
      for (int k = 0; k < NCH; ++k) {
        int jj = sub + k * LPR;
        if (jj < K && jj != j) {
          float delta_ij = (di - dl_[anc_[jj]]) - tauv_[jj];
          pp *= delta_ij / (di - dl_[jj]);
        }
      }
      #pragma unroll
      for (int m = 1; m < LPR; m <<= 1) pp *= __shfl_xor(pp, m);
      if (sub == 0) {
        float lead = (di - da_reg) - tauj_reg;
        float acc = lead * pp;
        zh_[j] = ssign_(sqrtf(fmaxf(-acc, 0.0f)), w_[j]);
      }
    }
    __syncthreads();
    // rank-1 system eigenvectors, chunked per lane, single scaled store
    if (act) {
      float sv[NCH]; float nrm = 0.0f;
      #pragma unroll
      for (int k = 0; k < NCH; ++k) {
        int i = sub + k * LPR;
        float s = 0.0f;
        if (i < K) s = zh_[i] / ((dl_loc[k] - da_reg) - tauj_reg);
        sv[k] = s; nrm += s * s;
      }
      #pragma unroll
      for (int m = 1; m < LPR; m <<= 1) nrm += __shfl_xor(nrm, m);
      nrm = 1.0f / sqrtf(nrm);
      float* scol = Sg + bo + j;
      #pragma unroll
      for (int k = 0; k < NCH; ++k) {
        int i = sub + k * LPR;
        if (i < K) scol[(size_t)(bo + i) * 128] = sv[k] * nrm;
      }
    }
    if (t == 0) {
      for (int jj = 0; jj < K; ++jj) dnew_[jj] = lam_[jj];
      for (int m = 0; m < n - K; ++m) dnew_[K + m] = d_[indxp_[n - 1 - m]];
      int i1 = 0, i2 = K, k = 0;
      while (i1 < K && i2 < n) { if (dnew_[i1] <= dnew_[i2]) fin_[k++] = i1++; else fin_[k++] = i2++; }
      while (i1 < K) fin_[k++] = i1++;
      while (i2 < n) fin_[k++] = i2++;
    }
    __syncthreads();
    if (t < n) {
      dvg[bo + t] = dnew_[fin_[t]];
      idxpG[bo + t] = indxp_[t];
      finG[bo + t] = fin_[t];
    }
    if (t < K) undG[bo + t] = und_[t];
    if (t == 0) KfG[mg] = K;
  } else {
    if (t < n) {
      dvg[bo + t] = d_[srt_[t]];
      idxpG[bo + t] = srt_[n - 1 - t];
      finG[bo + t] = t;
    }
    if (t == 0) KfG[mg] = 0;
  }
}

// ============ K3b: merge GEMM/permute, 32 rows per block ============
__global__ __launch_bounds__(256) void k_mergeB(float* __restrict__ wsG, int lvl,
                                                int qinoff, int qoutoff) {
  int b = blockIdx.x >> 2;
  int rblk = blockIdx.x & 3;
  int rbase = rblk * 32;
  int nm = 32 << lvl;
  int ln2 = 5 + lvl;
  int mg = rbase >> ln2;
  int bo = mg * nm, n = nm;
  const int t = threadIdx.x;
  float* base = wsG + (size_t)b * WS_STRIDE;
  const float* Qin = base + qinoff;
  float* Qout = base + qoutoff;
  const float* Sg = base + OFF_S;
  const int* meta = (const int*)(base + OFF_META);
  const int* undG = meta; const int* idxpG = meta + 128;
  const int* finG = meta + 256; const int* KfG = meta + 384;

  extern __shared__ float lds[];
  float* QT = lds;                 // [32][LDB]
  float* QC = QT + 32 * LDB;       // [32][LDB]
  float* WT = QC + 32 * LDB;       // [32][LDB]
  float* ST = WT + 32 * LDB;       // [128][LDB]
  __shared__ int und_l[128], idxp_l[128], fin_l[128];
  __shared__ int Ksh;

  if (t == 0) Ksh = KfG[mg];
  if (t < n) { und_l[t] = undG[bo + t]; idxp_l[t] = idxpG[bo + t]; fin_l[t] = finG[bo + t]; }
  for (int idx = t; idx < 32 * n; idx += 256) {
    int r = idx >> ln2, c = idx & (n - 1);
    QT[r * LDB + c] = Qin[(size_t)(rbase + r) * 128 + bo + c];
  }
  __syncthreads();
  int K = Ksh;
  for (int idx = t; idx < (K << 7); idx += 256) {
    int k = idx >> 7, j = idx & 127;
    ST[k * LDB + j] = Sg[(size_t)(bo + k) * 128 + bo + j];
  }
  for (int r = 0; r < 32; ++r)
    if (t < K) QC[r * LDB + t] = QT[r * LDB + und_l[t]];
  __syncthreads();
  for (int idx = t; idx < 32 * n; idx += 256) {
    int r = idx >> ln2, j = idx & (n - 1);
    float v;
    if (j < K) {
      float a0 = 0.f, a1 = 0.f, a2 = 0.f, a3 = 0.f;
      int k = 0;
      for (; k + 3 < K; k += 4) {
        a0 += QC[r * LDB + k]     * ST[k * LDB + j];
        a1 += QC[r * LDB + k + 1] * ST[(k + 1) * LDB + j];
        a2 += QC[r * LDB + k + 2] * ST[(k + 2) * LDB + j];
        a3 += QC[r * LDB + k + 3] * ST[(k + 3) * LDB + j];
      }
      for (; k < K; ++k) a0 += QC[r * LDB + k] * ST[k * LDB + j];
      v = (a0 + a1) + (a2 + a3);
    } else {
      v = QT[r * LDB + idxp_l[n - 1 - (j - K)]];
    }
    WT[r * LDB + j] = v;
  }
  __syncthreads();
  for (int idx = t; idx < 32 * 128; idx += 256) {
    int r = idx >> 7, c = idx & 127;
    int cl = c - bo;
    float v = 0.f;
    if (cl >= 0 && cl < n) v = WT[r * LDB + fin_l[cl]];
    Qout[(size_t)(rbase + r) * 128 + c] = v;
  }
}

// ============ K4: back-transform + outputs ============
// v2: 1024 threads, 16 waves; Q register-resident, barrier-free reflector loop.
__global__ __launch_bounds__(1024) void k_back(
    float* __restrict__ wsG, const unsigned char* __restrict__ nodemask,
    const float* __restrict__ mu, const float* __restrict__ isg,
    float* __restrict__ wsUt, float* __restrict__ wsLam,
    float* __restrict__ outEmb, float* __restrict__ outLmask) {
  const int b = blockIdx.x, t = threadIdx.x;
  float* base = wsG + (size_t)b * WS_STRIDE;
  float* Qg = base + OFF_Q1;
  float* dvg = base + OFF_DV;
  float* tg = base + OFF_TAU;
  float* og = base + OFF_ORG;
  extern __shared__ float lds[];
  float* At = lds;                 // [128][LDT]: At[c*LDT+r] = Aref[r][c]
  float* Qt = lds + 128 * LDT;     // [128][LDT]: Qt[c*LDT+r] = Q[r][c]
  __shared__ float d_[128], tau_[128];
  __shared__ unsigned char nm_[128];

  float orgnrm = og[0];
  for (int idx = t; idx < 16384; idx += 1024) {
    int r = idx >> 7, c = idx & 127;
    At[c * LDT + r] = base[idx];   // Aref transpose-staged
    Qt[c * LDT + r] = Qg[idx];
  }
  if (t < 128) {
    d_[t] = dvg[t] * orgnrm;
    tau_[t] = tg[t];
    nm_[t] = nodemask[b * 128 + t];
  }
  __syncthreads();

  // ---- register-resident back-transform ----
  const int w = t >> 6, l = t & 63;
  const int cidx = l & 7, sg = l >> 3;
  const int c = w * 8 + cidx;
  float q[16];
  #pragma unroll
  for (int k = 0; k < 4; ++k) {
    float4 v = *(const float4*)&Qt[c * LDT + 4 * sg + 32 * k];
    q[4 * k + 0] = v.x; q[4 * k + 1] = v.y; q[4 * k + 2] = v.z; q[4 * k + 3] = v.w;
  }
  for (int i = 126; i >= 0; --i) {
    float taui = tau_[i];
    if (taui == 0.0f) continue;     // uniform branch
    const int lo = i + 1;
    float a[16];
    float dot = 0.0f;
    #pragma unroll
    for (int k = 0; k < 4; ++k) {
      if (32 * k + 31 >= lo) {      // uniform chunk guard
        float4 av = *(const float4*)&At[i * LDT + 4 * sg + 32 * k];
        {
          int r = 4 * sg + 32 * k;
          float aj;
          aj = (r == lo) ? 1.0f : ((r > lo) ? av.x : 0.0f); a[4*k+0] = aj; dot += aj * q[4*k+0]; r++;
          aj = (r == lo) ? 1.0f : ((r > lo) ? av.y : 0.0f); a[4*k+1] = aj; dot += aj * q[4*k+1]; r++;
          aj = (r == lo) ? 1.0f : ((r > lo) ? av.z : 0.0f); a[4*k+2] = aj; dot += aj * q[4*k+2]; r++;
          aj = (r == lo) ? 1.0f : ((r > lo) ? av.w : 0.0f); a[4*k+3] = aj; dot += aj * q[4*k+3];
        }
      }
    }
    dot += __shfl_xor(dot, 8);
    dot += __shfl_xor(dot, 16);
    dot += __shfl_xor(dot, 32);
    float wv = taui * dot;
    #pragma unroll
    for (int k = 0; k < 4; ++k) {
      if (32 * k + 31 >= lo) {
        q[4*k+0] -= a[4*k+0] * wv;
        q[4*k+1] -= a[4*k+1] * wv;
        q[4*k+2] -= a[4*k+2] * wv;
        q[4*k+3] -= a[4*k+3] * wv;
      }
    }
  }
  #pragma unroll
  for (int k = 0; k < 4; ++k) {
    float4 v;
    v.x = q[4*k+0]; v.y = q[4*k+1]; v.z = q[4*k+2]; v.w = q[4*k+3];
    *(float4*)&Qt[c * LDT + 4 * sg + 32 * k] = v;
  }
  __syncthreads();

  // ---- outputs ----
  if (t < NL) {
    float lam = d_[t + 1];
    wsLam[b * NL + t] = lam;
    outLmask[b * NL + t] = (fabsf(lam) < 1e-4f) ? 1.f : 0.f;
  }
  for (int idx = t; idx < NL * 128; idx += 1024) {
    int ll = idx >> 7, nn2 = idx & 127;
    float lam = d_[ll + 1];
    float vv = Qt[(ll + 1) * LDT + nn2];   // Q[nn2][ll+1]
    if (fabsf(lam) < 1e-4f || nm_[nn2]) vv = 0.f;
    wsUt[(size_t)(b * NL + ll) * 128 + nn2] = vv;
  }
  for (int idx = t; idx < NL * NH; idx += 1024) {
    int ll = idx >> 7, h = idx & 127;
    float lam = d_[ll + 1];
    float sq = sqrtf(fmaxf(lam, 0.f));
    float dd = (sq - mu[h]) * isg[h];
    outEmb[(size_t)(b * NL + ll) * NH + h] = expf(-dd * dd);
  }
}

// ---------------- Xh = X*Wx + bx (masked) + nodemask passthrough ----------------
__global__ __launch_bounds__(256) void k_xh(
    const float* __restrict__ X, const unsigned char* __restrict__ nodemask,
    const float* __restrict__ Wx, const float* __restrict__ bx,
    float* __restrict__ outXh, float* __restrict__ outNm) {
  int idx = blockIdx.x * 256 + threadIdx.x;
  int h = idx & 127;
  int bn = idx >> 7;
  const float* xr = X + (size_t)bn * NDX;
  float acc = bx[h];
  #pragma unroll
  for (int d = 0; d < NDX; ++d) acc += xr[d] * Wx[d * NH + h];
  outXh[idx] = nodemask[bn] ? 0.f : acc;
  if (idx < NBATCH * NN) outNm[idx] = nodemask[idx] ? 1.f : 0.f;
}

// ---------------- Uc = (A x_d W_edge + b_edge) contracted with U ----------------
__global__ __launch_bounds__(256) void k_uc(
    const float* __restrict__ A, const unsigned char* __restrict__ nodemask,
    const float* __restrict__ We, const float* __restrict__ be,
    const float* __restrict__ wsUt, float* __restrict__ outUc) {
  int b = blockIdx.x >> 4;
  int ng = blockIdx.x & 15;
  int t = threadIdx.x;
  __shared__ float Uts[NL * 129];
  __shared__ float Ssh[NL];
  __shared__ float Wsh[NDE * NH];
  __shared__ float bsh[NH];
  __shared__ float Ar[NN * NDE];
  __shared__ float Tp[2 * NL * NDE];
  __shared__ float Ts[NL * NDE];
  for (int idx = t; idx < NL * NN; idx += 256) {
    int l = idx >> 7, n = idx & 127;
    Uts[l * 129 + n] = wsUt[(size_t)b * NL * NN + idx];
  }
  for (int idx = t; idx < NDE * NH; idx += 256) Wsh[idx] = We[idx];
  if (t < NH) bsh[t] = be[t];
  __syncthreads();
  if (t < NL) {
    float s = 0.f;
    for (int n = 0; n < NN; ++n) s += Uts[t * 129 + n];
    Ssh[t] = s;
  }
  __syncthreads();
  for (int nn = 0; nn < 8; ++nn) {
    int n = ng * 8 + nn;
    for (int idx = t; idx < NN * NDE; idx += 256)
      Ar[idx] = A[(size_t)(b * NN + n) * NN * NDE + idx];
    __syncthreads();
    {
      int l = t & 127, half = t >> 7;
      if (l < NL) {
        float a0 = 0.f, a1 = 0.f, a2 = 0.f, a3 = 0.f;
        for (int m = 64 * half; m < 64 * half + 64; ++m) {
          float u = Uts[l * 129 + m];
          a0 += Ar[m * 4 + 0] * u;
          a1 += Ar[m * 4 + 1] * u;
          a2 += Ar[m * 4 + 2] * u;
          a3 += Ar[m * 4 + 3] * u;
        }
        int base = (half * NL + l) * 4;
        Tp[base + 0] = a0; Tp[base + 1] = a1; Tp[base + 2] = a2; Tp[base + 3] = a3;
      }
    }
    __syncthreads();
    for (int idx = t; idx < NL * NDE; idx += 256) Ts[idx] = Tp[idx] + Tp[NL * NDE + idx];
    __syncthreads();
    bool mn = nodemask[b * NN + n] != 0;
    {
      int h = t & 127, lh = t >> 7;
      float w0 = Wsh[0 * NH + h], w1 = Wsh[1 * NH + h], w2 = Wsh[2 * NH + h], w3 = Wsh[3 * NH + h];
      float bb = bsh[h];
      for (int l = lh; l < NL; l += 2) {
        float v = w0 * Ts[l * 4 + 0] + w1 * Ts[l * 4 + 1] + w2 * Ts[l * 4 + 2] +
                  w3 * Ts[l * 4 + 3] + bb * Ssh[l];
        outUc[(size_t)((b * NN + n) * NL + l) * NH + h] = mn ? 0.f : v;
      }
    }
    __syncthreads();
  }
}

extern "C" void kernel_launch(void* const* d_in, const int* in_sizes, int n_in,
                              void* d_out, int out_size, void* d_ws, size_t ws_size,
                              hipStream_t stream) {
  const float* A = (const float*)d_in[0];
  const float* X = (const float*)d_in[1];
  const unsigned char* nodemask = (const unsigned char*)d_in[2];
  const float* We = (const float*)d_in[3];
  const float* be = (const float*)d_in[4];
  const float* Wx = (const float*)d_in[5];
  const float* bx = (const float*)d_in[6];
  const float* mu = (const float*)d_in[7];
  const float* isg = (const float*)d_in[8];

  float* out = (float*)d_out;
  float* outEmb = out;                   // 16*127*128
  float* outLmask = out + 260096;        // 16*127
  float* outUc = out + 262128;           // 16*128*127*128
  float* outXh = out + 33554416;         // 16*128*128
  float* outNm = out + 33816560;         // 16*128

  float* wsG = (float*)d_ws;                           // 16 * 66560 floats ≈ 4.26 MB
  float* wsUt = (float*)((char*)d_ws + 4456448);       // 16*127*128 floats
  float* wsLam = wsUt + 260096;

  size_t lds1 = (size_t)128 * LDA * sizeof(float);       // 67584
  size_t lds2 = (size_t)2 * 128 * LDT * sizeof(float);   // 135168
  size_t ldsB = (size_t)(3 * 32 * LDB + 128 * LDB) * sizeof(float);  // 115584

  k_tridiag<<<NBATCH, 1024, lds1, stream>>>(A, wsG);
  k_leaves<<<NBATCH * 8, 64, 0, stream>>>(wsG);
  k_mergeA<0><<<NBATCH * 4, 1024, 0, stream>>>(wsG, OFF_Q0);
  k_mergeB<<<NBATCH * 4, 256, ldsB, stream>>>(wsG, 0, OFF_Q0, OFF_Q1);
  k_mergeA<1><<<NBATCH * 2, 1024, 0, stream>>>(wsG, OFF_Q1);
  k_mergeB<<<NBATCH * 4, 256, ldsB, stream>>>(wsG, 1, OFF_Q1, OFF_Q0);
  k_mergeA<2><<<NBATCH * 1, 1024, 0, stream>>>(wsG, OFF_Q0);
  k_mergeB<<<NBATCH * 4, 256, ldsB, stream>>>(wsG, 2, OFF_Q0, OFF_Q1);
  k_back<<<NBATCH, 1024, lds2, stream>>>(wsG, nodemask, mu, isg, wsUt, wsLam, outEmb, outLmask);
  k_xh<<<(NBATCH * NN * NH) / 256, 256, 0, stream>>>(X, nodemask, Wx, bx, outXh, outNm);
  k_uc<<<NBATCH * 16, 256, 0, stream>>>(A, nodemask, We, be, wsUt, outUc);
}

// Round 12
// 915.999 us; speedup vs baseline: 1.0575x; 1.0575x over previous
//
#include <hip/hip_runtime.h>

#define NBATCH 16
#define NN 128
#define NH 128
#define NL 127
#define NDX 11
#define NDE 4
#define LDA 132
#define LDB 129
#define LDT 132
#define WS_STRIDE 66560  // floats per batch in wsG

// per-batch workspace float offsets
#define OFF_AREF 0
#define OFF_Q0   16384
#define OFF_Q1   32768
#define OFF_S    49152
#define OFF_DV   65536
#define OFF_EV   65664
#define OFF_TAU  65792
#define OFF_ORG  65920
#define OFF_META 66048   // 512 floats of int metadata

// ---------------- LAPACK fp32 helper ports ----------------
#define EPS32 5.9604645e-8f
#define EPS232 3.5527137e-15f
#define SAFMIN32 1.17549435e-38f

__device__ __forceinline__ float ssign_(float a, float b) {
  return (b >= 0.0f) ? fabsf(a) : -fabsf(a);
}
__device__ __forceinline__ float slapy2_(float x, float y) {
  float ax = fabsf(x), ay = fabsf(y);
  float w = fmaxf(ax, ay), z = fminf(ax, ay);
  if (z == 0.0f) return w;
  float q = z / w;
  return w * sqrtf(1.0f + q * q);
}

// broadcast-read lane `src`'s value of v (uniform src -> v_readlane, scalar pipe)
__device__ __forceinline__ float rdl(float v, int src) {
  return __int_as_float(__builtin_amdgcn_readlane(__float_as_int(v), src));
}

__device__ void slartg_(float f, float g, float* c, float* s, float* r) {
  if (g == 0.0f) { *c = 1.0f; *s = 0.0f; *r = f; }
  else if (f == 0.0f) { *c = 0.0f; *s = (g >= 0.0f) ? 1.0f : -1.0f; *r = fabsf(g); }
  else {
    float d = sqrtf(f * f + g * g);
    d = (f >= 0.0f) ? d : -d;
    *c = f / d; *s = g / d; *r = d;
  }
}

__device__ void slaev2_(float a, float b, float c0, float* rt1, float* rt2,
                        float* cs1, float* sn1) {
  float sm = a + c0, df = a - c0, adf = fabsf(df), tb = b + b, ab = fabsf(tb);
  float acmx, acmn;
  if (fabsf(a) > fabsf(c0)) { acmx = a; acmn = c0; } else { acmx = c0; acmn = a; }
  float rt;
  if (adf > ab) { float q = ab / adf; rt = adf * sqrtf(1.0f + q * q); }
  else if (adf < ab) { float q = adf / ab; rt = ab * sqrtf(1.0f + q * q); }
  else rt = ab * sqrtf(2.0f);
  int sgn1;
  if (sm < 0.0f) { *rt1 = 0.5f * (sm - rt); sgn1 = -1; *rt2 = (acmx / *rt1) * acmn - (b / *rt1) * b; }
  else if (sm > 0.0f) { *rt1 = 0.5f * (sm + rt); sgn1 = 1; *rt2 = (acmx / *rt1) * acmn - (b / *rt1) * b; }
  else { *rt1 = 0.5f * rt; *rt2 = -0.5f * rt; sgn1 = 1; }
  int sgn2; float cs;
  if (df >= 0.0f) { cs = df + rt; sgn2 = 1; } else { cs = df - rt; sgn2 = -1; }
  float acs = fabsf(cs);
  if (acs > ab) { float ct = -tb / cs; *sn1 = 1.0f / sqrtf(1.0f + ct * ct); *cs1 = ct * (*sn1); }
  else {
    if (ab == 0.0f) { *cs1 = 1.0f; *sn1 = 0.0f; }
    else { float tn = -cs / tb; *cs1 = 1.0f / sqrtf(1.0f + tn * tn); *sn1 = tn * (*cs1); }
  }
  if (sgn1 == sgn2) { float tn = *cs1; *cs1 = -(*sn1); *sn1 = tn; }
}

// ============ K1: Laplacian build + ssytd2 tridiagonalization ============
// v7 (R10, measured best 325us): 512 threads, R9 4-barrier schedule,
// LDA=132, shfl readbacks. R11's 1024-thread variant regressed (barrier
// skew) -> reverted.
__global__ __launch_bounds__(512) void k_tridiag(const float* __restrict__ A_in,
                                                 float* __restrict__ wsG) {
  const int b = blockIdx.x, t = threadIdx.x;
  float* Aref = wsG + (size_t)b * WS_STRIDE;
  float* dv = Aref + OFF_DV;
  float* ev = Aref + OFF_EV;
  float* tg = Aref + OFF_TAU;
  float* og = Aref + OFF_ORG;
  extern __shared__ float As[];  // [128][LDA], LDA=132
  __shared__ unsigned int maskp[128][4];
  __shared__ unsigned int Dp[128][4];
  __shared__ unsigned long long adj0_[128], adj1_[128];
  __shared__ float Dd_[128], tDs_[128];
  __shared__ float d_[128], e_[128], tau_[128];
  __shared__ alignas(16) float v_[128];
  __shared__ alignas(16) float w_[128];
  __shared__ float pmat[4][128];
  __shared__ alignas(16) float red_[16];
  __shared__ float xp[16];

  const int wid = t >> 6;        // wave id 0..7
  const int lane = t & 63;
  // ---- adjacency build: 4 threads per row, 32 m's each ----
  {
    const int r8 = t >> 2, s8 = t & 3;
    const float4* Arow = (const float4*)(A_in + (size_t)(b * 128 + r8) * 128 * 4);
    unsigned int mloc = 0; unsigned int cnt = 0;
    const int m0 = s8 * 32;
    #pragma unroll 4
    for (int mm = 0; mm < 32; ++mm) {
      float4 a = Arow[m0 + mm];
      if (a.x != 0.f || a.y != 0.f || a.z != 0.f || a.w != 0.f) { mloc |= 1u << mm; cnt++; }
    }
    maskp[r8][s8] = mloc; Dp[r8][s8] = cnt;
  }
  __syncthreads();
  if (t < 128) {
    unsigned long long b0 = (unsigned long long)maskp[t][0] |
                            ((unsigned long long)maskp[t][1] << 32);
    unsigned long long b1 = (unsigned long long)maskp[t][2] |
                            ((unsigned long long)maskp[t][3] << 32);
    unsigned int D = Dp[t][0] + Dp[t][1] + Dp[t][2] + Dp[t][3];
    adj0_[t] = b0; adj1_[t] = b1;
    float Df = (float)D;
    Dd_[t] = Df;
    tDs_[t] = 1.0f / sqrtf(fmaxf(Df, 1.0f));
  }
  __syncthreads();
  for (int idx = t; idx < 16384; idx += 512) {
    int r = idx >> 7, c = idx & 127;
    if (c <= r) {
      float adj = (float)((c < 64 ? (adj0_[r] >> c) : (adj1_[r] >> (c - 64))) & 1ull);
      float Lrc = ((c == r) ? Dd_[r] : 0.0f) - adj;
      float val = (tDs_[c] * Lrc) * tDs_[r];
      As[r * LDA + c] = val;
      As[c * LDA + r] = val;
    }
  }
  __syncthreads();

  const int rmv = t & 127;   // matvec row
  const int smv = t >> 7;    // matvec segment 0..3 (32 cols each)
  const int ucg = t & 31;    // update col-group (4 cols)
  const int urs = t >> 5;    // update row stripe 0..15

  bool usexp = false;
  for (int i = 0; i < 127; ++i) {
    const int lo = i + 1;
    // ---- xnorm2 of column i below subdiagonal ----
    float xnorm2;
    if (!usexp) {           // uniform fallback path (iter 0 / after taui==0)
      float part = 0.0f;
      if (t < 128 && t >= i + 2) { float x = As[t * LDA + i]; part = x * x; }
      if (wid < 2) {
        #pragma unroll
        for (int m = 1; m < 64; m <<= 1) part += __shfl_xor(part, m);
        if (lane == 0) red_[wid] = part;
      }
      __syncthreads();   // S1 (fallback only)
      xnorm2 = red_[0] + red_[1];
    } else {               // piggybacked: 1 LDS read + shfl tree (sum of 16)
      float s = xp[lane & 15];
      #pragma unroll
      for (int m = 1; m < 16; m <<= 1) s += __shfl_xor(s, m);
      xnorm2 = s;
    }
    float alpha = As[lo * LDA + i];   // row lo never written in phase B
    float beta, taui, scal;
    if (xnorm2 == 0.0f) { taui = 0.0f; beta = alpha; scal = 0.0f; }
    else {
      float xn = sqrtf(xnorm2);
      beta = -ssign_(slapy2_(alpha, xn), alpha);
      taui = (beta - alpha) / beta;
      scal = 1.0f / (alpha - beta);
    }
    if (t == 0) { e_[i] = beta; tau_[i] = taui; }
    if (taui != 0.0f) {    // uniform branch
      // ---- phase B: single-writer v construction ----
      if (t < 128) {
        float vv = 0.0f;
        if (t == lo) vv = 1.0f;
        else if (t > lo) { float xi = As[t * LDA + i]; vv = xi * scal; As[t * LDA + i] = vv; }
        v_[t] = vv;
      }
      __syncthreads();   // S2
      // ---- phase C: matvec partials (32-col chunk) + vpdot partial ----
      const int c0 = smv * 32;
      float acc = 0.0f;
      if (c0 + 31 >= lo && rmv >= lo) {
        const float4* Ar = (const float4*)&As[rmv * LDA + c0];
        const float4* Vr = (const float4*)&v_[c0];
        #pragma unroll
        for (int k = 0; k < 8; ++k) {
          float4 a = Ar[k], v4 = Vr[k];
          acc += a.x * v4.x + a.y * v4.y + a.z * v4.z + a.w * v4.w;
        }
      }
      pmat[smv][rmv] = acc;
      float p2 = v_[rmv] * acc;
      #pragma unroll
      for (int m = 1; m < 64; m <<= 1) p2 += __shfl_xor(p2, m);
      if (lane == 0) red_[wid] = p2;
      __syncthreads();   // S3
      // ---- phase D: w = taui*(Av); a2 via shfl-sum of red_[0..7] ----
      float vpr = red_[lane & 7];
      #pragma unroll
      for (int m = 1; m < 8; m <<= 1) vpr += __shfl_xor(vpr, m);
      float a2 = -0.5f * taui * (taui * vpr);
      if (t < 128) {
        float pv = pmat[0][t] + pmat[1][t] + pmat[2][t] + pmat[3][t];
        w_[t] = taui * pv;
      }
      __syncthreads();   // S4
      // ---- phase E: rank-2 update + next-xnorm piggyback ----
      const int uc0 = ucg * 4;
      if (uc0 + 3 >= lo) {
        float4 vc = *(const float4*)&v_[uc0];
        float4 wc = *(const float4*)&w_[uc0];
        float pcx = wc.x + a2 * vc.x;
        float pcy = wc.y + a2 * vc.y;
        float pcz = wc.z + a2 * vc.z;
        float pcw = wc.w + a2 * vc.w;
        if (uc0 < lo) {   // partial chunk: neutralize components left of lo
          if (uc0 + 0 < lo) { vc.x = 0.f; pcx = 0.f; }
          if (uc0 + 1 < lo) { vc.y = 0.f; pcy = 0.f; }
          if (uc0 + 2 < lo) { vc.z = 0.f; pcz = 0.f; }
        }
        const bool isxcol = (ucg == (lo >> 2));
        const int xc = lo & 3;
        float xpacc = 0.0f;
        #pragma unroll
        for (int k = 0; k < 8; ++k) {
          int r = urs + 16 * k;
          if (r >= lo) {
            float vr = v_[r];
            float pr = w_[r] + a2 * vr;
            float4 a = *(const float4*)&As[r * LDA + uc0];
            a.x -= vr * pcx + pr * vc.x;
            a.y -= vr * pcy + pr * vc.y;
            a.z -= vr * pcz + pr * vc.z;
            a.w -= vr * pcw + pr * vc.w;
            *(float4*)&As[r * LDA + uc0] = a;
            if (isxcol && r >= lo + 2) {
              float nc = (xc == 0) ? a.x : ((xc == 1) ? a.y : ((xc == 2) ? a.z : a.w));
              xpacc += nc * nc;
            }
          }
        }
        if (isxcol) xp[urs] = xpacc;
      }
    }
    __syncthreads();   // S5
    usexp = (taui != 0.0f);
  }
  if (t < 128) d_[t] = As[t * LDA + t];
  __syncthreads();

  {
    float mx = 0.0f;
    if (t < 128) mx = fabsf(d_[t]);
    if (t < 127) mx = fmaxf(mx, fabsf(e_[t]));
    if (wid < 2) {
      #pragma unroll
      for (int m = 1; m < 64; m <<= 1) mx = fmaxf(mx, __shfl_xor(mx, m));
      if (lane == 0) red_[wid] = mx;
    }
    __syncthreads();
  }
  float orgnrm = fmaxf(red_[0], red_[1]);
  if (orgnrm == 0.0f) orgnrm = 1.0f;
  float invnrm = 1.0f / orgnrm;
  if (t < 128) d_[t] *= invnrm;
  if (t < 127) e_[t] *= invnrm;
  __syncthreads();
  if (t == 0) {
    for (int bm = 16; bm < 128; bm += 16) {
      float ae = fabsf(e_[bm - 1]);
      d_[bm - 1] -= ae; d_[bm] -= ae;
    }
  }
  __syncthreads();
  for (int idx = t; idx < 16384; idx += 512)
    Aref[idx] = As[(idx >> 7) * LDA + (idx & 127)];
  if (t < 128) { dv[t] = d_[t]; tg[t] = tau_[t]; }
  if (t < 127) ev[t] = e_[t];
  if (t == 0) og[0] = orgnrm;
}

// ============ K2: 8 leaves x 16 batches, one block each ============
// v3: lane-register ssteqr (readlane broadcasts); band-limited Q0 write.
__global__ __launch_bounds__(64) void k_leaves(float* __restrict__ wsG) {
  int b = blockIdx.x >> 3, lf = blockIdx.x & 7;
  float* base = wsG + (size_t)b * WS_STRIDE;
  float* Qg = base + OFF_Q0;
  float* dv = base + OFF_DV;
  float* ev = base + OFF_EV;
  const int ln = threadIdx.x;
  __shared__ float zsh[16 * 17];

  const int n = 16;
  float dreg = (ln < 16) ? dv[lf * 16 + ln] : 0.f;
  float ereg = (ln < 15) ? ev[lf * 16 + ln] : 0.f;
  float csreg = 0.f, snreg = 0.f;
  float zr[16];
  #pragma unroll
  for (int c = 0; c < 16; ++c) zr[c] = (ln == c) ? 1.0f : 0.0f;

  {
    const float eps = EPS32, eps2 = EPS232, safmin = SAFMIN32;
    int nmaxit = n * 30, jtot = 0;
    int l1 = 0;
    while (l1 <= n - 1) {
      if (l1 > 0 && ln == l1 - 1) ereg = 0.0f;
      int m;
      for (m = l1; m <= n - 2; ++m) {
        float tst = fabsf(rdl(ereg, m));
        if (tst == 0.0f) break;
        if (tst <= (sqrtf(fabsf(rdl(dreg, m))) * sqrtf(fabsf(rdl(dreg, m + 1)))) * eps) {
          if (ln == m) ereg = 0.0f;
          break;
        }
      }
      int l = l1, lend = m;
      l1 = m + 1;
      if (lend == l) continue;
      {
        float an = 0.0f;
        for (int i = l; i <= lend; ++i) an = fmaxf(an, fabsf(rdl(dreg, i)));
        for (int i = l; i <= lend - 1; ++i) an = fmaxf(an, fabsf(rdl(ereg, i)));
        if (an == 0.0f) continue;
      }
      if (fabsf(rdl(dreg, lend)) < fabsf(rdl(dreg, l))) { int tsw = l; l = lend; lend = tsw; }
      if (lend > l) {
        while (true) {  // QL
          int m2;
          if (l != lend) {
            for (m2 = l; m2 <= lend - 1; ++m2) {
              float em = rdl(ereg, m2);
              float tst = em * em;
              if (tst <= (eps2 * fabsf(rdl(dreg, m2))) * fabsf(rdl(dreg, m2 + 1)) + safmin) break;
            }
          } else m2 = lend;
          if (m2 < lend && ln == m2) ereg = 0.0f;
          float p = rdl(dreg, l);
          if (m2 == l) { l++; if (l <= lend) continue; else break; }
          if (m2 == l + 1) {
            float rt1, rt2, c, s;
            slaev2_(rdl(dreg, l), rdl(ereg, l), rdl(dreg, l + 1), &rt1, &rt2, &c, &s);
            #pragma unroll
            for (int j = 0; j < 15; ++j) {
              if (j == l) {
                float t1 = zr[j + 1];
                zr[j + 1] = c * t1 - s * zr[j];
                zr[j] = s * t1 + c * zr[j];
              }
            }
            if (ln == l) { dreg = rt1; ereg = 0.0f; }
            if (ln == l + 1) dreg = rt2;
            l += 2; if (l <= lend) continue; else break;
          }
          if (jtot == nmaxit) break;
          jtot++;
          float g = (rdl(dreg, l + 1) - p) / (2.0f * rdl(ereg, l));
          float r = slapy2_(g, 1.0f);
          g = rdl(dreg, m2) - p + rdl(ereg, l) / (g + ssign_(r, g));
          float s = 1.0f, c = 1.0f; p = 0.0f;
          for (int i = m2 - 1; i >= l; --i) {
            float ei = rdl(ereg, i);
            float f = s * ei, bb = c * ei;
            slartg_(g, f, &c, &s, &r);
            if (i != m2 - 1 && ln == i + 1) ereg = r;
            g = rdl(dreg, i + 1) - p;
            r = (rdl(dreg, i) - g) * s + 2.0f * c * bb;
            p = s * r;
            if (ln == i + 1) dreg = g + p;
            g = c * r - bb;
            if (ln == i) { csreg = c; snreg = -s; }
          }
          #pragma unroll
          for (int j = 14; j >= 0; --j) {
            if (j <= m2 - 1 && j >= l) {
              float cj = rdl(csreg, j), sj = rdl(snreg, j);
              float t1 = zr[j + 1];
              zr[j + 1] = cj * t1 - sj * zr[j];
              zr[j] = sj * t1 + cj * zr[j];
            }
          }
          if (ln == l) { dreg = dreg - p; ereg = g; }
        }
      } else {
        while (true) {  // QR
          int m2;
          if (l != lend) {
            for (m2 = l; m2 >= lend + 1; --m2) {
              float em = rdl(ereg, m2 - 1);
              float tst = em * em;
              if (tst <= (eps2 * fabsf(rdl(dreg, m2))) * fabsf(rdl(dreg, m2 - 1)) + safmin) break;
            }
          } else m2 = lend;
          if (m2 > lend && ln == m2 - 1) ereg = 0.0f;
          float p = rdl(dreg, l);
          if (m2 == l) { l--; if (l >= lend) continue; else break; }
          if (m2 == l - 1) {
            float rt1, rt2, c, s;
            slaev2_(rdl(dreg, l - 1), rdl(ereg, l - 1), rdl(dreg, l), &rt1, &rt2, &c, &s);
            #pragma unroll
            for (int j = 0; j < 15; ++j) {
              if (j == l - 1) {
                float t1 = zr[j + 1];
                zr[j + 1] = c * t1 - s * zr[j];
                zr[j] = s * t1 + c * zr[j];
              }
            }
            if (ln == l - 1) { dreg = rt1; ereg = 0.0f; }
            if (ln == l) dreg = rt2;
            l -= 2; if (l >= lend) continue; else break;
          }
          if (jtot == nmaxit) break;
          jtot++;
          float g = (rdl(dreg, l - 1) - p) / (2.0f * rdl(ereg, l - 1));
          float r = slapy2_(g, 1.0f);
          g = rdl(dreg, m2) - p + rdl(ereg, l - 1) / (g + ssign_(r, g));
          float s = 1.0f, c = 1.0f; p = 0.0f;
          for (int i = m2; i <= l - 1; ++i) {
            float ei = rdl(ereg, i);
            float f = s * ei, bb = c * ei;
            slartg_(g, f, &c, &s, &r);
            if (i != m2 && ln == i - 1) ereg = r;
            g = rdl(dreg, i) - p;
            r = (rdl(dreg, i + 1) - g) * s + 2.0f * c * bb;
            p = s * r;
            if (ln == i) dreg = g + p;
            g = c * r - bb;
            if (ln == i) { csreg = c; snreg = s; }
          }
          #pragma unroll
          for (int j = 0; j <= 14; ++j) {
            if (j >= m2 && j <= l - 1) {
              float cj = rdl(csreg, j), sj = rdl(snreg, j);
              float t1 = zr[j + 1];
              zr[j + 1] = cj * t1 - sj * zr[j];
              zr[j] = sj * t1 + cj * zr[j];
            }
          }
          if (ln == l) dreg = dreg - p;
          if (ln == l - 1) ereg = g;
        }
      }
    }
  }

  // stage z rows to LDS for sort + band write
  if (ln < 16) {
    #pragma unroll
    for (int c = 0; c < 16; ++c) zsh[ln * 17 + c] = zr[c];
  }
  __syncthreads();
  // selection sort: d in lane registers, z column swaps row-parallel in LDS
  for (int ii = 1; ii <= n - 1; ++ii) {
    int i = ii - 1, k = i;
    float p = rdl(dreg, i);
    for (int j = ii; j <= n - 1; ++j) {
      float dj = rdl(dreg, j);
      if (dj < p) { k = j; p = dj; }
    }
    if (k != i) {
      float di = rdl(dreg, i);
      if (ln == k) dreg = di;
      if (ln == i) dreg = p;
      if (ln < 16) {
        float t1 = zsh[ln * 17 + i];
        zsh[ln * 17 + i] = zsh[ln * 17 + k];
        zsh[ln * 17 + k] = t1;
      }
    }
  }
  __syncthreads();
  if (ln < 16) dv[lf * 16 + ln] = dreg;
  // write only the 32-col merge band: cols bo..bo+31 where bo=(lf>>1)*32
  {
    const int bo = (lf >> 1) * 32;
    const int cofs = (lf & 1) * 16;   // local col offset of this leaf in band
    for (int idx = ln; idx < 16 * 32; idx += 64) {
      int rr = idx >> 5, c = idx & 31;
      int cl = c - cofs;
      float v = (cl >= 0 && cl < 16) ? zsh[rr * 17 + cl] : 0.f;
      Qg[(size_t)(lf * 16 + rr) * 128 + bo + c] = v;
    }
  }
}

// ============ K3a: merge metadata/secular per (batch, merge) ============
// v3: register bisection 36 iters (48 was below fp32 noise floor already).
template <int LVL>
__global__ __launch_bounds__(1024) void k_mergeA(float* __restrict__ wsG, int qoff) {
  constexpr int sh = 2 - LVL;
  constexpr int nm = 32 << LVL;     // merged size n
  constexpr int LPR = 1024 / nm;    // lanes per root: 32/16/8
  constexpr int NCH = nm / LPR;     // chunk regs per lane: 1/4/16
  int b = blockIdx.x >> sh;
  int mg = blockIdx.x & ((1 << sh) - 1);
  int bo = mg * nm, n1 = nm >> 1, n = nm;
  const int t = threadIdx.x;
  float* base = wsG + (size_t)b * WS_STRIDE;
  float* Qin = base + qoff;
  float* dvg = base + OFF_DV;
  float* evg = base + OFF_EV;
  float* Sg  = base + OFF_S;
  int* meta = (int*)(base + OFF_META);
  int* undG = meta; int* idxpG = meta + 128; int* finG = meta + 256; int* KfG = meta + 384;

  __shared__ float d_[128], z_[128], dl_[128], w_[128], zh_[128], lam_[128], tauv_[128], dnew_[128];
  __shared__ int srt_[128], indxp_[128], und_[128], anc_[128], fin_[128];
  __shared__ int gp_[128], gq_[128];
  __shared__ float gc_[128], gs_[128];
  __shared__ int sci[4];

  if (t < n) d_[t] = dvg[bo + t];
  float rho_in = evg[bo + n1 - 1];
  if (t < n) {
    float zv = (t < n1) ? Qin[(size_t)(bo + n1 - 1) * 128 + bo + t]
                        : Qin[(size_t)(bo + n1) * 128 + bo + t];
    if (rho_in < 0.0f && t >= n1) zv = -zv;
    z_[t] = zv * 0.70710678f;
  }
  __syncthreads();
  float rho = fabsf(2.0f * rho_in);
  if (t == 0) {
    int i1 = 0, i2 = n1, k = 0;
    while (i1 < n1 && i2 < n) {
      if (d_[i1] <= d_[i2]) srt_[k++] = i1++; else srt_[k++] = i2++;
    }
    while (i1 < n1) srt_[k++] = i1++;
    while (i2 < n) srt_[k++] = i2++;
    float zmax = 0.0f, dmax = 0.0f;
    for (int i = 0; i < n; ++i) {
      zmax = fmaxf(zmax, fabsf(z_[i]));
      dmax = fmaxf(dmax, fabsf(d_[i]));
    }
    float tol = 8.0f * EPS32 * fmaxf(dmax, zmax);
    int K = 0, k2 = n, full = 0, ngiv = 0;
    if (rho * zmax <= tol) full = 1;
    else {
      int pj = -1, jj = 0;
      for (; jj < n; ++jj) {
        int nj = srt_[jj];
        if (rho * fabsf(z_[nj]) <= tol) { k2--; indxp_[k2] = nj; }
        else { pj = nj; break; }
      }
      if (pj < 0) full = 1;
      else {
        for (jj = jj + 1; jj < n; ++jj) {
          int nj = srt_[jj];
          if (rho * fabsf(z_[nj]) <= tol) { k2--; indxp_[k2] = nj; }
          else {
            float s = z_[pj], c = z_[nj];
            float tauq = slapy2_(c, s);
            float tdf = d_[nj] - d_[pj];
            c /= tauq; s = -s / tauq;
            if (fabsf(tdf * c * s) <= tol) {
              z_[nj] = tauq; z_[pj] = 0.0f;
              gp_[ngiv] = pj; gq_[ngiv] = nj; gc_[ngiv] = c; gs_[ngiv] = s; ngiv++;
              float tt2 = d_[pj] * c * c + d_[nj] * s * s;
              d_[nj] = d_[pj] * s * s + d_[nj] * c * c;
              d_[pj] = tt2;
              k2--;
              int pos = k2;
              while (pos + 1 <= n - 1 && d_[pj] < d_[indxp_[pos + 1]]) {
                indxp_[pos] = indxp_[pos + 1]; pos++;
              }
              indxp_[pos] = pj;
              pj = nj;
            } else {
              dl_[K] = d_[pj]; w_[K] = z_[pj]; und_[K] = pj; K++;
              pj = nj;
            }
          }
        }
        dl_[K] = d_[pj]; w_[K] = z_[pj]; und_[K] = pj; K++;
      }
    }
    sci[0] = K; sci[1] = full; sci[2] = ngiv;
  }
  __syncthreads();
  int K = sci[0], full = sci[1], ngiv = sci[2];
  if (!full) {
    // Givens rotations applied row-parallel to global Q (same per-row op order)
    if (t < n) {
      size_t rowoff = (size_t)(bo + t) * 128 + bo;
      for (int g = 0; g < ngiv; ++g) {
        float c = gc_[g], s = gs_[g];
        float xq = Qin[rowoff + gp_[g]], yq = Qin[rowoff + gq_[g]];
        Qin[rowoff + gp_[g]] = c * xq + s * yq;
        Qin[rowoff + gq_[g]] = c * yq - s * xq;
      }
    }
    // ---- lane-group secular solve: root j = t/LPR, sub-lane sub = t%LPR ----
    const int j = t / LPR;
    const int sub = t % LPR;
    const bool act = (j < K);
    float dl_loc[NCH], w2_loc[NCH];
    float tauj_reg = 0.0f; float da_reg = 0.0f;
    if (act) {
      #pragma unroll
      for (int k = 0; k < NCH; ++k) {
        int i = sub + k * LPR;
        if (i < K) { dl_loc[k] = dl_[i]; float wi = w_[i]; w2_loc[k] = rho * wi * wi; }
        else { dl_loc[k] = 3.0e38f; w2_loc[k] = 0.0f; }   // term -> 0, no NaN
      }
      // zsum (already rho-scaled)
      float zs = 0.0f;
      #pragma unroll
      for (int k = 0; k < NCH; ++k) zs += w2_loc[k];
      #pragma unroll
      for (int m = 1; m < LPR; m <<= 1) zs += __shfl_xor(zs, m);
      // anchor decision
      int a; float lo2, hi2;
      if (j < K - 1) {
        float dj = dl_[j];
        float tm = 0.5f * (dl_[j + 1] - dj);
        float fm = 0.0f;
        #pragma unroll
        for (int k = 0; k < NCH; ++k) fm += w2_loc[k] / ((dl_loc[k] - dj) - tm);
        #pragma unroll
        for (int m = 1; m < LPR; m <<= 1) fm += __shfl_xor(fm, m);
        fm += 1.0f;
        if (fm >= 0.0f) { a = j; lo2 = 0.0f; hi2 = tm; }
        else { a = j + 1; lo2 = -tm; hi2 = 0.0f; }
      } else { a = K - 1; lo2 = 0.0f; hi2 = zs + 1e-30f; }
      float da = dl_[a];
      float sdl[NCH];
      #pragma unroll
      for (int k = 0; k < NCH; ++k) sdl[k] = dl_loc[k] - da;
      for (int it2 = 0; it2 < 36; ++it2) {
        float tc = 0.5f * (lo2 + hi2);
        float f = 0.0f;
        #pragma unroll
        for (int k = 0; k < NCH; ++k) f += w2_loc[k] / (sdl[k] - tc);
        #pragma unroll
        for (int m = 1; m < LPR; m <<= 1) f += __shfl_xor(f, m);
        f += 1.0f;
        if (f >= 0.0f) hi2 = tc; else lo2 = tc;
      }
      tauj_reg = 0.5f * (lo2 + hi2);
      da_reg = da;
      if (sub == 0) { lam_[j] = da + tauj_reg; tauv_[j] = tauj_reg; anc_[j] = a; }
    }
    __syncthreads();
    // Gu's sign-preserving z-hat (root i = j of this octet; chunk over jj)
    if (act) {
      float di = dl_[j];
      float pp = 1.0f;
      #pragma unroll
      for (int k = 0; k < NCH; ++k) {
        int jj = sub + k * LPR;
        if (jj < K && jj != j) {
          float delta_ij = (di - dl_[anc_[jj]]) - tauv_[jj];
          pp *= delta_ij / (di - dl_[jj]);
        }
      }
      #pragma unroll
      for (int m = 1; m < LPR; m <<= 1) pp *= __shfl_xor(pp, m);
      if (sub == 0) {
        float lead = (di - da_reg) - tauj_reg;
        float acc = lead * pp;
        zh_[j] = ssign_(sqrtf(fmaxf(-acc, 0.0f)), w_[j]);
      }
    }
    __syncthreads();
    // rank-1 system eigenvectors, chunked per lane, single scaled store
    if (act) {
      float sv[NCH]; float nrm = 0.0f;
      #pragma unroll
      for (int k = 0; k < NCH; ++k) {
        int i = sub + k * LPR;
        float s = 0.0f;
        if (i < K) s = zh_[i] / ((dl_loc[k] - da_reg) - tauj_reg);
        sv[k] = s; nrm += s * s;
      }
      #pragma unroll
      for (int m = 1; m < LPR; m <<= 1) nrm += __shfl_xor(nrm, m);
      nrm = 1.0f / sqrtf(nrm);
      float* scol = Sg + bo + j;
      #pragma unroll
      for (int k = 0; k < NCH; ++k) {
        int i = sub + k * LPR;
        if (i < K) scol[(size_t)(bo + i) * 128] = sv[k] * nrm;
      }
    }
    if (t == 0) {
      for (int jj = 0; jj < K; ++jj) dnew_[jj] = lam_[jj];
      for (int m = 0; m < n - K; ++m) dnew_[K + m] = d_[indxp_[n - 1 - m]];
      int i1 = 0, i2 = K, k = 0;
      while (i1 < K && i2 < n) { if (dnew_[i1] <= dnew_[i2]) fin_[k++] = i1++; else fin_[k++] = i2++; }
      while (i1 < K) fin_[k++] = i1++;
      while (i2 < n) fin_[k++] = i2++;
    }
    __syncthreads();
    if (t < n) {
      dvg[bo + t] = dnew_[fin_[t]];
      idxpG[bo + t] = indxp_[t];
      finG[bo + t] = fin_[t];
    }
    if (t < K) undG[bo + t] = und_[t];
    if (t == 0) KfG[mg] = K;
  } else {
    if (t < n) {
      dvg[bo + t] = d_[srt_[t]];
      idxpG[bo + t] = srt_[n - 1 - t];
      finG[bo + t] = t;
    }
    if (t == 0) KfG[mg] = 0;
  }
}

// ============ K3b: merge GEMM/permute, 32 rows per block ============
// v2: 512 threads (8 waves = 2/SIMD; was 1 wave/SIMD at 256 with 115KB LDS).
__global__ __launch_bounds__(512) void k_mergeB(float* __restrict__ wsG, int lvl,
                                                int qinoff, int qoutoff) {
  int b = blockIdx.x >> 2;
  int rblk = blockIdx.x & 3;
  int rbase = rblk * 32;
  int nm = 32 << lvl;
  int ln2 = 5 + lvl;
  int mg = rbase >> ln2;
  int bo = mg * nm, n = nm;
  const int t = threadIdx.x;
  float* base = wsG + (size_t)b * WS_STRIDE;
  const float* Qin = base + qinoff;
  float* Qout = base + qoutoff;
  const float* Sg = base + OFF_S;
  const int* meta = (const int*)(base + OFF_META);
  const int* undG = meta; const int* idxpG = meta + 128;
  const int* finG = meta + 256; const int* KfG = meta + 384;

  extern __shared__ float lds[];
  float* QT = lds;                 // [32][LDB]
  float* QC = QT + 32 * LDB;       // [32][LDB]
  float* WT = QC + 32 * LDB;       // [32][LDB]
  float* ST = WT + 32 * LDB;       // [128][LDB]
  __shared__ int und_l[128], idxp_l[128], fin_l[128];
  __shared__ int Ksh;

  if (t == 0) Ksh = KfG[mg];
  if (t < n) { und_l[t] = undG[bo + t]; idxp_l[t] = idxpG[bo + t]; fin_l[t] = finG[bo + t]; }
  for (int idx = t; idx < 32 * n; idx += 512) {
    int r = idx >> ln2, c = idx & (n - 1);
    QT[r * LDB + c] = Qin[(size_t)(rbase + r) * 128 + bo + c];
  }
  __syncthreads();
  int K = Ksh;
  for (int idx = t; idx < (K << 7); idx += 512) {
    int k = idx >> 7, j = idx & 127;
    ST[k * LDB + j] = Sg[(size_t)(bo + k) * 128 + bo + j];
  }
  for (int r = 0; r < 32; ++r)
    if (t < K) QC[r * LDB + t] = QT[r * LDB + und_l[t]];
  __syncthreads();
  for (int idx = t; idx < 32 * n; idx += 512) {
    int r = idx >> ln2, j = idx & (n - 1);
    float v;
    if (j < K) {
      float a0 = 0.f, a1 = 0.f, a2 = 0.f, a3 = 0.f;
      int k = 0;
      for (; k + 3 < K; k += 4) {
        a0 += QC[r * LDB + k]     * ST[k * LDB + j];
        a1 += QC[r * LDB + k + 1] * ST[(k + 1) * LDB + j];
        a2 += QC[r * LDB + k + 2] * ST[(k + 2) * LDB + j];
        a3 += QC[r * LDB + k + 3] * ST[(k + 3) * LDB + j];
      }
      for (; k < K; ++k) a0 += QC[r * LDB + k] * ST[k * LDB + j];
      v = (a0 + a1) + (a2 + a3);
    } else {
      v = QT[r * LDB + idxp_l[n - 1 - (j - K)]];
    }
    WT[r * LDB + j] = v;
  }
  __syncthreads();
  for (int idx = t; idx < 32 * 128; idx += 512) {
    int r = idx >> 7, c = idx & 127;
    int cl = c - bo;
    float v = 0.f;
    if (cl >= 0 && cl < n) v = WT[r * LDB + fin_l[cl]];
    Qout[(size_t)(rbase + r) * 128 + c] = v;
  }
}

// ============ K4: back-transform + outputs ============
// v2: 1024 threads, 16 waves; Q register-resident, barrier-free reflector loop.
__global__ __launch_bounds__(1024) void k_back(
    float* __restrict__ wsG, const unsigned char* __restrict__ nodemask,
    const float* __restrict__ mu, const float* __restrict__ isg,
    float* __restrict__ wsUt, float* __restrict__ wsLam,
    float* __restrict__ outEmb, float* __restrict__ outLmask) {
  const int b = blockIdx.x, t = threadIdx.x;
  float* base = wsG + (size_t)b * WS_STRIDE;
  float* Qg = base + OFF_Q1;
  float* dvg = base + OFF_DV;
  float* tg = base + OFF_TAU;
  float* og = base + OFF_ORG;
  extern __shared__ float lds[];
  float* At = lds;                 // [128][LDT]: At[c*LDT+r] = Aref[r][c]
  float* Qt = lds + 128 * LDT;     // [128][LDT]: Qt[c*LDT+r] = Q[r][c]
  __shared__ float d_[128], tau_[128];
  __shared__ unsigned char nm_[128];

  float orgnrm = og[0];
  for (int idx = t; idx < 16384; idx += 1024) {
    int r = idx >> 7, c = idx & 127;
    At[c * LDT + r] = base[idx];   // Aref transpose-staged
    Qt[c * LDT + r] = Qg[idx];
  }
  if (t < 128) {
    d_[t] = dvg[t] * orgnrm;
    tau_[t] = tg[t];
    nm_[t] = nodemask[b * 128 + t];
  }
  __syncthreads();

  // ---- register-resident back-transform ----
  const int w = t >> 6, l = t & 63;
  const int cidx = l & 7, sg = l >> 3;
  const int c = w * 8 + cidx;
  float q[16];
  #pragma unroll
  for (int k = 0; k < 4; ++k) {
    float4 v = *(const float4*)&Qt[c * LDT + 4 * sg + 32 * k];
    q[4 * k + 0] = v.x; q[4 * k + 1] = v.y; q[4 * k + 2] = v.z; q[4 * k + 3] = v.w;
  }
  for (int i = 126; i >= 0; --i) {
    float taui = tau_[i];
    if (taui == 0.0f) continue;     // uniform branch
    const int lo = i + 1;
    float a[16];
    float dot = 0.0f;
    #pragma unroll
    for (int k = 0; k < 4; ++k) {
      if (32 * k + 31 >= lo) {      // uniform chunk guard
        float4 av = *(const float4*)&At[i * LDT + 4 * sg + 32 * k];
        {
          int r = 4 * sg + 32 * k;
          float aj;
          aj = (r == lo) ? 1.0f : ((r > lo) ? av.x : 0.0f); a[4*k+0] = aj; dot += aj * q[4*k+0]; r++;
          aj = (r == lo) ? 1.0f : ((r > lo) ? av.y : 0.0f); a[4*k+1] = aj; dot += aj * q[4*k+1]; r++;
          aj = (r == lo) ? 1.0f : ((r > lo) ? av.z : 0.0f); a[4*k+2] = aj; dot += aj * q[4*k+2]; r++;
          aj = (r == lo) ? 1.0f : ((r > lo) ? av.w : 0.0f); a[4*k+3] = aj; dot += aj * q[4*k+3];
        }
      }
    }
    dot += __shfl_xor(dot, 8);
    dot += __shfl_xor(dot, 16);
    dot += __shfl_xor(dot, 32);
    float wv = taui * dot;
    #pragma unroll
    for (int k = 0; k < 4; ++k) {
      if (32 * k + 31 >= lo) {
        q[4*k+0] -= a[4*k+0] * wv;
        q[4*k+1] -= a[4*k+1] * wv;
        q[4*k+2] -= a[4*k+2] * wv;
        q[4*k+3] -= a[4*k+3] * wv;
      }
    }
  }
  #pragma unroll
  for (int k = 0; k < 4; ++k) {
    float4 v;
    v.x = q[4*k+0]; v.y = q[4*k+1]; v.z = q[4*k+2]; v.w = q[4*k+3];
    *(float4*)&Qt[c * LDT + 4 * sg + 32 * k] = v;
  }
  __syncthreads();

  // ---- outputs ----
  if (t < NL) {
    float lam = d_[t + 1];
    wsLam[b * NL + t] = lam;
    outLmask[b * NL + t] = (fabsf(lam) < 1e-4f) ? 1.f : 0.f;
  }
  for (int idx = t; idx < NL * 128; idx += 1024) {
    int ll = idx >> 7, nn2 = idx & 127;
    float lam = d_[ll + 1];
    float vv = Qt[(ll + 1) * LDT + nn2];   // Q[nn2][ll+1]
    if (fabsf(lam) < 1e-4f || nm_[nn2]) vv = 0.f;
    wsUt[(size_t)(b * NL + ll) * 128 + nn2] = vv;
  }
  for (int idx = t; idx < NL * NH; idx += 1024) {
    int ll = idx >> 7, h = idx & 127;
    float lam = d_[ll + 1];
    float sq = sqrtf(fmaxf(lam, 0.f));
    float dd = (sq - mu[h]) * isg[h];
    outEmb[(size_t)(b * NL + ll) * NH + h] = expf(-dd * dd);
  }
}

// ---------------- Xh = X*Wx + bx (masked) + nodemask passthrough ----------------
__global__ __launch_bounds__(256) void k_xh(
    const float* __restrict__ X, const unsigned char* __restrict__ nodemask,
    const float* __restrict__ Wx, const float* __restrict__ bx,
    float* __restrict__ outXh, float* __restrict__ outNm) {
  int idx = blockIdx.x * 256 + threadIdx.x;
  int h = idx & 127;
  int bn = idx >> 7;
  const float* xr = X + (size_t)bn * NDX;
  float acc = bx[h];
  #pragma unroll
  for (int d = 0; d < NDX; ++d) acc += xr[d] * Wx[d * NH + h];
  outXh[idx] = nodemask[bn] ? 0.f : acc;
  if (idx < NBATCH * NN) outNm[idx] = nodemask[idx] ? 1.f : 0.f;
}

// ---------------- Uc = (A x_d W_edge + b_edge) contracted with U ----------------
__global__ __launch_bounds__(256) void k_uc(
    const float* __restrict__ A, const unsigned char* __restrict__ nodemask,
    const float* __restrict__ We, const float* __restrict__ be,
    const float* __restrict__ wsUt, float* __restrict__ outUc) {
  int b = blockIdx.x >> 4;
  int ng = blockIdx.x & 15;
  int t = threadIdx.x;
  __shared__ float Uts[NL * 129];
  __shared__ float Ssh[NL];
  __shared__ float Wsh[NDE * NH];
  __shared__ float bsh[NH];
  __shared__ float Ar[NN * NDE];
  __shared__ float Tp[2 * NL * NDE];
  __shared__ float Ts[NL * NDE];
  for (int idx = t; idx < NL * NN; idx += 256) {
    int l = idx >> 7, n = idx & 127;
    Uts[l * 129 + n] = wsUt[(size_t)b * NL * NN + idx];
  }
  for (int idx = t; idx < NDE * NH; idx += 256) Wsh[idx] = We[idx];
  if (t < NH) bsh[t] = be[t];
  __syncthreads();
  if (t < NL) {
    float s = 0.f;
    for (int n = 0; n < NN; ++n) s += Uts[t * 129 + n];
    Ssh[t] = s;
  }
  __syncthreads();
  for (int nn = 0; nn < 8; ++nn) {
    int n = ng * 8 + nn;
    for (int idx = t; idx < NN * NDE; idx += 256)
      Ar[idx] = A[(size_t)(b * NN + n) * NN * NDE + idx];
    __syncthreads();
    {
      int l = t & 127, half = t >> 7;
      if (l < NL) {
        float a0 = 0.f, a1 = 0.f, a2 = 0.f, a3 = 0.f;
        for (int m = 64 * half; m < 64 * half + 64; ++m) {
          float u = Uts[l * 129 + m];
          a0 += Ar[m * 4 + 0] * u;
          a1 += Ar[m * 4 + 1] * u;
          a2 += Ar[m * 4 + 2] * u;
          a3 += Ar[m * 4 + 3] * u;
        }
        int base = (half * NL + l) * 4;
        Tp[base + 0] = a0; Tp[base + 1] = a1; Tp[base + 2] = a2; Tp[base + 3] = a3;
      }
    }
    __syncthreads();
    for (int idx = t; idx < NL * NDE; idx += 256) Ts[idx] = Tp[idx] + Tp[NL * NDE + idx];
    __syncthreads();
    bool mn = nodemask[b * NN + n] != 0;
    {
      int h = t & 127, lh = t >> 7;
      float w0 = Wsh[0 * NH + h], w1 = Wsh[1 * NH + h], w2 = Wsh[2 * NH + h], w3 = Wsh[3 * NH + h];
      float bb = bsh[h];
      for (int l = lh; l < NL; l += 2) {
        float v = w0 * Ts[l * 4 + 0] + w1 * Ts[l * 4 + 1] + w2 * Ts[l * 4 + 2] +
                  w3 * Ts[l * 4 + 3] + bb * Ssh[l];
        outUc[(size_t)((b * NN + n) * NL + l) * NH + h] = mn ? 0.f : v;
      }
    }
    __syncthreads();
  }
}

extern "C" void kernel_launch(void* const* d_in, const int* in_sizes, int n_in,
                              void* d_out, int out_size, void* d_ws, size_t ws_size,
                              hipStream_t stream) {
  const float* A = (const float*)d_in[0];
  const float* X = (const float*)d_in[1];
  const unsigned char* nodemask = (const unsigned char*)d_in[2];
  const float* We = (const float*)d_in[3];
  const float* be = (const float*)d_in[4];
  const float* Wx = (const float*)d_in[5];
  const float* bx = (const float*)d_in[6];
  const float* mu = (const float*)d_in[7];
  const float* isg = (const float*)d_in[8];

  float* out = (float*)d_out;
  float* outEmb = out;                   // 16*127*128
  float* outLmask = out + 260096;        // 16*127
  float* outUc = out + 262128;           // 16*128*127*128
  float* outXh = out + 33554416;         // 16*128*128
  float* outNm = out + 33816560;         // 16*128

  float* wsG = (float*)d_ws;                           // 16 * 66560 floats ≈ 4.26 MB
  float* wsUt = (float*)((char*)d_ws + 4456448);       // 16*127*128 floats
  float* wsLam = wsUt + 260096;

  size_t lds1 = (size_t)128 * LDA * sizeof(float);       // 67584
  size_t lds2 = (size_t)2 * 128 * LDT * sizeof(float);   // 135168
  size_t ldsB = (size_t)(3 * 32 * LDB + 128 * LDB) * sizeof(float);  // 115584

  k_tridiag<<<NBATCH, 512, lds1, stream>>>(A, wsG);
  k_leaves<<<NBATCH * 8, 64, 0, stream>>>(wsG);
  k_mergeA<0><<<NBATCH * 4, 1024, 0, stream>>>(wsG, OFF_Q0);
  k_mergeB<<<NBATCH * 4, 512, ldsB, stream>>>(wsG, 0, OFF_Q0, OFF_Q1);
  k_mergeA<1><<<NBATCH * 2, 1024, 0, stream>>>(wsG, OFF_Q1);
  k_mergeB<<<NBATCH * 4, 512, ldsB, stream>>>(wsG, 1, OFF_Q1, OFF_Q0);
  k_mergeA<2><<<NBATCH * 1, 1024, 0, stream>>>(wsG, OFF_Q0);
  k_mergeB<<<NBATCH * 4, 512, ldsB, stream>>>(wsG, 2, OFF_Q0, OFF_Q1);
  k_back<<<NBATCH, 1024, lds2, stream>>>(wsG, nodemask, mu, isg, wsUt, wsLam, outEmb, outLmask);
  k_xh<<<(NBATCH * NN * NH) / 256, 256, 0, stream>>>(X, nodemask, Wx, bx, outXh, outNm);
  k_uc<<<NBATCH * 16, 256, 0, stream>>>(A, nodemask, We, be, wsUt, outUc);
}

// Round 13
// 907.637 us; speedup vs baseline: 1.0673x; 1.0092x over previous
//
#include <hip/hip_runtime.h>

#define NBATCH 16
#define NN 128
#define NH 128
#define NL 127
#define NDX 11
#define NDE 4
#define LDA 132
#define LDB 129
#define LDT 132
#define WS_STRIDE 66560  // floats per batch in wsG

// per-batch workspace float offsets
#define OFF_AREF 0
#define OFF_Q0   16384
#define OFF_Q1   32768
#define OFF_S    49152
#define OFF_DV   65536
#define OFF_EV   65664
#define OFF_TAU  65792
#define OFF_ORG  65920
#define OFF_META 66048   // 512 floats of int metadata

// ---------------- LAPACK fp32 helper ports ----------------
#define EPS32 5.9604645e-8f
#define EPS232 3.5527137e-15f
#define SAFMIN32 1.17549435e-38f

__device__ __forceinline__ float ssign_(float a, float b) {
  return (b >= 0.0f) ? fabsf(a) : -fabsf(a);
}
__device__ __forceinline__ float slapy2_(float x, float y) {
  float ax = fabsf(x), ay = fabsf(y);
  float w = fmaxf(ax, ay), z = fminf(ax, ay);
  if (z == 0.0f) return w;
  float q = z / w;
  return w * sqrtf(1.0f + q * q);
}

// broadcast-read lane `src`'s value of v (uniform src -> v_readlane, scalar pipe)
__device__ __forceinline__ float rdl(float v, int src) {
  return __int_as_float(__builtin_amdgcn_readlane(__float_as_int(v), src));
}

__device__ void slartg_(float f, float g, float* c, float* s, float* r) {
  if (g == 0.0f) { *c = 1.0f; *s = 0.0f; *r = f; }
  else if (f == 0.0f) { *c = 0.0f; *s = (g >= 0.0f) ? 1.0f : -1.0f; *r = fabsf(g); }
  else {
    float d = sqrtf(f * f + g * g);
    d = (f >= 0.0f) ? d : -d;
    *c = f / d; *s = g / d; *r = d;
  }
}

__device__ void slaev2_(float a, float b, float c0, float* rt1, float* rt2,
                        float* cs1, float* sn1) {
  float sm = a + c0, df = a - c0, adf = fabsf(df), tb = b + b, ab = fabsf(tb);
  float acmx, acmn;
  if (fabsf(a) > fabsf(c0)) { acmx = a; acmn = c0; } else { acmx = c0; acmn = a; }
  float rt;
  if (adf > ab) { float q = ab / adf; rt = adf * sqrtf(1.0f + q * q); }
  else if (adf < ab) { float q = adf / ab; rt = ab * sqrtf(1.0f + q * q); }
  else rt = ab * sqrtf(2.0f);
  int sgn1;
  if (sm < 0.0f) { *rt1 = 0.5f * (sm - rt); sgn1 = -1; *rt2 = (acmx / *rt1) * acmn - (b / *rt1) * b; }
  else if (sm > 0.0f) { *rt1 = 0.5f * (sm + rt); sgn1 = 1; *rt2 = (acmx / *rt1) * acmn - (b / *rt1) * b; }
  else { *rt1 = 0.5f * rt; *rt2 = -0.5f * rt; sgn1 = 1; }
  int sgn2; float cs;
  if (df >= 0.0f) { cs = df + rt; sgn2 = 1; } else { cs = df - rt; sgn2 = -1; }
  float acs = fabsf(cs);
  if (acs > ab) { float ct = -tb / cs; *sn1 = 1.0f / sqrtf(1.0f + ct * ct); *cs1 = ct * (*sn1); }
  else {
    if (ab == 0.0f) { *cs1 = 1.0f; *sn1 = 0.0f; }
    else { float tn = -cs / tb; *cs1 = 1.0f / sqrtf(1.0f + tn * tn); *sn1 = tn * (*cs1); }
  }
  if (sgn1 == sgn2) { float tn = *cs1; *cs1 = -(*sn1); *sn1 = tn; }
}

// ============ K1: Laplacian build + ssytd2 tridiagonalization ============
// v7 (R10, measured best 325us): 512 threads, R9 4-barrier schedule,
// LDA=132, shfl readbacks.
__global__ __launch_bounds__(512) void k_tridiag(const float* __restrict__ A_in,
                                                 float* __restrict__ wsG) {
  const int b = blockIdx.x, t = threadIdx.x;
  float* Aref = wsG + (size_t)b * WS_STRIDE;
  float* dv = Aref + OFF_DV;
  float* ev = Aref + OFF_EV;
  float* tg = Aref + OFF_TAU;
  float* og = Aref + OFF_ORG;
  extern __shared__ float As[];  // [128][LDA], LDA=132
  __shared__ unsigned int maskp[128][4];
  __shared__ unsigned int Dp[128][4];
  __shared__ unsigned long long adj0_[128], adj1_[128];
  __shared__ float Dd_[128], tDs_[128];
  __shared__ float d_[128], e_[128], tau_[128];
  __shared__ alignas(16) float v_[128];
  __shared__ alignas(16) float w_[128];
  __shared__ float pmat[4][128];
  __shared__ alignas(16) float red_[16];
  __shared__ float xp[16];

  const int wid = t >> 6;        // wave id 0..7
  const int lane = t & 63;
  // ---- adjacency build: 4 threads per row, 32 m's each ----
  {
    const int r8 = t >> 2, s8 = t & 3;
    const float4* Arow = (const float4*)(A_in + (size_t)(b * 128 + r8) * 128 * 4);
    unsigned int mloc = 0; unsigned int cnt = 0;
    const int m0 = s8 * 32;
    #pragma unroll 4
    for (int mm = 0; mm < 32; ++mm) {
      float4 a = Arow[m0 + mm];
      if (a.x != 0.f || a.y != 0.f || a.z != 0.f || a.w != 0.f) { mloc |= 1u << mm; cnt++; }
    }
    maskp[r8][s8] = mloc; Dp[r8][s8] = cnt;
  }
  __syncthreads();
  if (t < 128) {
    unsigned long long b0 = (unsigned long long)maskp[t][0] |
                            ((unsigned long long)maskp[t][1] << 32);
    unsigned long long b1 = (unsigned long long)maskp[t][2] |
                            ((unsigned long long)maskp[t][3] << 32);
    unsigned int D = Dp[t][0] + Dp[t][1] + Dp[t][2] + Dp[t][3];
    adj0_[t] = b0; adj1_[t] = b1;
    float Df = (float)D;
    Dd_[t] = Df;
    tDs_[t] = 1.0f / sqrtf(fmaxf(Df, 1.0f));
  }
  __syncthreads();
  for (int idx = t; idx < 16384; idx += 512) {
    int r = idx >> 7, c = idx & 127;
    if (c <= r) {
      float adj = (float)((c < 64 ? (adj0_[r] >> c) : (adj1_[r] >> (c - 64))) & 1ull);
      float Lrc = ((c == r) ? Dd_[r] : 0.0f) - adj;
      float val = (tDs_[c] * Lrc) * tDs_[r];
      As[r * LDA + c] = val;
      As[c * LDA + r] = val;
    }
  }
  __syncthreads();

  const int rmv = t & 127;   // matvec row
  const int smv = t >> 7;    // matvec segment 0..3 (32 cols each)
  const int ucg = t & 31;    // update col-group (4 cols)
  const int urs = t >> 5;    // update row stripe 0..15

  bool usexp = false;
  for (int i = 0; i < 127; ++i) {
    const int lo = i + 1;
    // ---- xnorm2 of column i below subdiagonal ----
    float xnorm2;
    if (!usexp) {           // uniform fallback path (iter 0 / after taui==0)
      float part = 0.0f;
      if (t < 128 && t >= i + 2) { float x = As[t * LDA + i]; part = x * x; }
      if (wid < 2) {
        #pragma unroll
        for (int m = 1; m < 64; m <<= 1) part += __shfl_xor(part, m);
        if (lane == 0) red_[wid] = part;
      }
      __syncthreads();   // S1 (fallback only)
      xnorm2 = red_[0] + red_[1];
    } else {               // piggybacked: 1 LDS read + shfl tree (sum of 16)
      float s = xp[lane & 15];
      #pragma unroll
      for (int m = 1; m < 16; m <<= 1) s += __shfl_xor(s, m);
      xnorm2 = s;
    }
    float alpha = As[lo * LDA + i];   // row lo never written in phase B
    float beta, taui, scal;
    if (xnorm2 == 0.0f) { taui = 0.0f; beta = alpha; scal = 0.0f; }
    else {
      float xn = sqrtf(xnorm2);
      beta = -ssign_(slapy2_(alpha, xn), alpha);
      taui = (beta - alpha) / beta;
      scal = 1.0f / (alpha - beta);
    }
    if (t == 0) { e_[i] = beta; tau_[i] = taui; }
    if (taui != 0.0f) {    // uniform branch
      // ---- phase B: single-writer v construction ----
      if (t < 128) {
        float vv = 0.0f;
        if (t == lo) vv = 1.0f;
        else if (t > lo) { float xi = As[t * LDA + i]; vv = xi * scal; As[t * LDA + i] = vv; }
        v_[t] = vv;
      }
      __syncthreads();   // S2
      // ---- phase C: matvec partials (32-col chunk) + vpdot partial ----
      const int c0 = smv * 32;
      float acc = 0.0f;
      if (c0 + 31 >= lo && rmv >= lo) {
        const float4* Ar = (const float4*)&As[rmv * LDA + c0];
        const float4* Vr = (const float4*)&v_[c0];
        #pragma unroll
        for (int k = 0; k < 8; ++k) {
          float4 a = Ar[k], v4 = Vr[k];
          acc += a.x * v4.x + a.y * v4.y + a.z * v4.z + a.w * v4.w;
        }
      }
      pmat[smv][rmv] = acc;
      float p2 = v_[rmv] * acc;
      #pragma unroll
      for (int m = 1; m < 64; m <<= 1) p2 += __shfl_xor(p2, m);
      if (lane == 0) red_[wid] = p2;
      __syncthreads();   // S3
      // ---- phase D: w = taui*(Av); a2 via shfl-sum of red_[0..7] ----
      float vpr = red_[lane & 7];
      #pragma unroll
      for (int m = 1; m < 8; m <<= 1) vpr += __shfl_xor(vpr, m);
      float a2 = -0.5f * taui * (taui * vpr);
      if (t < 128) {
        float pv = pmat[0][t] + pmat[1][t] + pmat[2][t] + pmat[3][t];
        w_[t] = taui * pv;
      }
      __syncthreads();   // S4
      // ---- phase E: rank-2 update + next-xnorm piggyback ----
      const int uc0 = ucg * 4;
      if (uc0 + 3 >= lo) {
        float4 vc = *(const float4*)&v_[uc0];
        float4 wc = *(const float4*)&w_[uc0];
        float pcx = wc.x + a2 * vc.x;
        float pcy = wc.y + a2 * vc.y;
        float pcz = wc.z + a2 * vc.z;
        float pcw = wc.w + a2 * vc.w;
        if (uc0 < lo) {   // partial chunk: neutralize components left of lo
          if (uc0 + 0 < lo) { vc.x = 0.f; pcx = 0.f; }
          if (uc0 + 1 < lo) { vc.y = 0.f; pcy = 0.f; }
          if (uc0 + 2 < lo) { vc.z = 0.f; pcz = 0.f; }
        }
        const bool isxcol = (ucg == (lo >> 2));
        const int xc = lo & 3;
        float xpacc = 0.0f;
        #pragma unroll
        for (int k = 0; k < 8; ++k) {
          int r = urs + 16 * k;
          if (r >= lo) {
            float vr = v_[r];
            float pr = w_[r] + a2 * vr;
            float4 a = *(const float4*)&As[r * LDA + uc0];
            a.x -= vr * pcx + pr * vc.x;
            a.y -= vr * pcy + pr * vc.y;
            a.z -= vr * pcz + pr * vc.z;
            a.w -= vr * pcw + pr * vc.w;
            *(float4*)&As[r * LDA + uc0] = a;
            if (isxcol && r >= lo + 2) {
              float nc = (xc == 0) ? a.x : ((xc == 1) ? a.y : ((xc == 2) ? a.z : a.w));
              xpacc += nc * nc;
            }
          }
        }
        if (isxcol) xp[urs] = xpacc;
      }
    }
    __syncthreads();   // S5
    usexp = (taui != 0.0f);
  }
  if (t < 128) d_[t] = As[t * LDA + t];
  __syncthreads();

  {
    float mx = 0.0f;
    if (t < 128) mx = fabsf(d_[t]);
    if (t < 127) mx = fmaxf(mx, fabsf(e_[t]));
    if (wid < 2) {
      #pragma unroll
      for (int m = 1; m < 64; m <<= 1) mx = fmaxf(mx, __shfl_xor(mx, m));
      if (lane == 0) red_[wid] = mx;
    }
    __syncthreads();
  }
  float orgnrm = fmaxf(red_[0], red_[1]);
  if (orgnrm == 0.0f) orgnrm = 1.0f;
  float invnrm = 1.0f / orgnrm;
  if (t < 128) d_[t] *= invnrm;
  if (t < 127) e_[t] *= invnrm;
  __syncthreads();
  if (t == 0) {
    for (int bm = 16; bm < 128; bm += 16) {
      float ae = fabsf(e_[bm - 1]);
      d_[bm - 1] -= ae; d_[bm] -= ae;
    }
  }
  __syncthreads();
  for (int idx = t; idx < 16384; idx += 512)
    Aref[idx] = As[(idx >> 7) * LDA + (idx & 127)];
  if (t < 128) { dv[t] = d_[t]; tg[t] = tau_[t]; }
  if (t < 127) ev[t] = e_[t];
  if (t == 0) og[0] = orgnrm;
}

// ============ K2: 8 leaves x 16 batches, one block each ============
// v3: lane-register ssteqr (readlane broadcasts); band-limited Q0 write.
__global__ __launch_bounds__(64) void k_leaves(float* __restrict__ wsG) {
  int b = blockIdx.x >> 3, lf = blockIdx.x & 7;
  float* base = wsG + (size_t)b * WS_STRIDE;
  float* Qg = base + OFF_Q0;
  float* dv = base + OFF_DV;
  float* ev = base + OFF_EV;
  const int ln = threadIdx.x;
  __shared__ float zsh[16 * 17];

  const int n = 16;
  float dreg = (ln < 16) ? dv[lf * 16 + ln] : 0.f;
  float ereg = (ln < 15) ? ev[lf * 16 + ln] : 0.f;
  float csreg = 0.f, snreg = 0.f;
  float zr[16];
  #pragma unroll
  for (int c = 0; c < 16; ++c) zr[c] = (ln == c) ? 1.0f : 0.0f;

  {
    const float eps = EPS32, eps2 = EPS232, safmin = SAFMIN32;
    int nmaxit = n * 30, jtot = 0;
    int l1 = 0;
    while (l1 <= n - 1) {
      if (l1 > 0 && ln == l1 - 1) ereg = 0.0f;
      int m;
      for (m = l1; m <= n - 2; ++m) {
        float tst = fabsf(rdl(ereg, m));
        if (tst == 0.0f) break;
        if (tst <= (sqrtf(fabsf(rdl(dreg, m))) * sqrtf(fabsf(rdl(dreg, m + 1)))) * eps) {
          if (ln == m) ereg = 0.0f;
          break;
        }
      }
      int l = l1, lend = m;
      l1 = m + 1;
      if (lend == l) continue;
      {
        float an = 0.0f;
        for (int i = l; i <= lend; ++i) an = fmaxf(an, fabsf(rdl(dreg, i)));
        for (int i = l; i <= lend - 1; ++i) an = fmaxf(an, fabsf(rdl(ereg, i)));
        if (an == 0.0f) continue;
      }
      if (fabsf(rdl(dreg, lend)) < fabsf(rdl(dreg, l))) { int tsw = l; l = lend; lend = tsw; }
      if (lend > l) {
        while (true) {  // QL
          int m2;
          if (l != lend) {
            for (m2 = l; m2 <= lend - 1; ++m2) {
              float em = rdl(ereg, m2);
              float tst = em * em;
              if (tst <= (eps2 * fabsf(rdl(dreg, m2))) * fabsf(rdl(dreg, m2 + 1)) + safmin) break;
            }
          } else m2 = lend;
          if (m2 < lend && ln == m2) ereg = 0.0f;
          float p = rdl(dreg, l);
          if (m2 == l) { l++; if (l <= lend) continue; else break; }
          if (m2 == l + 1) {
            float rt1, rt2, c, s;
            slaev2_(rdl(dreg, l), rdl(ereg, l), rdl(dreg, l + 1), &rt1, &rt2, &c, &s);
            #pragma unroll
            for (int j = 0; j < 15; ++j) {
              if (j == l) {
                float t1 = zr[j + 1];
                zr[j + 1] = c * t1 - s * zr[j];
                zr[j] = s * t1 + c * zr[j];
              }
            }
            if (ln == l) { dreg = rt1; ereg = 0.0f; }
            if (ln == l + 1) dreg = rt2;
            l += 2; if (l <= lend) continue; else break;
          }
          if (jtot == nmaxit) break;
          jtot++;
          float g = (rdl(dreg, l + 1) - p) / (2.0f * rdl(ereg, l));
          float r = slapy2_(g, 1.0f);
          g = rdl(dreg, m2) - p + rdl(ereg, l) / (g + ssign_(r, g));
          float s = 1.0f, c = 1.0f; p = 0.0f;
          for (int i = m2 - 1; i >= l; --i) {
            float ei = rdl(ereg, i);
            float f = s * ei, bb = c * ei;
            slartg_(g, f, &c, &s, &r);
            if (i != m2 - 1 && ln == i + 1) ereg = r;
            g = rdl(dreg, i + 1) - p;
            r = (rdl(dreg, i) - g) * s + 2.0f * c * bb;
            p = s * r;
            if (ln == i + 1) dreg = g + p;
            g = c * r - bb;
            if (ln == i) { csreg = c; snreg = -s; }
          }
          #pragma unroll
          for (int j = 14; j >= 0; --j) {
            if (j <= m2 - 1 && j >= l) {
              float cj = rdl(csreg, j), sj = rdl(snreg, j);
              float t1 = zr[j + 1];
              zr[j + 1] = cj * t1 - sj * zr[j];
              zr[j] = sj * t1 + cj * zr[j];
            }
          }
          if (ln == l) { dreg = dreg - p; ereg = g; }
        }
      } else {
        while (true) {  // QR
          int m2;
          if (l != lend) {
            for (m2 = l; m2 >= lend + 1; --m2) {
              float em = rdl(ereg, m2 - 1);
              float tst = em * em;
              if (tst <= (eps2 * fabsf(rdl(dreg, m2))) * fabsf(rdl(dreg, m2 - 1)) + safmin) break;
            }
          } else m2 = lend;
          if (m2 > lend && ln == m2 - 1) ereg = 0.0f;
          float p = rdl(dreg, l);
          if (m2 == l) { l--; if (l >= lend) continue; else break; }
          if (m2 == l - 1) {
            float rt1, rt2, c, s;
            slaev2_(rdl(dreg, l - 1), rdl(ereg, l - 1), rdl(dreg, l), &rt1, &rt2, &c, &s);
            #pragma unroll
            for (int j = 0; j < 15; ++j) {
              if (j == l - 1) {
                float t1 = zr[j + 1];
                zr[j + 1] = c * t1 - s * zr[j];
                zr[j] = s * t1 + c * zr[j];
              }
            }
            if (ln == l - 1) { dreg = rt1; ereg = 0.0f; }
            if (ln == l) dreg = rt2;
            l -= 2; if (l >= lend) continue; else break;
          }
          if (jtot == nmaxit) break;
          jtot++;
          float g = (rdl(dreg, l - 1) - p) / (2.0f * rdl(ereg, l - 1));
          float r = slapy2_(g, 1.0f);
          g = rdl(dreg, m2) - p + rdl(ereg, l - 1) / (g + ssign_(r, g));
          float s = 1.0f, c = 1.0f; p = 0.0f;
          for (int i = m2; i <= l - 1; ++i) {
            float ei = rdl(ereg, i);
            float f = s * ei, bb = c * ei;
            slartg_(g, f, &c, &s, &r);
            if (i != m2 && ln == i - 1) ereg = r;
            g = rdl(dreg, i) - p;
            r = (rdl(dreg, i + 1) - g) * s + 2.0f * c * bb;
            p = s * r;
            if (ln == i) dreg = g + p;
            g = c * r - bb;
            if (ln == i) { csreg = c; snreg = s; }
          }
          #pragma unroll
          for (int j = 0; j <= 14; ++j) {
            if (j >= m2 && j <= l - 1) {
              float cj = rdl(csreg, j), sj = rdl(snreg, j);
              float t1 = zr[j + 1];
              zr[j + 1] = cj * t1 - sj * zr[j];
              zr[j] = sj * t1 + cj * zr[j];
            }
          }
          if (ln == l) dreg = dreg - p;
          if (ln == l - 1) ereg = g;
        }
      }
    }
  }

  // stage z rows to LDS for sort + band write
  if (ln < 16) {
    #pragma unroll
    for (int c = 0; c < 16; ++c) zsh[ln * 17 + c] = zr[c];
  }
  __syncthreads();
  // selection sort: d in lane registers, z column swaps row-parallel in LDS
  for (int ii = 1; ii <= n - 1; ++ii) {
    int i = ii - 1, k = i;
    float p = rdl(dreg, i);
    for (int j = ii; j <= n - 1; ++j) {
      float dj = rdl(dreg, j);
      if (dj < p) { k = j; p = dj; }
    }
    if (k != i) {
      float di = rdl(dreg, i);
      if (ln == k) dreg = di;
      if (ln == i) dreg = p;
      if (ln < 16) {
        float t1 = zsh[ln * 17 + i];
        zsh[ln * 17 + i] = zsh[ln * 17 + k];
        zsh[ln * 17 + k] = t1;
      }
    }
  }
  __syncthreads();
  if (ln < 16) dv[lf * 16 + ln] = dreg;
  // write only the 32-col merge band: cols bo..bo+31 where bo=(lf>>1)*32
  {
    const int bo = (lf >> 1) * 32;
    const int cofs = (lf & 1) * 16;   // local col offset of this leaf in band
    for (int idx = ln; idx < 16 * 32; idx += 64) {
      int rr = idx >> 5, c = idx & 31;
      int cl = c - cofs;
      float v = (cl >= 0 && cl < 16) ? zsh[rr * 17 + cl] : 0.f;
      Qg[(size_t)(lf * 16 + rr) * 128 + bo + c] = v;
    }
  }
}

// ============ K3a: merge metadata/secular per (batch, merge) ============
// v3: register bisection 36 iters.
template <int LVL>
__global__ __launch_bounds__(1024) void k_mergeA(float* __restrict__ wsG, int qoff) {
  constexpr int sh = 2 - LVL;
  constexpr int nm = 32 << LVL;     // merged size n
  constexpr int LPR = 1024 / nm;    // lanes per root: 32/16/8
  constexpr int NCH = nm / LPR;     // chunk regs per lane: 1/4/16
  int b = blockIdx.x >> sh;
  int mg = blockIdx.x & ((1 << sh) - 1);
  int bo = mg * nm, n1 = nm >> 1, n = nm;
  const int t = threadIdx.x;
  float* base = wsG + (size_t)b * WS_STRIDE;
  float* Qin = base + qoff;
  float* dvg = base + OFF_DV;
  float* evg = base + OFF_EV;
  float* Sg  = base + OFF_S;
  int* meta = (int*)(base + OFF_META);
  int* undG = meta; int* idxpG = meta + 128; int* finG = meta + 256; int* KfG = meta + 384;

  __shared__ float d_[128], z_[128], dl_[128], w_[128], zh_[128], lam_[128], tauv_[128], dnew_[128];
  __shared__ int srt_[128], indxp_[128], und_[128], anc_[128], fin_[128];
  __shared__ int gp_[128], gq_[128];
  __shared__ float gc_[128], gs_[128];
  __shared__ int sci[4];

  if (t < n) d_[t] = dvg[bo + t];
  float rho_in = evg[bo + n1 - 1];
  if (t < n) {
    float zv = (t < n1) ? Qin[(size_t)(bo + n1 - 1) * 128 + bo + t]
                        : Qin[(size_t)(bo + n1) * 128 + bo + t];
    if (rho_in < 0.0f && t >= n1) zv = -zv;
    z_[t] = zv * 0.70710678f;
  }
  __syncthreads();
  float rho = fabsf(2.0f * rho_in);
  if (t == 0) {
    int i1 = 0, i2 = n1, k = 0;
    while (i1 < n1 && i2 < n) {
      if (d_[i1] <= d_[i2]) srt_[k++] = i1++; else srt_[k++] = i2++;
    }
    while (i1 < n1) srt_[k++] = i1++;
    while (i2 < n) srt_[k++] = i2++;
    float zmax = 0.0f, dmax = 0.0f;
    for (int i = 0; i < n; ++i) {
      zmax = fmaxf(zmax, fabsf(z_[i]));
      dmax = fmaxf(dmax, fabsf(d_[i]));
    }
    float tol = 8.0f * EPS32 * fmaxf(dmax, zmax);
    int K = 0, k2 = n, full = 0, ngiv = 0;
    if (rho * zmax <= tol) full = 1;
    else {
      int pj = -1, jj = 0;
      for (; jj < n; ++jj) {
        int nj = srt_[jj];
        if (rho * fabsf(z_[nj]) <= tol) { k2--; indxp_[k2] = nj; }
        else { pj = nj; break; }
      }
      if (pj < 0) full = 1;
      else {
        for (jj = jj + 1; jj < n; ++jj) {
          int nj = srt_[jj];
          if (rho * fabsf(z_[nj]) <= tol) { k2--; indxp_[k2] = nj; }
          else {
            float s = z_[pj], c = z_[nj];
            float tauq = slapy2_(c, s);
            float tdf = d_[nj] - d_[pj];
            c /= tauq; s = -s / tauq;
            if (fabsf(tdf * c * s) <= tol) {
              z_[nj] = tauq; z_[pj] = 0.0f;
              gp_[ngiv] = pj; gq_[ngiv] = nj; gc_[ngiv] = c; gs_[ngiv] = s; ngiv++;
              float tt2 = d_[pj] * c * c + d_[nj] * s * s;
              d_[nj] = d_[pj] * s * s + d_[nj] * c * c;
              d_[pj] = tt2;
              k2--;
              int pos = k2;
              while (pos + 1 <= n - 1 && d_[pj] < d_[indxp_[pos + 1]]) {
                indxp_[pos] = indxp_[pos + 1]; pos++;
              }
              indxp_[pos] = pj;
              pj = nj;
            } else {
              dl_[K] = d_[pj]; w_[K] = z_[pj]; und_[K] = pj; K++;
              pj = nj;
            }
          }
        }
        dl_[K] = d_[pj]; w_[K] = z_[pj]; und_[K] = pj; K++;
      }
    }
    sci[0] = K; sci[1] = full; sci[2] = ngiv;
  }
  __syncthreads();
  int K = sci[0], full = sci[1], ngiv = sci[2];
  if (!full) {
    // Givens rotations applied row-parallel to global Q (same per-row op order)
    if (t < n) {
      size_t rowoff = (size_t)(bo + t) * 128 + bo;
      for (int g = 0; g < ngiv; ++g) {
        float c = gc_[g], s = gs_[g];
        float xq = Qin[rowoff + gp_[g]], yq = Qin[rowoff + gq_[g]];
        Qin[rowoff + gp_[g]] = c * xq + s * yq;
        Qin[rowoff + gq_[g]] = c * yq - s * xq;
      }
    }
    // ---- lane-group secular solve: root j = t/LPR, sub-lane sub = t%LPR ----
    const int j = t / LPR;
    const int sub = t % LPR;
    const bool act = (j < K);
    float dl_loc[NCH], w2_loc[NCH];
    float tauj_reg = 0.0f; float da_reg = 0.0f;
    if (act) {
      #pragma unroll
      for (int k = 0; k < NCH; ++k) {
        int i = sub + k * LPR;
        if (i < K) { dl_loc[k] = dl_[i]; float wi = w_[i]; w2_loc[k] = rho * wi * wi; }
        else { dl_loc[k] = 3.0e38f; w2_loc[k] = 0.0f; }   // term -> 0, no NaN
      }
      // zsum (already rho-scaled)
      float zs = 0.0f;
      #pragma unroll
      for (int k = 0; k < NCH; ++k) zs += w2_loc[k];
      #pragma unroll
      for (int m = 1; m < LPR; m <<= 1) zs += __shfl_xor(zs, m);
      // anchor decision
      int a; float lo2, hi2;
      if (j < K - 1) {
        float dj = dl_[j];
        float tm = 0.5f * (dl_[j + 1] - dj);
        float fm = 0.0f;
        #pragma unroll
        for (int k = 0; k < NCH; ++k) fm += w2_loc[k] / ((dl_loc[k] - dj) - tm);
        #pragma unroll
        for (int m = 1; m < LPR; m <<= 1) fm += __shfl_xor(fm, m);
        fm += 1.0f;
        if (fm >= 0.0f) { a = j; lo2 = 0.0f; hi2 = tm; }
        else { a = j + 1; lo2 = -tm; hi2 = 0.0f; }
      } else { a = K - 1; lo2 = 0.0f; hi2 = zs + 1e-30f; }
      float da = dl_[a];
      float sdl[NCH];
      #pragma unroll
      for (int k = 0; k < NCH; ++k) sdl[k] = dl_loc[k] - da;
      for (int it2 = 0; it2 < 36; ++it2) {
        float tc = 0.5f * (lo2 + hi2);
        float f = 0.0f;
        #pragma unroll
        for (int k = 0; k < NCH; ++k) f += w2_loc[k] / (sdl[k] - tc);
        #pragma unroll
        for (int m = 1; m < LPR; m <<= 1) f += __shfl_xor(f, m);
        f += 1.0f;
        if (f >= 0.0f) hi2 = tc; else lo2 = tc;
      }
      tauj_reg = 0.5f * (lo2 + hi2);
      da_reg = da;
      if (sub == 0) { lam_[j] = da + tauj_reg; tauv_[j] = tauj_reg; anc_[j] = a; }
    }
    __syncthreads();
    // Gu's sign-preserving z-hat (root i = j of this octet; chunk over jj)
    if (act) {
      float di = dl_[j];
      float pp = 1.0f;
      #pragma unroll
      for (int k = 0; k < NCH; ++k) {
        int jj = sub + k * LPR;
        if (jj < K && jj != j) {
          float delta_ij = (di - dl_[anc_[jj]]) - tauv_[jj];
          pp *= delta_ij / (di - dl_[jj]);
        }
      }
      #pragma unroll
      for (int m = 1; m < LPR; m <<= 1) pp *= __shfl_xor(pp, m);
      if (sub == 0) {
        float lead = (di - da_reg) - tauj_reg;
        float acc = lead * pp;
        zh_[j] = ssign_(sqrtf(fmaxf(-acc, 0.0f)), w_[j]);
      }
    }
    __syncthreads();
    // rank-1 system eigenvectors, chunked per lane, single scaled store
    if (act) {
      float sv[NCH]; float nrm = 0.0f;
      #pragma unroll
      for (int k = 0; k < NCH; ++k) {
        int i = sub + k * LPR;
        float s = 0.0f;
        if (i < K) s = zh_[i] / ((dl_loc[k] - da_reg) - tauj_reg);
        sv[k] = s; nrm += s * s;
      }
      #pragma unroll
      for (int m = 1; m < LPR; m <<= 1) nrm += __shfl_xor(nrm, m);
      nrm = 1.0f / sqrtf(nrm);
      float* scol = Sg + bo + j;
      #pragma unroll
      for (int k = 0; k < NCH; ++k) {
        int i = sub + k * LPR;
        if (i < K) scol[(size_t)(bo + i) * 128] = sv[k] * nrm;
      }
    }
    if (t == 0) {
      for (int jj = 0; jj < K; ++jj) dnew_[jj] = lam_[jj];
      for (int m = 0; m < n - K; ++m) dnew_[K + m] = d_[indxp_[n - 1 - m]];
      int i1 = 0, i2 = K, k = 0;
      while (i1 < K && i2 < n) { if (dnew_[i1] <= dnew_[i2]) fin_[k++] = i1++; else fin_[k++] = i2++; }
      while (i1 < K) fin_[k++] = i1++;
      while (i2 < n) fin_[k++] = i2++;
    }
    __syncthreads();
    if (t < n) {
      dvg[bo + t] = dnew_[fin_[t]];
      idxpG[bo + t] = indxp_[t];
      finG[bo + t] = fin_[t];
    }
    if (t < K) undG[bo + t] = und_[t];
    if (t == 0) KfG[mg] = K;
  } else {
    if (t < n) {
      dvg[bo + t] = d_[srt_[t]];
      idxpG[bo + t] = srt_[n - 1 - t];
      finG[bo + t] = t;
    }
    if (t == 0) KfG[mg] = 0;
  }
}

// ============ K3b: merge GEMM/permute, 32 rows per block ============
// v2: 512 threads (8 waves = 2/SIMD).
__global__ __launch_bounds__(512) void k_mergeB(float* __restrict__ wsG, int lvl,
                                                int qinoff, int qoutoff) {
  int b = blockIdx.x >> 2;
  int rblk = blockIdx.x & 3;
  int rbase = rblk * 32;
  int nm = 32 << lvl;
  int ln2 = 5 + lvl;
  int mg = rbase >> ln2;
  int bo = mg * nm, n = nm;
  const int t = threadIdx.x;
  float* base = wsG + (size_t)b * WS_STRIDE;
  const float* Qin = base + qinoff;
  float* Qout = base + qoutoff;
  const float* Sg = base + OFF_S;
  const int* meta = (const int*)(base + OFF_META);
  const int* undG = meta; const int* idxpG = meta + 128;
  const int* finG = meta + 256; const int* KfG = meta + 384;

  extern __shared__ float lds[];
  float* QT = lds;                 // [32][LDB]
  float* QC = QT + 32 * LDB;       // [32][LDB]
  float* WT = QC + 32 * LDB;       // [32][LDB]
  float* ST = WT + 32 * LDB;       // [128][LDB]
  __shared__ int und_l[128], idxp_l[128], fin_l[128];
  __shared__ int Ksh;

  if (t == 0) Ksh = KfG[mg];
  if (t < n) { und_l[t] = undG[bo + t]; idxp_l[t] = idxpG[bo + t]; fin_l[t] = finG[bo + t]; }
  for (int idx = t; idx < 32 * n; idx += 512) {
    int r = idx >> ln2, c = idx & (n - 1);
    QT[r * LDB + c] = Qin[(size_t)(rbase + r) * 128 + bo + c];
  }
  __syncthreads();
  int K = Ksh;
  for (int idx = t; idx < (K << 7); idx += 512) {
    int k = idx >> 7, j = idx & 127;
    ST[k * LDB + j] = Sg[(size_t)(bo + k) * 128 + bo + j];
  }
  for (int r = 0; r < 32; ++r)
    if (t < K) QC[r * LDB + t] = QT[r * LDB + und_l[t]];
  __syncthreads();
  for (int idx = t; idx < 32 * n; idx += 512) {
    int r = idx >> ln2, j = idx & (n - 1);
    float v;
    if (j < K) {
      float a0 = 0.f, a1 = 0.f, a2 = 0.f, a3 = 0.f;
      int k = 0;
      for (; k + 3 < K; k += 4) {
        a0 += QC[r * LDB + k]     * ST[k * LDB + j];
        a1 += QC[r * LDB + k + 1] * ST[(k + 1) * LDB + j];
        a2 += QC[r * LDB + k + 2] * ST[(k + 2) * LDB + j];
        a3 += QC[r * LDB + k + 3] * ST[(k + 3) * LDB + j];
      }
      for (; k < K; ++k) a0 += QC[r * LDB + k] * ST[k * LDB + j];
      v = (a0 + a1) + (a2 + a3);
    } else {
      v = QT[r * LDB + idxp_l[n - 1 - (j - K)]];
    }
    WT[r * LDB + j] = v;
  }
  __syncthreads();
  for (int idx = t; idx < 32 * 128; idx += 512) {
    int r = idx >> 7, c = idx & 127;
    int cl = c - bo;
    float v = 0.f;
    if (cl >= 0 && cl < n) v = WT[r * LDB + fin_l[cl]];
    Qout[(size_t)(rbase + r) * 128 + c] = v;
  }
}

// ============ K4: back-transform + outputs ============
// v2: 1024 threads, 16 waves; Q register-resident, barrier-free reflector loop.
__global__ __launch_bounds__(1024) void k_back(
    float* __restrict__ wsG, const unsigned char* __restrict__ nodemask,
    const float* __restrict__ mu, const float* __restrict__ isg,
    float* __restrict__ wsUt, float* __restrict__ wsLam,
    float* __restrict__ outEmb, float* __restrict__ outLmask) {
  const int b = blockIdx.x, t = threadIdx.x;
  float* base = wsG + (size_t)b * WS_STRIDE;
  float* Qg = base + OFF_Q1;
  float* dvg = base + OFF_DV;
  float* tg = base + OFF_TAU;
  float* og = base + OFF_ORG;
  extern __shared__ float lds[];
  float* At = lds;                 // [128][LDT]: At[c*LDT+r] = Aref[r][c]
  float* Qt = lds + 128 * LDT;     // [128][LDT]: Qt[c*LDT+r] = Q[r][c]
  __shared__ float d_[128], tau_[128];
  __shared__ unsigned char nm_[128];

  float orgnrm = og[0];
  for (int idx = t; idx < 16384; idx += 1024) {
    int r = idx >> 7, c = idx & 127;
    At[c * LDT + r] = base[idx];   // Aref transpose-staged
    Qt[c * LDT + r] = Qg[idx];
  }
  if (t < 128) {
    d_[t] = dvg[t] * orgnrm;
    tau_[t] = tg[t];
    nm_[t] = nodemask[b * 128 + t];
  }
  __syncthreads();

  // ---- register-resident back-transform ----
  const int w = t >> 6, l = t & 63;
  const int cidx = l & 7, sg = l >> 3;
  const int c = w * 8 + cidx;
  float q[16];
  #pragma unroll
  for (int k = 0; k < 4; ++k) {
    float4 v = *(const float4*)&Qt[c * LDT + 4 * sg + 32 * k];
    q[4 * k + 0] = v.x; q[4 * k + 1] = v.y; q[4 * k + 2] = v.z; q[4 * k + 3] = v.w;
  }
  for (int i = 126; i >= 0; --i) {
    float taui = tau_[i];
    if (taui == 0.0f) continue;     // uniform branch
    const int lo = i + 1;
    float a[16];
    float dot = 0.0f;
    #pragma unroll
    for (int k = 0; k < 4; ++k) {
      if (32 * k + 31 >= lo) {      // uniform chunk guard
        float4 av = *(const float4*)&At[i * LDT + 4 * sg + 32 * k];
        {
          int r = 4 * sg + 32 * k;
          float aj;
          aj = (r == lo) ? 1.0f : ((r > lo) ? av.x : 0.0f); a[4*k+0] = aj; dot += aj * q[4*k+0]; r++;
          aj = (r == lo) ? 1.0f : ((r > lo) ? av.y : 0.0f); a[4*k+1] = aj; dot += aj * q[4*k+1]; r++;
          aj = (r == lo) ? 1.0f : ((r > lo) ? av.z : 0.0f); a[4*k+2] = aj; dot += aj * q[4*k+2]; r++;
          aj = (r == lo) ? 1.0f : ((r > lo) ? av.w : 0.0f); a[4*k+3] = aj; dot += aj * q[4*k+3];
        }
      }
    }
    dot += __shfl_xor(dot, 8);
    dot += __shfl_xor(dot, 16);
    dot += __shfl_xor(dot, 32);
    float wv = taui * dot;
    #pragma unroll
    for (int k = 0; k < 4; ++k) {
      if (32 * k + 31 >= lo) {
        q[4*k+0] -= a[4*k+0] * wv;
        q[4*k+1] -= a[4*k+1] * wv;
        q[4*k+2] -= a[4*k+2] * wv;
        q[4*k+3] -= a[4*k+3] * wv;
      }
    }
  }
  #pragma unroll
  for (int k = 0; k < 4; ++k) {
    float4 v;
    v.x = q[4*k+0]; v.y = q[4*k+1]; v.z = q[4*k+2]; v.w = q[4*k+3];
    *(float4*)&Qt[c * LDT + 4 * sg + 32 * k] = v;
  }
  __syncthreads();

  // ---- outputs ----
  if (t < NL) {
    float lam = d_[t + 1];
    wsLam[b * NL + t] = lam;
    outLmask[b * NL + t] = (fabsf(lam) < 1e-4f) ? 1.f : 0.f;
  }
  for (int idx = t; idx < NL * 128; idx += 1024) {
    int ll = idx >> 7, nn2 = idx & 127;
    float lam = d_[ll + 1];
    float vv = Qt[(ll + 1) * LDT + nn2];   // Q[nn2][ll+1]
    if (fabsf(lam) < 1e-4f || nm_[nn2]) vv = 0.f;
    wsUt[(size_t)(b * NL + ll) * 128 + nn2] = vv;
  }
  for (int idx = t; idx < NL * NH; idx += 1024) {
    int ll = idx >> 7, h = idx & 127;
    float lam = d_[ll + 1];
    float sq = sqrtf(fmaxf(lam, 0.f));
    float dd = (sq - mu[h]) * isg[h];
    outEmb[(size_t)(b * NL + ll) * NH + h] = expf(-dd * dd);
  }
}

// ---------------- Xh = X*Wx + bx (masked) + nodemask passthrough ----------------
__global__ __launch_bounds__(256) void k_xh(
    const float* __restrict__ X, const unsigned char* __restrict__ nodemask,
    const float* __restrict__ Wx, const float* __restrict__ bx,
    float* __restrict__ outXh, float* __restrict__ outNm) {
  int idx = blockIdx.x * 256 + threadIdx.x;
  int h = idx & 127;
  int bn = idx >> 7;
  const float* xr = X + (size_t)bn * NDX;
  float acc = bx[h];
  #pragma unroll
  for (int d = 0; d < NDX; ++d) acc += xr[d] * Wx[d * NH + h];
  outXh[idx] = nodemask[bn] ? 0.f : acc;
  if (idx < NBATCH * NN) outNm[idx] = nodemask[idx] ? 1.f : 0.f;
}

// ---------------- Uc = (A x_d W_edge + b_edge) contracted with U ----------------
// v2: 32 groups/batch x 4 n-slices (was 16x8): halves the serial n-loop,
// 512 blocks -> 2 blocks/CU co-residency (2x77KB LDS fits 160KB).
__global__ __launch_bounds__(256) void k_uc(
    const float* __restrict__ A, const unsigned char* __restrict__ nodemask,
    const float* __restrict__ We, const float* __restrict__ be,
    const float* __restrict__ wsUt, float* __restrict__ outUc) {
  int b = blockIdx.x >> 5;
  int ng = blockIdx.x & 31;
  int t = threadIdx.x;
  __shared__ float Uts[NL * 129];
  __shared__ float Ssh[NL];
  __shared__ float Wsh[NDE * NH];
  __shared__ float bsh[NH];
  __shared__ float Ar[NN * NDE];
  __shared__ float Tp[2 * NL * NDE];
  __shared__ float Ts[NL * NDE];
  for (int idx = t; idx < NL * NN; idx += 256) {
    int l = idx >> 7, n = idx & 127;
    Uts[l * 129 + n] = wsUt[(size_t)b * NL * NN + idx];
  }
  for (int idx = t; idx < NDE * NH; idx += 256) Wsh[idx] = We[idx];
  if (t < NH) bsh[t] = be[t];
  __syncthreads();
  if (t < NL) {
    float s = 0.f;
    for (int n = 0; n < NN; ++n) s += Uts[t * 129 + n];
    Ssh[t] = s;
  }
  __syncthreads();
  for (int nn = 0; nn < 4; ++nn) {
    int n = ng * 4 + nn;
    for (int idx = t; idx < NN * NDE; idx += 256)
      Ar[idx] = A[(size_t)(b * NN + n) * NN * NDE + idx];
    __syncthreads();
    {
      int l = t & 127, half = t >> 7;
      if (l < NL) {
        float a0 = 0.f, a1 = 0.f, a2 = 0.f, a3 = 0.f;
        for (int m = 64 * half; m < 64 * half + 64; ++m) {
          float u = Uts[l * 129 + m];
          a0 += Ar[m * 4 + 0] * u;
          a1 += Ar[m * 4 + 1] * u;
          a2 += Ar[m * 4 + 2] * u;
          a3 += Ar[m * 4 + 3] * u;
        }
        int base = (half * NL + l) * 4;
        Tp[base + 0] = a0; Tp[base + 1] = a1; Tp[base + 2] = a2; Tp[base + 3] = a3;
      }
    }
    __syncthreads();
    for (int idx = t; idx < NL * NDE; idx += 256) Ts[idx] = Tp[idx] + Tp[NL * NDE + idx];
    __syncthreads();
    bool mn = nodemask[b * NN + n] != 0;
    {
      int h = t & 127, lh = t >> 7;
      float w0 = Wsh[0 * NH + h], w1 = Wsh[1 * NH + h], w2 = Wsh[2 * NH + h], w3 = Wsh[3 * NH + h];
      float bb = bsh[h];
      for (int l = lh; l < NL; l += 2) {
        float v = w0 * Ts[l * 4 + 0] + w1 * Ts[l * 4 + 1] + w2 * Ts[l * 4 + 2] +
                  w3 * Ts[l * 4 + 3] + bb * Ssh[l];
        outUc[(size_t)((b * NN + n) * NL + l) * NH + h] = mn ? 0.f : v;
      }
    }
    __syncthreads();
  }
}

extern "C" void kernel_launch(void* const* d_in, const int* in_sizes, int n_in,
                              void* d_out, int out_size, void* d_ws, size_t ws_size,
                              hipStream_t stream) {
  const float* A = (const float*)d_in[0];
  const float* X = (const float*)d_in[1];
  const unsigned char* nodemask = (const unsigned char*)d_in[2];
  const float* We = (const float*)d_in[3];
  const float* be = (const float*)d_in[4];
  const float* Wx = (const float*)d_in[5];
  const float* bx = (const float*)d_in[6];
  const float* mu = (const float*)d_in[7];
  const float* isg = (const float*)d_in[8];

  float* out = (float*)d_out;
  float* outEmb = out;                   // 16*127*128
  float* outLmask = out + 260096;        // 16*127
  float* outUc = out + 262128;           // 16*128*127*128
  float* outXh = out + 33554416;         // 16*128*128
  float* outNm = out + 33816560;         // 16*128

  float* wsG = (float*)d_ws;                           // 16 * 66560 floats ≈ 4.26 MB
  float* wsUt = (float*)((char*)d_ws + 4456448);       // 16*127*128 floats
  float* wsLam = wsUt + 260096;

  size_t lds1 = (size_t)128 * LDA * sizeof(float);       // 67584
  size_t lds2 = (size_t)2 * 128 * LDT * sizeof(float);   // 135168
  size_t ldsB = (size_t)(3 * 32 * LDB + 128 * LDB) * sizeof(float);  // 115584

  k_tridiag<<<NBATCH, 512, lds1, stream>>>(A, wsG);
  k_leaves<<<NBATCH * 8, 64, 0, stream>>>(wsG);
  k_mergeA<0><<<NBATCH * 4, 1024, 0, stream>>>(wsG, OFF_Q0);
  k_mergeB<<<NBATCH * 4, 512, ldsB, stream>>>(wsG, 0, OFF_Q0, OFF_Q1);
  k_mergeA<1><<<NBATCH * 2, 1024, 0, stream>>>(wsG, OFF_Q1);
  k_mergeB<<<NBATCH * 4, 512, ldsB, stream>>>(wsG, 1, OFF_Q1, OFF_Q0);
  k_mergeA<2><<<NBATCH * 1, 1024, 0, stream>>>(wsG, OFF_Q0);
  k_mergeB<<<NBATCH * 4, 512, ldsB, stream>>>(wsG, 2, OFF_Q0, OFF_Q1);
  k_back<<<NBATCH, 1024, lds2, stream>>>(wsG, nodemask, mu, isg, wsUt, wsLam, outEmb, outLmask);
  k_xh<<<(NBATCH * NN * NH) / 256, 256, 0, stream>>>(X, nodemask, Wx, bx, outXh, outNm);
  k_uc<<<NBATCH * 32, 256, 0, stream>>>(A, nodemask, We, be, wsUt, outUc);
}

// Round 14
// 888.224 us; speedup vs baseline: 1.0906x; 1.0219x over previous
//
#include <hip/hip_runtime.h>

#define NBATCH 16
#define NN 128
#define NH 128
#define NL 127
#define NDX 11
#define NDE 4
#define LDA 132
#define LDB 129
#define LDT 132
#define WS_STRIDE 66560  // floats per batch in wsG

// per-batch workspace float offsets
#define OFF_AREF 0
#define OFF_Q0   16384
#define OFF_Q1   32768
#define OFF_S    49152
#define OFF_DV   65536
#define OFF_EV   65664
#define OFF_TAU  65792
#define OFF_ORG  65920
#define OFF_META 66048   // 512 floats of int metadata

// ---------------- LAPACK fp32 helper ports ----------------
#define EPS32 5.9604645e-8f
#define EPS232 3.5527137e-15f
#define SAFMIN32 1.17549435e-38f

__device__ __forceinline__ float ssign_(float a, float b) {
  return (b >= 0.0f) ? fabsf(a) : -fabsf(a);
}
__device__ __forceinline__ float slapy2_(float x, float y) {
  float ax = fabsf(x), ay = fabsf(y);
  float w = fmaxf(ax, ay), z = fminf(ax, ay);
  if (z == 0.0f) return w;
  float q = z / w;
  return w * sqrtf(1.0f + q * q);
}

// broadcast-read lane `src`'s value of v (uniform src -> v_readlane, scalar pipe)
__device__ __forceinline__ float rdl(float v, int src) {
  return __int_as_float(__builtin_amdgcn_readlane(__float_as_int(v), src));
}

// rsqrt-based Givens (k_leaves only; all args O(1) after orgnrm scaling so
// f^2+g^2 cannot overflow). Replaces sqrt + 2 divides (~60cy dependent) with
// v_rsq + 4 muls (~25cy). rsq rel-err ~1e-6/rotation; ~500 rotations -> ~1e-3,
// well inside the 3.6e-2 test threshold.
__device__ __forceinline__ void slartg_(float f, float g, float* c, float* s, float* r) {
  if (g == 0.0f) { *c = 1.0f; *s = 0.0f; *r = f; }
  else if (f == 0.0f) { *c = 0.0f; *s = (g >= 0.0f) ? 1.0f : -1.0f; *r = fabsf(g); }
  else {
    float t2 = f * f + g * g;
    float inv = rsqrtf(t2);
    if (f < 0.0f) inv = -inv;
    *c = f * inv; *s = g * inv; *r = t2 * inv;
  }
}

__device__ void slaev2_(float a, float b, float c0, float* rt1, float* rt2,
                        float* cs1, float* sn1) {
  float sm = a + c0, df = a - c0, adf = fabsf(df), tb = b + b, ab = fabsf(tb);
  float acmx, acmn;
  if (fabsf(a) > fabsf(c0)) { acmx = a; acmn = c0; } else { acmx = c0; acmn = a; }
  float rt;
  if (adf > ab) { float q = ab / adf; rt = adf * sqrtf(1.0f + q * q); }
  else if (adf < ab) { float q = adf / ab; rt = ab * sqrtf(1.0f + q * q); }
  else rt = ab * sqrtf(2.0f);
  int sgn1;
  if (sm < 0.0f) { *rt1 = 0.5f * (sm - rt); sgn1 = -1; *rt2 = (acmx / *rt1) * acmn - (b / *rt1) * b; }
  else if (sm > 0.0f) { *rt1 = 0.5f * (sm + rt); sgn1 = 1; *rt2 = (acmx / *rt1) * acmn - (b / *rt1) * b; }
  else { *rt1 = 0.5f * rt; *rt2 = -0.5f * rt; sgn1 = 1; }
  int sgn2; float cs;
  if (df >= 0.0f) { cs = df + rt; sgn2 = 1; } else { cs = df - rt; sgn2 = -1; }
  float acs = fabsf(cs);
  if (acs > ab) { float ct = -tb / cs; *sn1 = 1.0f / sqrtf(1.0f + ct * ct); *cs1 = ct * (*sn1); }
  else {
    if (ab == 0.0f) { *cs1 = 1.0f; *sn1 = 0.0f; }
    else { float tn = -cs / tb; *cs1 = 1.0f / sqrtf(1.0f + tn * tn); *sn1 = tn * (*cs1); }
  }
  if (sgn1 == sgn2) { float tn = *cs1; *cs1 = -(*sn1); *sn1 = tn; }
}

// ============ K1: Laplacian build + ssytd2 tridiagonalization ============
// v7 (R10, measured best 325us): 512 threads, R9 4-barrier schedule,
// LDA=132, shfl readbacks.
__global__ __launch_bounds__(512) void k_tridiag(const float* __restrict__ A_in,
                                                 float* __restrict__ wsG) {
  const int b = blockIdx.x, t = threadIdx.x;
  float* Aref = wsG + (size_t)b * WS_STRIDE;
  float* dv = Aref + OFF_DV;
  float* ev = Aref + OFF_EV;
  float* tg = Aref + OFF_TAU;
  float* og = Aref + OFF_ORG;
  extern __shared__ float As[];  // [128][LDA], LDA=132
  __shared__ unsigned int maskp[128][4];
  __shared__ unsigned int Dp[128][4];
  __shared__ unsigned long long adj0_[128], adj1_[128];
  __shared__ float Dd_[128], tDs_[128];
  __shared__ float d_[128], e_[128], tau_[128];
  __shared__ alignas(16) float v_[128];
  __shared__ alignas(16) float w_[128];
  __shared__ float pmat[4][128];
  __shared__ alignas(16) float red_[16];
  __shared__ float xp[16];

  const int wid = t >> 6;        // wave id 0..7
  const int lane = t & 63;
  // ---- adjacency build: 4 threads per row, 32 m's each ----
  {
    const int r8 = t >> 2, s8 = t & 3;
    const float4* Arow = (const float4*)(A_in + (size_t)(b * 128 + r8) * 128 * 4);
    unsigned int mloc = 0; unsigned int cnt = 0;
    const int m0 = s8 * 32;
    #pragma unroll 4
    for (int mm = 0; mm < 32; ++mm) {
      float4 a = Arow[m0 + mm];
      if (a.x != 0.f || a.y != 0.f || a.z != 0.f || a.w != 0.f) { mloc |= 1u << mm; cnt++; }
    }
    maskp[r8][s8] = mloc; Dp[r8][s8] = cnt;
  }
  __syncthreads();
  if (t < 128) {
    unsigned long long b0 = (unsigned long long)maskp[t][0] |
                            ((unsigned long long)maskp[t][1] << 32);
    unsigned long long b1 = (unsigned long long)maskp[t][2] |
                            ((unsigned long long)maskp[t][3] << 32);
    unsigned int D = Dp[t][0] + Dp[t][1] + Dp[t][2] + Dp[t][3];
    adj0_[t] = b0; adj1_[t] = b1;
    float Df = (float)D;
    Dd_[t] = Df;
    tDs_[t] = 1.0f / sqrtf(fmaxf(Df, 1.0f));
  }
  __syncthreads();
  for (int idx = t; idx < 16384; idx += 512) {
    int r = idx >> 7, c = idx & 127;
    if (c <= r) {
      float adj = (float)((c < 64 ? (adj0_[r] >> c) : (adj1_[r] >> (c - 64))) & 1ull);
      float Lrc = ((c == r) ? Dd_[r] : 0.0f) - adj;
      float val = (tDs_[c] * Lrc) * tDs_[r];
      As[r * LDA + c] = val;
      As[c * LDA + r] = val;
    }
  }
  __syncthreads();

  const int rmv = t & 127;   // matvec row
  const int smv = t >> 7;    // matvec segment 0..3 (32 cols each)
  const int ucg = t & 31;    // update col-group (4 cols)
  const int urs = t >> 5;    // update row stripe 0..15

  bool usexp = false;
  for (int i = 0; i < 127; ++i) {
    const int lo = i + 1;
    // ---- xnorm2 of column i below subdiagonal ----
    float xnorm2;
    if (!usexp) {           // uniform fallback path (iter 0 / after taui==0)
      float part = 0.0f;
      if (t < 128 && t >= i + 2) { float x = As[t * LDA + i]; part = x * x; }
      if (wid < 2) {
        #pragma unroll
        for (int m = 1; m < 64; m <<= 1) part += __shfl_xor(part, m);
        if (lane == 0) red_[wid] = part;
      }
      __syncthreads();   // S1 (fallback only)
      xnorm2 = red_[0] + red_[1];
    } else {               // piggybacked: 1 LDS read + shfl tree (sum of 16)
      float s = xp[lane & 15];
      #pragma unroll
      for (int m = 1; m < 16; m <<= 1) s += __shfl_xor(s, m);
      xnorm2 = s;
    }
    float alpha = As[lo * LDA + i];   // row lo never written in phase B
    float beta, taui, scal;
    if (xnorm2 == 0.0f) { taui = 0.0f; beta = alpha; scal = 0.0f; }
    else {
      float xn = sqrtf(xnorm2);
      beta = -ssign_(slapy2_(alpha, xn), alpha);
      taui = (beta - alpha) / beta;
      scal = 1.0f / (alpha - beta);
    }
    if (t == 0) { e_[i] = beta; tau_[i] = taui; }
    if (taui != 0.0f) {    // uniform branch
      // ---- phase B: single-writer v construction ----
      if (t < 128) {
        float vv = 0.0f;
        if (t == lo) vv = 1.0f;
        else if (t > lo) { float xi = As[t * LDA + i]; vv = xi * scal; As[t * LDA + i] = vv; }
        v_[t] = vv;
      }
      __syncthreads();   // S2
      // ---- phase C: matvec partials (32-col chunk) + vpdot partial ----
      const int c0 = smv * 32;
      float acc = 0.0f;
      if (c0 + 31 >= lo && rmv >= lo) {
        const float4* Ar = (const float4*)&As[rmv * LDA + c0];
        const float4* Vr = (const float4*)&v_[c0];
        #pragma unroll
        for (int k = 0; k < 8; ++k) {
          float4 a = Ar[k], v4 = Vr[k];
          acc += a.x * v4.x + a.y * v4.y + a.z * v4.z + a.w * v4.w;
        }
      }
      pmat[smv][rmv] = acc;
      float p2 = v_[rmv] * acc;
      #pragma unroll
      for (int m = 1; m < 64; m <<= 1) p2 += __shfl_xor(p2, m);
      if (lane == 0) red_[wid] = p2;
      __syncthreads();   // S3
      // ---- phase D: w = taui*(Av); a2 via shfl-sum of red_[0..7] ----
      float vpr = red_[lane & 7];
      #pragma unroll
      for (int m = 1; m < 8; m <<= 1) vpr += __shfl_xor(vpr, m);
      float a2 = -0.5f * taui * (taui * vpr);
      if (t < 128) {
        float pv = pmat[0][t] + pmat[1][t] + pmat[2][t] + pmat[3][t];
        w_[t] = taui * pv;
      }
      __syncthreads();   // S4
      // ---- phase E: rank-2 update + next-xnorm piggyback ----
      const int uc0 = ucg * 4;
      if (uc0 + 3 >= lo) {
        float4 vc = *(const float4*)&v_[uc0];
        float4 wc = *(const float4*)&w_[uc0];
        float pcx = wc.x + a2 * vc.x;
        float pcy = wc.y + a2 * vc.y;
        float pcz = wc.z + a2 * vc.z;
        float pcw = wc.w + a2 * vc.w;
        if (uc0 < lo) {   // partial chunk: neutralize components left of lo
          if (uc0 + 0 < lo) { vc.x = 0.f; pcx = 0.f; }
          if (uc0 + 1 < lo) { vc.y = 0.f; pcy = 0.f; }
          if (uc0 + 2 < lo) { vc.z = 0.f; pcz = 0.f; }
        }
        const bool isxcol = (ucg == (lo >> 2));
        const int xc = lo & 3;
        float xpacc = 0.0f;
        #pragma unroll
        for (int k = 0; k < 8; ++k) {
          int r = urs + 16 * k;
          if (r >= lo) {
            float vr = v_[r];
            float pr = w_[r] + a2 * vr;
            float4 a = *(const float4*)&As[r * LDA + uc0];
            a.x -= vr * pcx + pr * vc.x;
            a.y -= vr * pcy + pr * vc.y;
            a.z -= vr * pcz + pr * vc.z;
            a.w -= vr * pcw + pr * vc.w;
            *(float4*)&As[r * LDA + uc0] = a;
            if (isxcol && r >= lo + 2) {
              float nc = (xc == 0) ? a.x : ((xc == 1) ? a.y : ((xc == 2) ? a.z : a.w));
              xpacc += nc * nc;
            }
          }
        }
        if (isxcol) xp[urs] = xpacc;
      }
    }
    __syncthreads();   // S5
    usexp = (taui != 0.0f);
  }
  if (t < 128) d_[t] = As[t * LDA + t];
  __syncthreads();

  {
    float mx = 0.0f;
    if (t < 128) mx = fabsf(d_[t]);
    if (t < 127) mx = fmaxf(mx, fabsf(e_[t]));
    if (wid < 2) {
      #pragma unroll
      for (int m = 1; m < 64; m <<= 1) mx = fmaxf(mx, __shfl_xor(mx, m));
      if (lane == 0) red_[wid] = mx;
    }
    __syncthreads();
  }
  float orgnrm = fmaxf(red_[0], red_[1]);
  if (orgnrm == 0.0f) orgnrm = 1.0f;
  float invnrm = 1.0f / orgnrm;
  if (t < 128) d_[t] *= invnrm;
  if (t < 127) e_[t] *= invnrm;
  __syncthreads();
  if (t == 0) {
    for (int bm = 16; bm < 128; bm += 16) {
      float ae = fabsf(e_[bm - 1]);
      d_[bm - 1] -= ae; d_[bm] -= ae;
    }
  }
  __syncthreads();
  for (int idx = t; idx < 16384; idx += 512)
    Aref[idx] = As[(idx >> 7) * LDA + (idx & 127)];
  if (t < 128) { dv[t] = d_[t]; tg[t] = tau_[t]; }
  if (t < 127) ev[t] = e_[t];
  if (t == 0) og[0] = orgnrm;
}

// ============ K2: 8 leaves x 16 batches, one block each ============
// v4: lane-register ssteqr + rsqrt-based slartg (the serial bulge-chase
// chain is the kernel's floor; sqrt+2div -> rsq+4mul cuts ~35%/step).
__global__ __launch_bounds__(64) void k_leaves(float* __restrict__ wsG) {
  int b = blockIdx.x >> 3, lf = blockIdx.x & 7;
  float* base = wsG + (size_t)b * WS_STRIDE;
  float* Qg = base + OFF_Q0;
  float* dv = base + OFF_DV;
  float* ev = base + OFF_EV;
  const int ln = threadIdx.x;
  __shared__ float zsh[16 * 17];

  const int n = 16;
  float dreg = (ln < 16) ? dv[lf * 16 + ln] : 0.f;
  float ereg = (ln < 15) ? ev[lf * 16 + ln] : 0.f;
  float csreg = 0.f, snreg = 0.f;
  float zr[16];
  #pragma unroll
  for (int c = 0; c < 16; ++c) zr[c] = (ln == c) ? 1.0f : 0.0f;

  {
    const float eps = EPS32, eps2 = EPS232, safmin = SAFMIN32;
    int nmaxit = n * 30, jtot = 0;
    int l1 = 0;
    while (l1 <= n - 1) {
      if (l1 > 0 && ln == l1 - 1) ereg = 0.0f;
      int m;
      for (m = l1; m <= n - 2; ++m) {
        float tst = fabsf(rdl(ereg, m));
        if (tst == 0.0f) break;
        if (tst <= (sqrtf(fabsf(rdl(dreg, m))) * sqrtf(fabsf(rdl(dreg, m + 1)))) * eps) {
          if (ln == m) ereg = 0.0f;
          break;
        }
      }
      int l = l1, lend = m;
      l1 = m + 1;
      if (lend == l) continue;
      {
        float an = 0.0f;
        for (int i = l; i <= lend; ++i) an = fmaxf(an, fabsf(rdl(dreg, i)));
        for (int i = l; i <= lend - 1; ++i) an = fmaxf(an, fabsf(rdl(ereg, i)));
        if (an == 0.0f) continue;
      }
      if (fabsf(rdl(dreg, lend)) < fabsf(rdl(dreg, l))) { int tsw = l; l = lend; lend = tsw; }
      if (lend > l) {
        while (true) {  // QL
          int m2;
          if (l != lend) {
            for (m2 = l; m2 <= lend - 1; ++m2) {
              float em = rdl(ereg, m2);
              float tst = em * em;
              if (tst <= (eps2 * fabsf(rdl(dreg, m2))) * fabsf(rdl(dreg, m2 + 1)) + safmin) break;
            }
          } else m2 = lend;
          if (m2 < lend && ln == m2) ereg = 0.0f;
          float p = rdl(dreg, l);
          if (m2 == l) { l++; if (l <= lend) continue; else break; }
          if (m2 == l + 1) {
            float rt1, rt2, c, s;
            slaev2_(rdl(dreg, l), rdl(ereg, l), rdl(dreg, l + 1), &rt1, &rt2, &c, &s);
            #pragma unroll
            for (int j = 0; j < 15; ++j) {
              if (j == l) {
                float t1 = zr[j + 1];
                zr[j + 1] = c * t1 - s * zr[j];
                zr[j] = s * t1 + c * zr[j];
              }
            }
            if (ln == l) { dreg = rt1; ereg = 0.0f; }
            if (ln == l + 1) dreg = rt2;
            l += 2; if (l <= lend) continue; else break;
          }
          if (jtot == nmaxit) break;
          jtot++;
          float g = (rdl(dreg, l + 1) - p) / (2.0f * rdl(ereg, l));
          float r = slapy2_(g, 1.0f);
          g = rdl(dreg, m2) - p + rdl(ereg, l) / (g + ssign_(r, g));
          float s = 1.0f, c = 1.0f; p = 0.0f;
          for (int i = m2 - 1; i >= l; --i) {
            float ei = rdl(ereg, i);
            float f = s * ei, bb = c * ei;
            slartg_(g, f, &c, &s, &r);
            if (i != m2 - 1 && ln == i + 1) ereg = r;
            g = rdl(dreg, i + 1) - p;
            r = (rdl(dreg, i) - g) * s + 2.0f * c * bb;
            p = s * r;
            if (ln == i + 1) dreg = g + p;
            g = c * r - bb;
            if (ln == i) { csreg = c; snreg = -s; }
          }
          #pragma unroll
          for (int j = 14; j >= 0; --j) {
            if (j <= m2 - 1 && j >= l) {
              float cj = rdl(csreg, j), sj = rdl(snreg, j);
              float t1 = zr[j + 1];
              zr[j + 1] = cj * t1 - sj * zr[j];
              zr[j] = sj * t1 + cj * zr[j];
            }
          }
          if (ln == l) { dreg = dreg - p; ereg = g; }
        }
      } else {
        while (true) {  // QR
          int m2;
          if (l != lend) {
            for (m2 = l; m2 >= lend + 1; --m2) {
              float em = rdl(ereg, m2 - 1);
              float tst = em * em;
              if (tst <= (eps2 * fabsf(rdl(dreg, m2))) * fabsf(rdl(dreg, m2 - 1)) + safmin) break;
            }
          } else m2 = lend;
          if (m2 > lend && ln == m2 - 1) ereg = 0.0f;
          float p = rdl(dreg, l);
          if (m2 == l) { l--; if (l >= lend) continue; else break; }
          if (m2 == l - 1) {
            float rt1, rt2, c, s;
            slaev2_(rdl(dreg, l - 1), rdl(ereg, l - 1), rdl(dreg, l), &rt1, &rt2, &c, &s);
            #pragma unroll
            for (int j = 0; j < 15; ++j) {
              if (j == l - 1) {
                float t1 = zr[j + 1];
                zr[j + 1] = c * t1 - s * zr[j];
                zr[j] = s * t1 + c * zr[j];
              }
            }
            if (ln == l - 1) { dreg = rt1; ereg = 0.0f; }
            if (ln == l) dreg = rt2;
            l -= 2; if (l >= lend) continue; else break;
          }
          if (jtot == nmaxit) break;
          jtot++;
          float g = (rdl(dreg, l - 1) - p) / (2.0f * rdl(ereg, l - 1));
          float r = slapy2_(g, 1.0f);
          g = rdl(dreg, m2) - p + rdl(ereg, l - 1) / (g + ssign_(r, g));
          float s = 1.0f, c = 1.0f; p = 0.0f;
          for (int i = m2; i <= l - 1; ++i) {
            float ei = rdl(ereg, i);
            float f = s * ei, bb = c * ei;
            slartg_(g, f, &c, &s, &r);
            if (i != m2 && ln == i - 1) ereg = r;
            g = rdl(dreg, i) - p;
            r = (rdl(dreg, i + 1) - g) * s + 2.0f * c * bb;
            p = s * r;
            if (ln == i) dreg = g + p;
            g = c * r - bb;
            if (ln == i) { csreg = c; snreg = s; }
          }
          #pragma unroll
          for (int j = 0; j <= 14; ++j) {
            if (j >= m2 && j <= l - 1) {
              float cj = rdl(csreg, j), sj = rdl(snreg, j);
              float t1 = zr[j + 1];
              zr[j + 1] = cj * t1 - sj * zr[j];
              zr[j] = sj * t1 + cj * zr[j];
            }
          }
          if (ln == l) dreg = dreg - p;
          if (ln == l - 1) ereg = g;
        }
      }
    }
  }

  // stage z rows to LDS for sort + band write
  if (ln < 16) {
    #pragma unroll
    for (int c = 0; c < 16; ++c) zsh[ln * 17 + c] = zr[c];
  }
  __syncthreads();
  // selection sort: d in lane registers, z column swaps row-parallel in LDS
  for (int ii = 1; ii <= n - 1; ++ii) {
    int i = ii - 1, k = i;
    float p = rdl(dreg, i);
    for (int j = ii; j <= n - 1; ++j) {
      float dj = rdl(dreg, j);
      if (dj < p) { k = j; p = dj; }
    }
    if (k != i) {
      float di = rdl(dreg, i);
      if (ln == k) dreg = di;
      if (ln == i) dreg = p;
      if (ln < 16) {
        float t1 = zsh[ln * 17 + i];
        zsh[ln * 17 + i] = zsh[ln * 17 + k];
        zsh[ln * 17 + k] = t1;
      }
    }
  }
  __syncthreads();
  if (ln < 16) dv[lf * 16 + ln] = dreg;
  // write only the 32-col merge band: cols bo..bo+31 where bo=(lf>>1)*32
  {
    const int bo = (lf >> 1) * 32;
    const int cofs = (lf & 1) * 16;   // local col offset of this leaf in band
    for (int idx = ln; idx < 16 * 32; idx += 64) {
      int rr = idx >> 5, c = idx & 31;
      int cl = c - cofs;
      float v = (cl >= 0 && cl < 16) ? zsh[rr * 17 + cl] : 0.f;
      Qg[(size_t)(lf * 16 + rr) * 128 + bo + c] = v;
    }
  }
}

// ============ K3a: merge metadata/secular per (batch, merge) ============
// v3: register bisection 36 iters.
template <int LVL>
__global__ __launch_bounds__(1024) void k_mergeA(float* __restrict__ wsG, int qoff) {
  constexpr int sh = 2 - LVL;
  constexpr int nm = 32 << LVL;     // merged size n
  constexpr int LPR = 1024 / nm;    // lanes per root: 32/16/8
  constexpr int NCH = nm / LPR;     // chunk regs per lane: 1/4/16
  int b = blockIdx.x >> sh;
  int mg = blockIdx.x & ((1 << sh) - 1);
  int bo = mg * nm, n1 = nm >> 1, n = nm;
  const int t = threadIdx.x;
  float* base = wsG + (size_t)b * WS_STRIDE;
  float* Qin = base + qoff;
  float* dvg = base + OFF_DV;
  float* evg = base + OFF_EV;
  float* Sg  = base + OFF_S;
  int* meta = (int*)(base + OFF_META);
  int* undG = meta; int* idxpG = meta + 128; int* finG = meta + 256; int* KfG = meta + 384;

  __shared__ float d_[128], z_[128], dl_[128], w_[128], zh_[128], lam_[128], tauv_[128], dnew_[128];
  __shared__ int srt_[128], indxp_[128], und_[128], anc_[128], fin_[128];
  __shared__ int gp_[128], gq_[128];
  __shared__ float gc_[128], gs_[128];
  __shared__ int sci[4];

  if (t < n) d_[t] = dvg[bo + t];
  float rho_in = evg[bo + n1 - 1];
  if (t < n) {
    float zv = (t < n1) ? Qin[(size_t)(bo + n1 - 1) * 128 + bo + t]
                        : Qin[(size_t)(bo + n1) * 128 + bo + t];
    if (rho_in < 0.0f && t >= n1) zv = -zv;
    z_[t] = zv * 0.70710678f;
  }
  __syncthreads();
  float rho = fabsf(2.0f * rho_in);
  if (t == 0) {
    int i1 = 0, i2 = n1, k = 0;
    while (i1 < n1 && i2 < n) {
      if (d_[i1] <= d_[i2]) srt_[k++] = i1++; else srt_[k++] = i2++;
    }
    while (i1 < n1) srt_[k++] = i1++;
    while (i2 < n) srt_[k++] = i2++;
    float zmax = 0.0f, dmax = 0.0f;
    for (int i = 0; i < n; ++i) {
      zmax = fmaxf(zmax, fabsf(z_[i]));
      dmax = fmaxf(dmax, fabsf(d_[i]));
    }
    float tol = 8.0f * EPS32 * fmaxf(dmax, zmax);
    int K = 0, k2 = n, full = 0, ngiv = 0;
    if (rho * zmax <= tol) full = 1;
    else {
      int pj = -1, jj = 0;
      for (; jj < n; ++jj) {
        int nj = srt_[jj];
        if (rho * fabsf(z_[nj]) <= tol) { k2--; indxp_[k2] = nj; }
        else { pj = nj; break; }
      }
      if (pj < 0) full = 1;
      else {
        for (jj = jj + 1; jj < n; ++jj) {
          int nj = srt_[jj];
          if (rho * fabsf(z_[nj]) <= tol) { k2--; indxp_[k2] = nj; }
          else {
            float s = z_[pj], c = z_[nj];
            float tauq = slapy2_(c, s);
            float tdf = d_[nj] - d_[pj];
            c /= tauq; s = -s / tauq;
            if (fabsf(tdf * c * s) <= tol) {
              z_[nj] = tauq; z_[pj] = 0.0f;
              gp_[ngiv] = pj; gq_[ngiv] = nj; gc_[ngiv] = c; gs_[ngiv] = s; ngiv++;
              float tt2 = d_[pj] * c * c + d_[nj] * s * s;
              d_[nj] = d_[pj] * s * s + d_[nj] * c * c;
              d_[pj] = tt2;
              k2--;
              int pos = k2;
              while (pos + 1 <= n - 1 && d_[pj] < d_[indxp_[pos + 1]]) {
                indxp_[pos] = indxp_[pos + 1]; pos++;
              }
              indxp_[pos] = pj;
              pj = nj;
            } else {
              dl_[K] = d_[pj]; w_[K] = z_[pj]; und_[K] = pj; K++;
              pj = nj;
            }
          }
        }
        dl_[K] = d_[pj]; w_[K] = z_[pj]; und_[K] = pj; K++;
      }
    }
    sci[0] = K; sci[1] = full; sci[2] = ngiv;
  }
  __syncthreads();
  int K = sci[0], full = sci[1], ngiv = sci[2];
  if (!full) {
    // Givens rotations applied row-parallel to global Q (same per-row op order)
    if (t < n) {
      size_t rowoff = (size_t)(bo + t) * 128 + bo;
      for (int g = 0; g < ngiv; ++g) {
        float c = gc_[g], s = gs_[g];
        float xq = Qin[rowoff + gp_[g]], yq = Qin[rowoff + gq_[g]];
        Qin[rowoff + gp_[g]] = c * xq + s * yq;
        Qin[rowoff + gq_[g]] = c * yq - s * xq;
      }
    }
    // ---- lane-group secular solve: root j = t/LPR, sub-lane sub = t%LPR ----
    const int j = t / LPR;
    const int sub = t % LPR;
    const bool act = (j < K);
    float dl_loc[NCH], w2_loc[NCH];
    float tauj_reg = 0.0f; float da_reg = 0.0f;
    if (act) {
      #pragma unroll
      for (int k = 0; k < NCH; ++k) {
        int i = sub + k * LPR;
        if (i < K) { dl_loc[k] = dl_[i]; float wi = w_[i]; w2_loc[k] = rho * wi * wi; }
        else { dl_loc[k] = 3.0e38f; w2_loc[k] = 0.0f; }   // term -> 0, no NaN
      }
      // zsum (already rho-scaled)
      float zs = 0.0f;
      #pragma unroll
      for (int k = 0; k < NCH; ++k) zs += w2_loc[k];
      #pragma unroll
      for (int m = 1; m < LPR; m <<= 1) zs += __shfl_xor(zs, m);
      // anchor decision
      int a; float lo2, hi2;
      if (j < K - 1) {
        float dj = dl_[j];
        float tm = 0.5f * (dl_[j + 1] - dj);
        float fm = 0.0f;
        #pragma unroll
        for (int k = 0; k < NCH; ++k) fm += w2_loc[k] / ((dl_loc[k] - dj) - tm);
        #pragma unroll
        for (int m = 1; m < LPR; m <<= 1) fm += __shfl_xor(fm, m);
        fm += 1.0f;
        if (fm >= 0.0f) { a = j; lo2 = 0.0f; hi2 = tm; }
        else { a = j + 1; lo2 = -tm; hi2 = 0.0f; }
      } else { a = K - 1; lo2 = 0.0f; hi2 = zs + 1e-30f; }
      float da = dl_[a];
      float sdl[NCH];
      #pragma unroll
      for (int k = 0; k < NCH; ++k) sdl[k] = dl_loc[k] - da;
      for (int it2 = 0; it2 < 36; ++it2) {
        float tc = 0.5f * (lo2 + hi2);
        float f = 0.0f;
        #pragma unroll
        for (int k = 0; k < NCH; ++k) f += w2_loc[k] / (sdl[k] - tc);
        #pragma unroll
        for (int m = 1; m < LPR; m <<= 1) f += __shfl_xor(f, m);
        f += 1.0f;
        if (f >= 0.0f) hi2 = tc; else lo2 = tc;
      }
      tauj_reg = 0.5f * (lo2 + hi2);
      da_reg = da;
      if (sub == 0) { lam_[j] = da + tauj_reg; tauv_[j] = tauj_reg; anc_[j] = a; }
    }
    __syncthreads();
    // Gu's sign-preserving z-hat (root i = j of this octet; chunk over jj)
    if (act) {
      float di = dl_[j];
      float pp = 1.0f;
      #pragma unroll
      for (int k = 0; k < NCH; ++k) {
        int jj = sub + k * LPR;
        if (jj < K && jj != j) {
          float delta_ij = (di - dl_[anc_[jj]]) - tauv_[jj];
          pp *= delta_ij / (di - dl_[jj]);
        }
      }
      #pragma unroll
      for (int m = 1; m < LPR; m <<= 1) pp *= __shfl_xor(pp, m);
      if (sub == 0) {
        float lead = (di - da_reg) - tauj_reg;
        float acc = lead * pp;
        zh_[j] = ssign_(sqrtf(fmaxf(-acc, 0.0f)), w_[j]);
      }
    }
    __syncthreads();
    // rank-1 system eigenvectors, chunked per lane, single scaled store
    if (act) {
      float sv[NCH]; float nrm = 0.0f;
      #pragma unroll
      for (int k = 0; k < NCH; ++k) {
        int i = sub + k * LPR;
        float s = 0.0f;
        if (i < K) s = zh_[i] / ((dl_loc[k] - da_reg) - tauj_reg);
        sv[k] = s; nrm += s * s;
      }
      #pragma unroll
      for (int m = 1; m < LPR; m <<= 1) nrm += __shfl_xor(nrm, m);
      nrm = 1.0f / sqrtf(nrm);
      float* scol = Sg + bo + j;
      #pragma unroll
      for (int k = 0; k < NCH; ++k) {
        int i = sub + k * LPR;
        if (i < K) scol[(size_t)(bo + i) * 128] = sv[k] * nrm;
      }
    }
    if (t == 0) {
      for (int jj = 0; jj < K; ++jj) dnew_[jj] = lam_[jj];
      for (int m = 0; m < n - K; ++m) dnew_[K + m] = d_[indxp_[n - 1 - m]];
      int i1 = 0, i2 = K, k = 0;
      while (i1 < K && i2 < n) { if (dnew_[i1] <= dnew_[i2]) fin_[k++] = i1++; else fin_[k++] = i2++; }
      while (i1 < K) fin_[k++] = i1++;
      while (i2 < n) fin_[k++] = i2++;
    }
    __syncthreads();
    if (t < n) {
      dvg[bo + t] = dnew_[fin_[t]];
      idxpG[bo + t] = indxp_[t];
      finG[bo + t] = fin_[t];
    }
    if (t < K) undG[bo + t] = und_[t];
    if (t == 0) KfG[mg] = K;
  } else {
    if (t < n) {
      dvg[bo + t] = d_[srt_[t]];
      idxpG[bo + t] = srt_[n - 1 - t];
      finG[bo + t] = t;
    }
    if (t == 0) KfG[mg] = 0;
  }
}

// ============ K3b: merge GEMM/permute, 32 rows per block ============
// v2: 512 threads (8 waves = 2/SIMD).
__global__ __launch_bounds__(512) void k_mergeB(float* __restrict__ wsG, int lvl,
                                                int qinoff, int qoutoff) {
  int b = blockIdx.x >> 2;
  int rblk = blockIdx.x & 3;
  int rbase = rblk * 32;
  int nm = 32 << lvl;
  int ln2 = 5 + lvl;
  int mg = rbase >> ln2;
  int bo = mg * nm, n = nm;
  const int t = threadIdx.x;
  float* base = wsG + (size_t)b * WS_STRIDE;
  const float* Qin = base + qinoff;
  float* Qout = base + qoutoff;
  const float* Sg = base + OFF_S;
  const int* meta = (const int*)(base + OFF_META);
  const int* undG = meta; const int* idxpG = meta + 128;
  const int* finG = meta + 256; const int* KfG = meta + 384;

  extern __shared__ float lds[];
  float* QT = lds;                 // [32][LDB]
  float* QC = QT + 32 * LDB;       // [32][LDB]
  float* WT = QC + 32 * LDB;       // [32][LDB]
  float* ST = WT + 32 * LDB;       // [128][LDB]
  __shared__ int und_l[128], idxp_l[128], fin_l[128];
  __shared__ int Ksh;

  if (t == 0) Ksh = KfG[mg];
  if (t < n) { und_l[t] = undG[bo + t]; idxp_l[t] = idxpG[bo + t]; fin_l[t] = finG[bo + t]; }
  for (int idx = t; idx < 32 * n; idx += 512) {
    int r = idx >> ln2, c = idx & (n - 1);
    QT[r * LDB + c] = Qin[(size_t)(rbase + r) * 128 + bo + c];
  }
  __syncthreads();
  int K = Ksh;
  for (int idx = t; idx < (K << 7); idx += 512) {
    int k = idx >> 7, j = idx & 127;
    ST[k * LDB + j] = Sg[(size_t)(bo + k) * 128 + bo + j];
  }
  for (int r = 0; r < 32; ++r)
    if (t < K) QC[r * LDB + t] = QT[r * LDB + und_l[t]];
  __syncthreads();
  for (int idx = t; idx < 32 * n; idx += 512) {
    int r = idx >> ln2, j = idx & (n - 1);
    float v;
    if (j < K) {
      float a0 = 0.f, a1 = 0.f, a2 = 0.f, a3 = 0.f;
      int k = 0;
      for (; k + 3 < K; k += 4) {
        a0 += QC[r * LDB + k]     * ST[k * LDB + j];
        a1 += QC[r * LDB + k + 1] * ST[(k + 1) * LDB + j];
        a2 += QC[r * LDB + k + 2] * ST[(k + 2) * LDB + j];
        a3 += QC[r * LDB + k + 3] * ST[(k + 3) * LDB + j];
      }
      for (; k < K; ++k) a0 += QC[r * LDB + k] * ST[k * LDB + j];
      v = (a0 + a1) + (a2 + a3);
    } else {
      v = QT[r * LDB + idxp_l[n - 1 - (j - K)]];
    }
    WT[r * LDB + j] = v;
  }
  __syncthreads();
  for (int idx = t; idx < 32 * 128; idx += 512) {
    int r = idx >> 7, c = idx & 127;
    int cl = c - bo;
    float v = 0.f;
    if (cl >= 0 && cl < n) v = WT[r * LDB + fin_l[cl]];
    Qout[(size_t)(rbase + r) * 128 + c] = v;
  }
}

// ============ K4: back-transform + outputs ============
// v2: 1024 threads, 16 waves; Q register-resident, barrier-free reflector loop.
__global__ __launch_bounds__(1024) void k_back(
    float* __restrict__ wsG, const unsigned char* __restrict__ nodemask,
    const float* __restrict__ mu, const float* __restrict__ isg,
    float* __restrict__ wsUt, float* __restrict__ wsLam,
    float* __restrict__ outEmb, float* __restrict__ outLmask) {
  const int b = blockIdx.x, t = threadIdx.x;
  float* base = wsG + (size_t)b * WS_STRIDE;
  float* Qg = base + OFF_Q1;
  float* dvg = base + OFF_DV;
  float* tg = base + OFF_TAU;
  float* og = base + OFF_ORG;
  extern __shared__ float lds[];
  float* At = lds;                 // [128][LDT]: At[c*LDT+r] = Aref[r][c]
  float* Qt = lds + 128 * LDT;     // [128][LDT]: Qt[c*LDT+r] = Q[r][c]
  __shared__ float d_[128], tau_[128];
  __shared__ unsigned char nm_[128];

  float orgnrm = og[0];
  for (int idx = t; idx < 16384; idx += 1024) {
    int r = idx >> 7, c = idx & 127;
    At[c * LDT + r] = base[idx];   // Aref transpose-staged
    Qt[c * LDT + r] = Qg[idx];
  }
  if (t < 128) {
    d_[t] = dvg[t] * orgnrm;
    tau_[t] = tg[t];
    nm_[t] = nodemask[b * 128 + t];
  }
  __syncthreads();

  // ---- register-resident back-transform ----
  const int w = t >> 6, l = t & 63;
  const int cidx = l & 7, sg = l >> 3;
  const int c = w * 8 + cidx;
  float q[16];
  #pragma unroll
  for (int k = 0; k < 4; ++k) {
    float4 v = *(const float4*)&Qt[c * LDT + 4 * sg + 32 * k];
    q[4 * k + 0] = v.x; q[4 * k + 1] = v.y; q[4 * k + 2] = v.z; q[4 * k + 3] = v.w;
  }
  for (int i = 126; i >= 0; --i) {
    float taui = tau_[i];
    if (taui == 0.0f) continue;     // uniform branch
    const int lo = i + 1;
    float a[16];
    float dot = 0.0f;
    #pragma unroll
    for (int k = 0; k < 4; ++k) {
      if (32 * k + 31 >= lo) {      // uniform chunk guard
        float4 av = *(const float4*)&At[i * LDT + 4 * sg + 32 * k];
        {
          int r = 4 * sg + 32 * k;
          float aj;
          aj = (r == lo) ? 1.0f : ((r > lo) ? av.x : 0.0f); a[4*k+0] = aj; dot += aj * q[4*k+0]; r++;
          aj = (r == lo) ? 1.0f : ((r > lo) ? av.y : 0.0f); a[4*k+1] = aj; dot += aj * q[4*k+1]; r++;
          aj = (r == lo) ? 1.0f : ((r > lo) ? av.z : 0.0f); a[4*k+2] = aj; dot += aj * q[4*k+2]; r++;
          aj = (r == lo) ? 1.0f : ((r > lo) ? av.w : 0.0f); a[4*k+3] = aj; dot += aj * q[4*k+3];
        }
      }
    }
    dot += __shfl_xor(dot, 8);
    dot += __shfl_xor(dot, 16);
    dot += __shfl_xor(dot, 32);
    float wv = taui * dot;
    #pragma unroll
    for (int k = 0; k < 4; ++k) {
      if (32 * k + 31 >= lo) {
        q[4*k+0] -= a[4*k+0] * wv;
        q[4*k+1] -= a[4*k+1] * wv;
        q[4*k+2] -= a[4*k+2] * wv;
        q[4*k+3] -= a[4*k+3] * wv;
      }
    }
  }
  #pragma unroll
  for (int k = 0; k < 4; ++k) {
    float4 v;
    v.x = q[4*k+0]; v.y = q[4*k+1]; v.z = q[4*k+2]; v.w = q[4*k+3];
    *(float4*)&Qt[c * LDT + 4 * sg + 32 * k] = v;
  }
  __syncthreads();

  // ---- outputs ----
  if (t < NL) {
    float lam = d_[t + 1];
    wsLam[b * NL + t] = lam;
    outLmask[b * NL + t] = (fabsf(lam) < 1e-4f) ? 1.f : 0.f;
  }
  for (int idx = t; idx < NL * 128; idx += 1024) {
    int ll = idx >> 7, nn2 = idx & 127;
    float lam = d_[ll + 1];
    float vv = Qt[(ll + 1) * LDT + nn2];   // Q[nn2][ll+1]
    if (fabsf(lam) < 1e-4f || nm_[nn2]) vv = 0.f;
    wsUt[(size_t)(b * NL + ll) * 128 + nn2] = vv;
  }
  for (int idx = t; idx < NL * NH; idx += 1024) {
    int ll = idx >> 7, h = idx & 127;
    float lam = d_[ll + 1];
    float sq = sqrtf(fmaxf(lam, 0.f));
    float dd = (sq - mu[h]) * isg[h];
    outEmb[(size_t)(b * NL + ll) * NH + h] = expf(-dd * dd);
  }
}

// ---------------- Xh = X*Wx + bx (masked) + nodemask passthrough ----------------
__global__ __launch_bounds__(256) void k_xh(
    const float* __restrict__ X, const unsigned char* __restrict__ nodemask,
    const float* __restrict__ Wx, const float* __restrict__ bx,
    float* __restrict__ outXh, float* __restrict__ outNm) {
  int idx = blockIdx.x * 256 + threadIdx.x;
  int h = idx & 127;
  int bn = idx >> 7;
  const float* xr = X + (size_t)bn * NDX;
  float acc = bx[h];
  #pragma unroll
  for (int d = 0; d < NDX; ++d) acc += xr[d] * Wx[d * NH + h];
  outXh[idx] = nodemask[bn] ? 0.f : acc;
  if (idx < NBATCH * NN) outNm[idx] = nodemask[idx] ? 1.f : 0.f;
}

// ---------------- Uc = (A x_d W_edge + b_edge) contracted with U ----------------
// v2: 32 groups/batch x 4 n-slices; 512 blocks -> 2 blocks/CU co-residency.
__global__ __launch_bounds__(256) void k_uc(
    const float* __restrict__ A, const unsigned char* __restrict__ nodemask,
    const float* __restrict__ We, const float* __restrict__ be,
    const float* __restrict__ wsUt, float* __restrict__ outUc) {
  int b = blockIdx.x >> 5;
  int ng = blockIdx.x & 31;
  int t = threadIdx.x;
  __shared__ float Uts[NL * 129];
  __shared__ float Ssh[NL];
  __shared__ float Wsh[NDE * NH];
  __shared__ float bsh[NH];
  __shared__ float Ar[NN * NDE];
  __shared__ float Tp[2 * NL * NDE];
  __shared__ float Ts[NL * NDE];
  for (int idx = t; idx < NL * NN; idx += 256) {
    int l = idx >> 7, n = idx & 127;
    Uts[l * 129 + n] = wsUt[(size_t)b * NL * NN + idx];
  }
  for (int idx = t; idx < NDE * NH; idx += 256) Wsh[idx] = We[idx];
  if (t < NH) bsh[t] = be[t];
  __syncthreads();
  if (t < NL) {
    float s = 0.f;
    for (int n = 0; n < NN; ++n) s += Uts[t * 129 + n];
    Ssh[t] = s;
  }
  __syncthreads();
  for (int nn = 0; nn < 4; ++nn) {
    int n = ng * 4 + nn;
    for (int idx = t; idx < NN * NDE; idx += 256)
      Ar[idx] = A[(size_t)(b * NN + n) * NN * NDE + idx];
    __syncthreads();
    {
      int l = t & 127, half = t >> 7;
      if (l < NL) {
        float a0 = 0.f, a1 = 0.f, a2 = 0.f, a3 = 0.f;
        for (int m = 64 * half; m < 64 * half + 64; ++m) {
          float u = Uts[l * 129 + m];
          a0 += Ar[m * 4 + 0] * u;
          a1 += Ar[m * 4 + 1] * u;
          a2 += Ar[m * 4 + 2] * u;
          a3 += Ar[m * 4 + 3] * u;
        }
        int base = (half * NL + l) * 4;
        Tp[base + 0] = a0; Tp[base + 1] = a1; Tp[base + 2] = a2; Tp[base + 3] = a3;
      }
    }
    __syncthreads();
    for (int idx = t; idx < NL * NDE; idx += 256) Ts[idx] = Tp[idx] + Tp[NL * NDE + idx];
    __syncthreads();
    bool mn = nodemask[b * NN + n] != 0;
    {
      int h = t & 127, lh = t >> 7;
      float w0 = Wsh[0 * NH + h], w1 = Wsh[1 * NH + h], w2 = Wsh[2 * NH + h], w3 = Wsh[3 * NH + h];
      float bb = bsh[h];
      for (int l = lh; l < NL; l += 2) {
        float v = w0 * Ts[l * 4 + 0] + w1 * Ts[l * 4 + 1] + w2 * Ts[l * 4 + 2] +
                  w3 * Ts[l * 4 + 3] + bb * Ssh[l];
        outUc[(size_t)((b * NN + n) * NL + l) * NH + h] = mn ? 0.f : v;
      }
    }
    __syncthreads();
  }
}

extern "C" void kernel_launch(void* const* d_in, const int* in_sizes, int n_in,
                              void* d_out, int out_size, void* d_ws, size_t ws_size,
                              hipStream_t stream) {
  const float* A = (const float*)d_in[0];
  const float* X = (const float*)d_in[1];
  const unsigned char* nodemask = (const unsigned char*)d_in[2];
  const float* We = (const float*)d_in[3];
  const float* be = (const float*)d_in[4];
  const float* Wx = (const float*)d_in[5];
  const float* bx = (const float*)d_in[6];
  const float* mu = (const float*)d_in[7];
  const float* isg = (const float*)d_in[8];

  float* out = (float*)d_out;
  float* outEmb = out;                   // 16*127*128
  float* outLmask = out + 260096;        // 16*127
  float* outUc = out + 262128;           // 16*128*127*128
  float* outXh = out + 33554416;         // 16*128*128
  float* outNm = out + 33816560;         // 16*128

  float* wsG = (float*)d_ws;                           // 16 * 66560 floats ≈ 4.26 MB
  float* wsUt = (float*)((char*)d_ws + 4456448);       // 16*127*128 floats
  float* wsLam = wsUt + 260096;

  size_t lds1 = (size_t)128 * LDA * sizeof(float);       // 67584
  size_t lds2 = (size_t)2 * 128 * LDT * sizeof(float);   // 135168
  size_t ldsB = (size_t)(3 * 32 * LDB + 128 * LDB) * sizeof(float);  // 115584

  k_tridiag<<<NBATCH, 512, lds1, stream>>>(A, wsG);
  k_leaves<<<NBATCH * 8, 64, 0, stream>>>(wsG);
  k_mergeA<0><<<NBATCH * 4, 1024, 0, stream>>>(wsG, OFF_Q0);
  k_mergeB<<<NBATCH * 4, 512, ldsB, stream>>>(wsG, 0, OFF_Q0, OFF_Q1);
  k_mergeA<1><<<NBATCH * 2, 1024, 0, stream>>>(wsG, OFF_Q1);
  k_mergeB<<<NBATCH * 4, 512, ldsB, stream>>>(wsG, 1, OFF_Q1, OFF_Q0);
  k_mergeA<2><<<NBATCH * 1, 1024, 0, stream>>>(wsG, OFF_Q0);
  k_mergeB<<<NBATCH * 4, 512, ldsB, stream>>>(wsG, 2, OFF_Q0, OFF_Q1);
  k_back<<<NBATCH, 1024, lds2, stream>>>(wsG, nodemask, mu, isg, wsUt, wsLam, outEmb, outLmask);
  k_xh<<<(NBATCH * NN * NH) / 256, 256, 0, stream>>>(X, nodemask, Wx, bx, outXh, outNm);
  k_uc<<<NBATCH * 32, 256, 0, stream>>>(A, nodemask, We, be, wsUt, outUc);
}

// Round 15
// 868.772 us; speedup vs baseline: 1.1150x; 1.0224x over previous
//
#include <hip/hip_runtime.h>

#define NBATCH 16
#define NN 128
#define NH 128
#define NL 127
#define NDX 11
#define NDE 4
#define LDA 132
#define LDB 129
#define LDT 132
#define WS_STRIDE 66560  // floats per batch in wsG

// per-batch workspace float offsets
#define OFF_AREF 0
#define OFF_Q0   16384
#define OFF_Q1   32768
#define OFF_S    49152
#define OFF_DV   65536
#define OFF_EV   65664
#define OFF_TAU  65792
#define OFF_ORG  65920
#define OFF_META 66048   // 512 floats of int metadata

// ---------------- LAPACK fp32 helper ports ----------------
#define EPS32 5.9604645e-8f
#define EPS232 3.5527137e-15f
#define SAFMIN32 1.17549435e-38f

__device__ __forceinline__ float ssign_(float a, float b) {
  return (b >= 0.0f) ? fabsf(a) : -fabsf(a);
}
__device__ __forceinline__ float slapy2_(float x, float y) {
  float ax = fabsf(x), ay = fabsf(y);
  float w = fmaxf(ax, ay), z = fminf(ax, ay);
  if (z == 0.0f) return w;
  float q = z / w;
  return w * sqrtf(1.0f + q * q);
}

// broadcast-read lane `src`'s value of v (uniform src -> v_readlane, scalar pipe)
__device__ __forceinline__ float rdl(float v, int src) {
  return __int_as_float(__builtin_amdgcn_readlane(__float_as_int(v), src));
}

// rsqrt-based Givens (k_leaves only; args O(1) after orgnrm scaling).
__device__ __forceinline__ void slartg_(float f, float g, float* c, float* s, float* r) {
  if (g == 0.0f) { *c = 1.0f; *s = 0.0f; *r = f; }
  else if (f == 0.0f) { *c = 0.0f; *s = (g >= 0.0f) ? 1.0f : -1.0f; *r = fabsf(g); }
  else {
    float t2 = f * f + g * g;
    float inv = rsqrtf(t2);
    if (f < 0.0f) inv = -inv;
    *c = f * inv; *s = g * inv; *r = t2 * inv;
  }
}

__device__ void slaev2_(float a, float b, float c0, float* rt1, float* rt2,
                        float* cs1, float* sn1) {
  float sm = a + c0, df = a - c0, adf = fabsf(df), tb = b + b, ab = fabsf(tb);
  float acmx, acmn;
  if (fabsf(a) > fabsf(c0)) { acmx = a; acmn = c0; } else { acmx = c0; acmn = a; }
  float rt;
  if (adf > ab) { float q = ab / adf; rt = adf * sqrtf(1.0f + q * q); }
  else if (adf < ab) { float q = adf / ab; rt = ab * sqrtf(1.0f + q * q); }
  else rt = ab * sqrtf(2.0f);
  int sgn1;
  if (sm < 0.0f) { *rt1 = 0.5f * (sm - rt); sgn1 = -1; *rt2 = (acmx / *rt1) * acmn - (b / *rt1) * b; }
  else if (sm > 0.0f) { *rt1 = 0.5f * (sm + rt); sgn1 = 1; *rt2 = (acmx / *rt1) * acmn - (b / *rt1) * b; }
  else { *rt1 = 0.5f * rt; *rt2 = -0.5f * rt; sgn1 = 1; }
  int sgn2; float cs;
  if (df >= 0.0f) { cs = df + rt; sgn2 = 1; } else { cs = df - rt; sgn2 = -1; }
  float acs = fabsf(cs);
  if (acs > ab) { float ct = -tb / cs; *sn1 = 1.0f / sqrtf(1.0f + ct * ct); *cs1 = ct * (*sn1); }
  else {
    if (ab == 0.0f) { *cs1 = 1.0f; *sn1 = 0.0f; }
    else { float tn = -cs / tb; *cs1 = 1.0f / sqrtf(1.0f + tn * tn); *sn1 = tn * (*cs1); }
  }
  if (sgn1 == sgn2) { float tn = *cs1; *cs1 = -(*sn1); *sn1 = tn; }
}

// ============ K1: Laplacian build + ssytd2 tridiagonalization ============
// v7 (R10, measured best 325us): 512 threads, R9 4-barrier schedule,
// LDA=132, shfl readbacks.
__global__ __launch_bounds__(512) void k_tridiag(const float* __restrict__ A_in,
                                                 float* __restrict__ wsG) {
  const int b = blockIdx.x, t = threadIdx.x;
  float* Aref = wsG + (size_t)b * WS_STRIDE;
  float* dv = Aref + OFF_DV;
  float* ev = Aref + OFF_EV;
  float* tg = Aref + OFF_TAU;
  float* og = Aref + OFF_ORG;
  extern __shared__ float As[];  // [128][LDA], LDA=132
  __shared__ unsigned int maskp[128][4];
  __shared__ unsigned int Dp[128][4];
  __shared__ unsigned long long adj0_[128], adj1_[128];
  __shared__ float Dd_[128], tDs_[128];
  __shared__ float d_[128], e_[128], tau_[128];
  __shared__ alignas(16) float v_[128];
  __shared__ alignas(16) float w_[128];
  __shared__ float pmat[4][128];
  __shared__ alignas(16) float red_[16];
  __shared__ float xp[16];

  const int wid = t >> 6;        // wave id 0..7
  const int lane = t & 63;
  // ---- adjacency build: 4 threads per row, 32 m's each ----
  {
    const int r8 = t >> 2, s8 = t & 3;
    const float4* Arow = (const float4*)(A_in + (size_t)(b * 128 + r8) * 128 * 4);
    unsigned int mloc = 0; unsigned int cnt = 0;
    const int m0 = s8 * 32;
    #pragma unroll 4
    for (int mm = 0; mm < 32; ++mm) {
      float4 a = Arow[m0 + mm];
      if (a.x != 0.f || a.y != 0.f || a.z != 0.f || a.w != 0.f) { mloc |= 1u << mm; cnt++; }
    }
    maskp[r8][s8] = mloc; Dp[r8][s8] = cnt;
  }
  __syncthreads();
  if (t < 128) {
    unsigned long long b0 = (unsigned long long)maskp[t][0] |
                            ((unsigned long long)maskp[t][1] << 32);
    unsigned long long b1 = (unsigned long long)maskp[t][2] |
                            ((unsigned long long)maskp[t][3] << 32);
    unsigned int D = Dp[t][0] + Dp[t][1] + Dp[t][2] + Dp[t][3];
    adj0_[t] = b0; adj1_[t] = b1;
    float Df = (float)D;
    Dd_[t] = Df;
    tDs_[t] = 1.0f / sqrtf(fmaxf(Df, 1.0f));
  }
  __syncthreads();
  for (int idx = t; idx < 16384; idx += 512) {
    int r = idx >> 7, c = idx & 127;
    if (c <= r) {
      float adj = (float)((c < 64 ? (adj0_[r] >> c) : (adj1_[r] >> (c - 64))) & 1ull);
      float Lrc = ((c == r) ? Dd_[r] : 0.0f) - adj;
      float val = (tDs_[c] * Lrc) * tDs_[r];
      As[r * LDA + c] = val;
      As[c * LDA + r] = val;
    }
  }
  __syncthreads();

  const int rmv = t & 127;   // matvec row
  const int smv = t >> 7;    // matvec segment 0..3 (32 cols each)
  const int ucg = t & 31;    // update col-group (4 cols)
  const int urs = t >> 5;    // update row stripe 0..15

  bool usexp = false;
  for (int i = 0; i < 127; ++i) {
    const int lo = i + 1;
    // ---- xnorm2 of column i below subdiagonal ----
    float xnorm2;
    if (!usexp) {           // uniform fallback path (iter 0 / after taui==0)
      float part = 0.0f;
      if (t < 128 && t >= i + 2) { float x = As[t * LDA + i]; part = x * x; }
      if (wid < 2) {
        #pragma unroll
        for (int m = 1; m < 64; m <<= 1) part += __shfl_xor(part, m);
        if (lane == 0) red_[wid] = part;
      }
      __syncthreads();   // S1 (fallback only)
      xnorm2 = red_[0] + red_[1];
    } else {               // piggybacked: 1 LDS read + shfl tree (sum of 16)
      float s = xp[lane & 15];
      #pragma unroll
      for (int m = 1; m < 16; m <<= 1) s += __shfl_xor(s, m);
      xnorm2 = s;
    }
    float alpha = As[lo * LDA + i];   // row lo never written in phase B
    float beta, taui, scal;
    if (xnorm2 == 0.0f) { taui = 0.0f; beta = alpha; scal = 0.0f; }
    else {
      float xn = sqrtf(xnorm2);
      beta = -ssign_(slapy2_(alpha, xn), alpha);
      taui = (beta - alpha) / beta;
      scal = 1.0f / (alpha - beta);
    }
    if (t == 0) { e_[i] = beta; tau_[i] = taui; }
    if (taui != 0.0f) {    // uniform branch
      // ---- phase B: single-writer v construction ----
      if (t < 128) {
        float vv = 0.0f;
        if (t == lo) vv = 1.0f;
        else if (t > lo) { float xi = As[t * LDA + i]; vv = xi * scal; As[t * LDA + i] = vv; }
        v_[t] = vv;
      }
      __syncthreads();   // S2
      // ---- phase C: matvec partials (32-col chunk) + vpdot partial ----
      const int c0 = smv * 32;
      float acc = 0.0f;
      if (c0 + 31 >= lo && rmv >= lo) {
        const float4* Ar = (const float4*)&As[rmv * LDA + c0];
        const float4* Vr = (const float4*)&v_[c0];
        #pragma unroll
        for (int k = 0; k < 8; ++k) {
          float4 a = Ar[k], v4 = Vr[k];
          acc += a.x * v4.x + a.y * v4.y + a.z * v4.z + a.w * v4.w;
        }
      }
      pmat[smv][rmv] = acc;
      float p2 = v_[rmv] * acc;
      #pragma unroll
      for (int m = 1; m < 64; m <<= 1) p2 += __shfl_xor(p2, m);
      if (lane == 0) red_[wid] = p2;
      __syncthreads();   // S3
      // ---- phase D: w = taui*(Av); a2 via shfl-sum of red_[0..7] ----
      float vpr = red_[lane & 7];
      #pragma unroll
      for (int m = 1; m < 8; m <<= 1) vpr += __shfl_xor(vpr, m);
      float a2 = -0.5f * taui * (taui * vpr);
      if (t < 128) {
        float pv = pmat[0][t] + pmat[1][t] + pmat[2][t] + pmat[3][t];
        w_[t] = taui * pv;
      }
      __syncthreads();   // S4
      // ---- phase E: rank-2 update + next-xnorm piggyback ----
      const int uc0 = ucg * 4;
      if (uc0 + 3 >= lo) {
        float4 vc = *(const float4*)&v_[uc0];
        float4 wc = *(const float4*)&w_[uc0];
        float pcx = wc.x + a2 * vc.x;
        float pcy = wc.y + a2 * vc.y;
        float pcz = wc.z + a2 * vc.z;
        float pcw = wc.w + a2 * vc.w;
        if (uc0 < lo) {   // partial chunk: neutralize components left of lo
          if (uc0 + 0 < lo) { vc.x = 0.f; pcx = 0.f; }
          if (uc0 + 1 < lo) { vc.y = 0.f; pcy = 0.f; }
          if (uc0 + 2 < lo) { vc.z = 0.f; pcz = 0.f; }
        }
        const bool isxcol = (ucg == (lo >> 2));
        const int xc = lo & 3;
        float xpacc = 0.0f;
        #pragma unroll
        for (int k = 0; k < 8; ++k) {
          int r = urs + 16 * k;
          if (r >= lo) {
            float vr = v_[r];
            float pr = w_[r] + a2 * vr;
            float4 a = *(const float4*)&As[r * LDA + uc0];
            a.x -= vr * pcx + pr * vc.x;
            a.y -= vr * pcy + pr * vc.y;
            a.z -= vr * pcz + pr * vc.z;
            a.w -= vr * pcw + pr * vc.w;
            *(float4*)&As[r * LDA + uc0] = a;
            if (isxcol && r >= lo + 2) {
              float nc = (xc == 0) ? a.x : ((xc == 1) ? a.y : ((xc == 2) ? a.z : a.w));
              xpacc += nc * nc;
            }
          }
        }
        if (isxcol) xp[urs] = xpacc;
      }
    }
    __syncthreads();   // S5
    usexp = (taui != 0.0f);
  }
  if (t < 128) d_[t] = As[t * LDA + t];
  __syncthreads();

  {
    float mx = 0.0f;
    if (t < 128) mx = fabsf(d_[t]);
    if (t < 127) mx = fmaxf(mx, fabsf(e_[t]));
    if (wid < 2) {
      #pragma unroll
      for (int m = 1; m < 64; m <<= 1) mx = fmaxf(mx, __shfl_xor(mx, m));
      if (lane == 0) red_[wid] = mx;
    }
    __syncthreads();
  }
  float orgnrm = fmaxf(red_[0], red_[1]);
  if (orgnrm == 0.0f) orgnrm = 1.0f;
  float invnrm = 1.0f / orgnrm;
  if (t < 128) d_[t] *= invnrm;
  if (t < 127) e_[t] *= invnrm;
  __syncthreads();
  if (t == 0) {
    for (int bm = 16; bm < 128; bm += 16) {
      float ae = fabsf(e_[bm - 1]);
      d_[bm - 1] -= ae; d_[bm] -= ae;
    }
  }
  __syncthreads();
  for (int idx = t; idx < 16384; idx += 512)
    Aref[idx] = As[(idx >> 7) * LDA + (idx & 127)];
  if (t < 128) { dv[t] = d_[t]; tg[t] = tau_[t]; }
  if (t < 127) ev[t] = e_[t];
  if (t == 0) og[0] = orgnrm;
}

// ============ K2: 8 leaves x 16 batches, one block each ============
// v5: lane-register ssteqr + rsqrt slartg + BALLOT-parallel scans:
// every "first index where predicate" scan (outer deflation, QL/QR split)
// is one ballot + ffs/clz instead of a serial readlane chain; range-max via
// 64-lane shfl_xor (lanes>=16 contribute 0 -> convergent). Identical float
// predicates -> identical iteration sequence as v4.
__global__ __launch_bounds__(64) void k_leaves(float* __restrict__ wsG) {
  int b = blockIdx.x >> 3, lf = blockIdx.x & 7;
  float* base = wsG + (size_t)b * WS_STRIDE;
  float* Qg = base + OFF_Q0;
  float* dv = base + OFF_DV;
  float* ev = base + OFF_EV;
  const int ln = threadIdx.x;
  __shared__ float zsh[16 * 17];

  const int n = 16;
  float dreg = (ln < 16) ? dv[lf * 16 + ln] : 0.f;
  float ereg = (ln < 15) ? ev[lf * 16 + ln] : 0.f;
  float csreg = 0.f, snreg = 0.f;
  float zr[16];
  #pragma unroll
  for (int c = 0; c < 16; ++c) zr[c] = (ln == c) ? 1.0f : 0.0f;

  {
    const float eps = EPS32, eps2 = EPS232, safmin = SAFMIN32;
    int nmaxit = n * 30, jtot = 0;
    int l1 = 0;
    while (l1 <= n - 1) {
      if (l1 > 0 && ln == l1 - 1) ereg = 0.0f;
      // ---- ballot outer deflation scan over m in [l1, n-2] ----
      int m;
      {
        float dn1 = __shfl_down(dreg, 1);   // d[ln+1]
        float tst = fabsf(ereg);
        bool cond = (tst == 0.0f) ||
                    (tst <= (sqrtf(fabsf(dreg)) * sqrtf(fabsf(dn1))) * eps);
        unsigned long long mask = __ballot(cond);
        unsigned long long rng = ((1ull << (n - 1)) - 1) & ~((1ull << l1) - 1);
        mask &= rng;
        m = mask ? (__ffsll(mask) - 1) : (n - 1);
        // zeroing is a no-op when the hit was tst==0 (e already 0)
        if (mask && ln == m) ereg = 0.0f;
      }
      int l = l1, lend = m;
      l1 = m + 1;
      if (lend == l) continue;
      {
        // ---- 64-lane range-max (abs) over d[l..lend], e[l..lend-1] ----
        float av = (ln >= l && ln <= lend) ? fabsf(dreg) : 0.0f;
        if (ln >= l && ln <= lend - 1) av = fmaxf(av, fabsf(ereg));
        #pragma unroll
        for (int mm = 1; mm < 64; mm <<= 1) av = fmaxf(av, __shfl_xor(av, mm));
        if (av == 0.0f) continue;
      }
      if (fabsf(rdl(dreg, lend)) < fabsf(rdl(dreg, l))) { int tsw = l; l = lend; lend = tsw; }
      if (lend > l) {
        while (true) {  // QL
          // ---- ballot split scan: lowest m2 in [l, lend-1] ----
          int m2;
          if (l != lend) {
            float dn1 = __shfl_down(dreg, 1);
            bool cond = (ereg * ereg) <= (eps2 * fabsf(dreg)) * fabsf(dn1) + safmin;
            unsigned long long mask = __ballot(cond) &
                (((1ull << lend) - 1) & ~((1ull << l) - 1));
            m2 = mask ? (__ffsll(mask) - 1) : lend;
          } else m2 = lend;
          if (m2 < lend && ln == m2) ereg = 0.0f;
          float p = rdl(dreg, l);
          if (m2 == l) { l++; if (l <= lend) continue; else break; }
          if (m2 == l + 1) {
            float rt1, rt2, c, s;
            slaev2_(rdl(dreg, l), rdl(ereg, l), rdl(dreg, l + 1), &rt1, &rt2, &c, &s);
            #pragma unroll
            for (int j = 0; j < 15; ++j) {
              if (j == l) {
                float t1 = zr[j + 1];
                zr[j + 1] = c * t1 - s * zr[j];
                zr[j] = s * t1 + c * zr[j];
              }
            }
            if (ln == l) { dreg = rt1; ereg = 0.0f; }
            if (ln == l + 1) dreg = rt2;
            l += 2; if (l <= lend) continue; else break;
          }
          if (jtot == nmaxit) break;
          jtot++;
          float g = (rdl(dreg, l + 1) - p) / (2.0f * rdl(ereg, l));
          float r = slapy2_(g, 1.0f);
          g = rdl(dreg, m2) - p + rdl(ereg, l) / (g + ssign_(r, g));
          float s = 1.0f, c = 1.0f; p = 0.0f;
          for (int i = m2 - 1; i >= l; --i) {
            float ei = rdl(ereg, i);
            float f = s * ei, bb = c * ei;
            slartg_(g, f, &c, &s, &r);
            if (i != m2 - 1 && ln == i + 1) ereg = r;
            g = rdl(dreg, i + 1) - p;
            r = (rdl(dreg, i) - g) * s + 2.0f * c * bb;
            p = s * r;
            if (ln == i + 1) dreg = g + p;
            g = c * r - bb;
            if (ln == i) { csreg = c; snreg = -s; }
          }
          #pragma unroll
          for (int j = 14; j >= 0; --j) {
            if (j <= m2 - 1 && j >= l) {
              float cj = rdl(csreg, j), sj = rdl(snreg, j);
              float t1 = zr[j + 1];
              zr[j + 1] = cj * t1 - sj * zr[j];
              zr[j] = sj * t1 + cj * zr[j];
            }
          }
          if (ln == l) { dreg = dreg - p; ereg = g; }
        }
      } else {
        while (true) {  // QR
          // ---- ballot split scan: highest m2 in [lend+1, l] ----
          int m2;
          if (l != lend) {
            float ep = __shfl_up(ereg, 1);   // e[ln-1]
            float dp = __shfl_up(dreg, 1);   // d[ln-1]
            bool cond = (ep * ep) <= (eps2 * fabsf(dreg)) * fabsf(dp) + safmin;
            unsigned long long mask = __ballot(cond) &
                (((1ull << (l + 1)) - 1) & ~((1ull << (lend + 1)) - 1));
            m2 = mask ? (63 - __clzll(mask)) : lend;
          } else m2 = lend;
          if (m2 > lend && ln == m2 - 1) ereg = 0.0f;
          float p = rdl(dreg, l);
          if (m2 == l) { l--; if (l >= lend) continue; else break; }
          if (m2 == l - 1) {
            float rt1, rt2, c, s;
            slaev2_(rdl(dreg, l - 1), rdl(ereg, l - 1), rdl(dreg, l), &rt1, &rt2, &c, &s);
            #pragma unroll
            for (int j = 0; j < 15; ++j) {
              if (j == l - 1) {
                float t1 = zr[j + 1];
                zr[j + 1] = c * t1 - s * zr[j];
                zr[j] = s * t1 + c * zr[j];
              }
            }
            if (ln == l - 1) { dreg = rt1; ereg = 0.0f; }
            if (ln == l) dreg = rt2;
            l -= 2; if (l >= lend) continue; else break;
          }
          if (jtot == nmaxit) break;
          jtot++;
          float g = (rdl(dreg, l - 1) - p) / (2.0f * rdl(ereg, l - 1));
          float r = slapy2_(g, 1.0f);
          g = rdl(dreg, m2) - p + rdl(ereg, l - 1) / (g + ssign_(r, g));
          float s = 1.0f, c = 1.0f; p = 0.0f;
          for (int i = m2; i <= l - 1; ++i) {
            float ei = rdl(ereg, i);
            float f = s * ei, bb = c * ei;
            slartg_(g, f, &c, &s, &r);
            if (i != m2 && ln == i - 1) ereg = r;
            g = rdl(dreg, i) - p;
            r = (rdl(dreg, i + 1) - g) * s + 2.0f * c * bb;
            p = s * r;
            if (ln == i) dreg = g + p;
            g = c * r - bb;
            if (ln == i) { csreg = c; snreg = s; }
          }
          #pragma unroll
          for (int j = 0; j <= 14; ++j) {
            if (j >= m2 && j <= l - 1) {
              float cj = rdl(csreg, j), sj = rdl(snreg, j);
              float t1 = zr[j + 1];
              zr[j + 1] = cj * t1 - sj * zr[j];
              zr[j] = sj * t1 + cj * zr[j];
            }
          }
          if (ln == l) dreg = dreg - p;
          if (ln == l - 1) ereg = g;
        }
      }
    }
  }

  // stage z rows to LDS for sort + band write
  if (ln < 16) {
    #pragma unroll
    for (int c = 0; c < 16; ++c) zsh[ln * 17 + c] = zr[c];
  }
  __syncthreads();
  // selection sort: d in lane registers, z column swaps row-parallel in LDS
  for (int ii = 1; ii <= n - 1; ++ii) {
    int i = ii - 1, k = i;
    float p = rdl(dreg, i);
    for (int j = ii; j <= n - 1; ++j) {
      float dj = rdl(dreg, j);
      if (dj < p) { k = j; p = dj; }
    }
    if (k != i) {
      float di = rdl(dreg, i);
      if (ln == k) dreg = di;
      if (ln == i) dreg = p;
      if (ln < 16) {
        float t1 = zsh[ln * 17 + i];
        zsh[ln * 17 + i] = zsh[ln * 17 + k];
        zsh[ln * 17 + k] = t1;
      }
    }
  }
  __syncthreads();
  if (ln < 16) dv[lf * 16 + ln] = dreg;
  // write only the 32-col merge band: cols bo..bo+31 where bo=(lf>>1)*32
  {
    const int bo = (lf >> 1) * 32;
    const int cofs = (lf & 1) * 16;   // local col offset of this leaf in band
    for (int idx = ln; idx < 16 * 32; idx += 64) {
      int rr = idx >> 5, c = idx & 31;
      int cl = c - cofs;
      float v = (cl >= 0 && cl < 16) ? zsh[rr * 17 + cl] : 0.f;
      Qg[(size_t)(lf * 16 + rr) * 128 + bo + c] = v;
    }
  }
}

// ============ K3a: merge metadata/secular per (batch, merge) ============
// v3: register bisection 36 iters.
template <int LVL>
__global__ __launch_bounds__(1024) void k_mergeA(float* __restrict__ wsG, int qoff) {
  constexpr int sh = 2 - LVL;
  constexpr int nm = 32 << LVL;     // merged size n
  constexpr int LPR = 1024 / nm;    // lanes per root: 32/16/8
  constexpr int NCH = nm / LPR;     // chunk regs per lane: 1/4/16
  int b = blockIdx.x >> sh;
  int mg = blockIdx.x & ((1 << sh) - 1);
  int bo = mg * nm, n1 = nm >> 1, n = nm;
  const int t = threadIdx.x;
  float* base = wsG + (size_t)b * WS_STRIDE;
  float* Qin = base + qoff;
  float* dvg = base + OFF_DV;
  float* evg = base + OFF_EV;
  float* Sg  = base + OFF_S;
  int* meta = (int*)(base + OFF_META);
  int* undG = meta; int* idxpG = meta + 128; int* finG = meta + 256; int* KfG = meta + 384;

  __shared__ float d_[128], z_[128], dl_[128], w_[128], zh_[128], lam_[128], tauv_[128], dnew_[128];
  __shared__ int srt_[128], indxp_[128], und_[128], anc_[128], fin_[128];
  __shared__ int gp_[128], gq_[128];
  __shared__ float gc_[128], gs_[128];
  __shared__ int sci[4];

  if (t < n) d_[t] = dvg[bo + t];
  float rho_in = evg[bo + n1 - 1];
  if (t < n) {
    float zv = (t < n1) ? Qin[(size_t)(bo + n1 - 1) * 128 + bo + t]
                        : Qin[(size_t)(bo + n1) * 128 + bo + t];
    if (rho_in < 0.0f && t >= n1) zv = -zv;
    z_[t] = zv * 0.70710678f;
  }
  __syncthreads();
  float rho = fabsf(2.0f * rho_in);
  if (t == 0) {
    int i1 = 0, i2 = n1, k = 0;
    while (i1 < n1 && i2 < n) {
      if (d_[i1] <= d_[i2]) srt_[k++] = i1++; else srt_[k++] = i2++;
    }
    while (i1 < n1) srt_[k++] = i1++;
    while (i2 < n) srt_[k++] = i2++;
    float zmax = 0.0f, dmax = 0.0f;
    for (int i = 0; i < n; ++i) {
      zmax = fmaxf(zmax, fabsf(z_[i]));
      dmax = fmaxf(dmax, fabsf(d_[i]));
    }
    float tol = 8.0f * EPS32 * fmaxf(dmax, zmax);
    int K = 0, k2 = n, full = 0, ngiv = 0;
    if (rho * zmax <= tol) full = 1;
    else {
      int pj = -1, jj = 0;
      for (; jj < n; ++jj) {
        int nj = srt_[jj];
        if (rho * fabsf(z_[nj]) <= tol) { k2--; indxp_[k2] = nj; }
        else { pj = nj; break; }
      }
      if (pj < 0) full = 1;
      else {
        for (jj = jj + 1; jj < n; ++jj) {
          int nj = srt_[jj];
          if (rho * fabsf(z_[nj]) <= tol) { k2--; indxp_[k2] = nj; }
          else {
            float s = z_[pj], c = z_[nj];
            float tauq = slapy2_(c, s);
            float tdf = d_[nj] - d_[pj];
            c /= tauq; s = -s / tauq;
            if (fabsf(tdf * c * s) <= tol) {
              z_[nj] = tauq; z_[pj] = 0.0f;
              gp_[ngiv] = pj; gq_[ngiv] = nj; gc_[ngiv] = c; gs_[ngiv] = s; ngiv++;
              float tt2 = d_[pj] * c * c + d_[nj] * s * s;
              d_[nj] = d_[pj] * s * s + d_[nj] * c * c;
              d_[pj] = tt2;
              k2--;
              int pos = k2;
              while (pos + 1 <= n - 1 && d_[pj] < d_[indxp_[pos + 1]]) {
                indxp_[pos] = indxp_[pos + 1]; pos++;
              }
              indxp_[pos] = pj;
              pj = nj;
            } else {
              dl_[K] = d_[pj]; w_[K] = z_[pj]; und_[K] = pj; K++;
              pj = nj;
            }
          }
        }
        dl_[K] = d_[pj]; w_[K] = z_[pj]; und_[K] = pj; K++;
      }
    }
    sci[0] = K; sci[1] = full; sci[2] = ngiv;
  }
  __syncthreads();
  int K = sci[0], full = sci[1], ngiv = sci[2];
  if (!full) {
    // Givens rotations applied row-parallel to global Q (same per-row op order)
    if (t < n) {
      size_t rowoff = (size_t)(bo + t) * 128 + bo;
      for (int g = 0; g < ngiv; ++g) {
        float c = gc_[g], s = gs_[g];
        float xq = Qin[rowoff + gp_[g]], yq = Qin[rowoff + gq_[g]];
        Qin[rowoff + gp_[g]] = c * xq + s * yq;
        Qin[rowoff + gq_[g]] = c * yq - s * xq;
      }
    }
    // ---- lane-group secular solve: root j = t/LPR, sub-lane sub = t%LPR ----
    const int j = t / LPR;
    const int sub = t % LPR;
    const bool act = (j < K);
    float dl_loc[NCH], w2_loc[NCH];
    float tauj_reg = 0.0f; float da_reg = 0.0f;
    if (act) {
      #pragma unroll
      for (int k = 0; k < NCH; ++k) {
        int i = sub + k * LPR;
        if (i < K) { dl_loc[k] = dl_[i]; float wi = w_[i]; w2_loc[k] = rho * wi * wi; }
        else { dl_loc[k] = 3.0e38f; w2_loc[k] = 0.0f; }   // term -> 0, no NaN
      }
      // zsum (already rho-scaled)
      float zs = 0.0f;
      #pragma unroll
      for (int k = 0; k < NCH; ++k) zs += w2_loc[k];
      #pragma unroll
      for (int m = 1; m < LPR; m <<= 1) zs += __shfl_xor(zs, m);
      // anchor decision
      int a; float lo2, hi2;
      if (j < K - 1) {
        float dj = dl_[j];
        float tm = 0.5f * (dl_[j + 1] - dj);
        float fm = 0.0f;
        #pragma unroll
        for (int k = 0; k < NCH; ++k) fm += w2_loc[k] / ((dl_loc[k] - dj) - tm);
        #pragma unroll
        for (int m = 1; m < LPR; m <<= 1) fm += __shfl_xor(fm, m);
        fm += 1.0f;
        if (fm >= 0.0f) { a = j; lo2 = 0.0f; hi2 = tm; }
        else { a = j + 1; lo2 = -tm; hi2 = 0.0f; }
      } else { a = K - 1; lo2 = 0.0f; hi2 = zs + 1e-30f; }
      float da = dl_[a];
      float sdl[NCH];
      #pragma unroll
      for (int k = 0; k < NCH; ++k) sdl[k] = dl_loc[k] - da;
      for (int it2 = 0; it2 < 36; ++it2) {
        float tc = 0.5f * (lo2 + hi2);
        float f = 0.0f;
        #pragma unroll
        for (int k = 0; k < NCH; ++k) f += w2_loc[k] / (sdl[k] - tc);
        #pragma unroll
        for (int m = 1; m < LPR; m <<= 1) f += __shfl_xor(f, m);
        f += 1.0f;
        if (f >= 0.0f) hi2 = tc; else lo2 = tc;
      }
      tauj_reg = 0.5f * (lo2 + hi2);
      da_reg = da;
      if (sub == 0) { lam_[j] = da + tauj_reg; tauv_[j] = tauj_reg; anc_[j] = a; }
    }
    __syncthreads();
    // Gu's sign-preserving z-hat (root i = j of this octet; chunk over jj)
    if (act) {
      float di = dl_[j];
      float pp = 1.0f;
      #pragma unroll
      for (int k = 0; k < NCH; ++k) {
        int jj = sub + k * LPR;
        if (jj < K && jj != j) {
          float delta_ij = (di - dl_[anc_[jj]]) - tauv_[jj];
          pp *= delta_ij / (di - dl_[jj]);
        }
      }
      #pragma unroll
      for (int m = 1; m < LPR; m <<= 1) pp *= __shfl_xor(pp, m);
      if (sub == 0) {
        float lead = (di - da_reg) - tauj_reg;
        float acc = lead * pp;
        zh_[j] = ssign_(sqrtf(fmaxf(-acc, 0.0f)), w_[j]);
      }
    }
    __syncthreads();
    // rank-1 system eigenvectors, chunked per lane, single scaled store
    if (act) {
      float sv[NCH]; float nrm = 0.0f;
      #pragma unroll
      for (int k = 0; k < NCH; ++k) {
        int i = sub + k * LPR;
        float s = 0.0f;
        if (i < K) s = zh_[i] / ((dl_loc[k] - da_reg) - tauj_reg);
        sv[k] = s; nrm += s * s;
      }
      #pragma unroll
      for (int m = 1; m < LPR; m <<= 1) nrm += __shfl_xor(nrm, m);
      nrm = 1.0f / sqrtf(nrm);
      float* scol = Sg + bo + j;
      #pragma unroll
      for (int k = 0; k < NCH; ++k) {
        int i = sub + k * LPR;
        if (i < K) scol[(size_t)(bo + i) * 128] = sv[k] * nrm;
      }
    }
    if (t == 0) {
      for (int jj = 0; jj < K; ++jj) dnew_[jj] = lam_[jj];
      for (int m = 0; m < n - K; ++m) dnew_[K + m] = d_[indxp_[n - 1 - m]];
      int i1 = 0, i2 = K, k = 0;
      while (i1 < K && i2 < n) { if (dnew_[i1] <= dnew_[i2]) fin_[k++] = i1++; else fin_[k++] = i2++; }
      while (i1 < K) fin_[k++] = i1++;
      while (i2 < n) fin_[k++] = i2++;
    }
    __syncthreads();
    if (t < n) {
      dvg[bo + t] = dnew_[fin_[t]];
      idxpG[bo + t] = indxp_[t];
      finG[bo + t] = fin_[t];
    }
    if (t < K) undG[bo + t] = und_[t];
    if (t == 0) KfG[mg] = K;
  } else {
    if (t < n) {
      dvg[bo + t] = d_[srt_[t]];
      idxpG[bo + t] = srt_[n - 1 - t];
      finG[bo + t] = t;
    }
    if (t == 0) KfG[mg] = 0;
  }
}

// ============ K3b: merge GEMM/permute, 32 rows per block ============
// v2: 512 threads (8 waves = 2/SIMD).
__global__ __launch_bounds__(512) void k_mergeB(float* __restrict__ wsG, int lvl,
                                                int qinoff, int qoutoff) {
  int b = blockIdx.x >> 2;
  int rblk = blockIdx.x & 3;
  int rbase = rblk * 32;
  int nm = 32 << lvl;
  int ln2 = 5 + lvl;
  int mg = rbase >> ln2;
  int bo = mg * nm, n = nm;
  const int t = threadIdx.x;
  float* base = wsG + (size_t)b * WS_STRIDE;
  const float* Qin = base + qinoff;
  float* Qout = base + qoutoff;
  const float* Sg = base + OFF_S;
  const int* meta = (const int*)(base + OFF_META);
  const int* undG = meta; const int* idxpG = meta + 128;
  const int* finG = meta + 256; const int* KfG = meta + 384;

  extern __shared__ float lds[];
  float* QT = lds;                 // [32][LDB]
  float* QC = QT + 32 * LDB;       // [32][LDB]
  float* WT = QC + 32 * LDB;       // [32][LDB]
  float* ST = WT + 32 * LDB;       // [128][LDB]
  __shared__ int und_l[128], idxp_l[128], fin_l[128];
  __shared__ int Ksh;

  if (t == 0) Ksh = KfG[mg];
  if (t < n) { und_l[t] = undG[bo + t]; idxp_l[t] = idxpG[bo + t]; fin_l[t] = finG[bo + t]; }
  for (int idx = t; idx < 32 * n; idx += 512) {
    int r = idx >> ln2, c = idx & (n - 1);
    QT[r * LDB + c] = Qin[(size_t)(rbase + r) * 128 + bo + c];
  }
  __syncthreads();
  int K = Ksh;
  for (int idx = t; idx < (K << 7); idx += 512) {
    int k = idx >> 7, j = idx & 127;
    ST[k * LDB + j] = Sg[(size_t)(bo + k) * 128 + bo + j];
  }
  for (int r = 0; r < 32; ++r)
    if (t < K) QC[r * LDB + t] = QT[r * LDB + und_l[t]];
  __syncthreads();
  for (int idx = t; idx < 32 * n; idx += 512) {
    int r = idx >> ln2, j = idx & (n - 1);
    float v;
    if (j < K) {
      float a0 = 0.f, a1 = 0.f, a2 = 0.f, a3 = 0.f;
      int k = 0;
      for (; k + 3 < K; k += 4) {
        a0 += QC[r * LDB + k]     * ST[k * LDB + j];
        a1 += QC[r * LDB + k + 1] * ST[(k + 1) * LDB + j];
        a2 += QC[r * LDB + k + 2] * ST[(k + 2) * LDB + j];
        a3 += QC[r * LDB + k + 3] * ST[(k + 3) * LDB + j];
      }
      for (; k < K; ++k) a0 += QC[r * LDB + k] * ST[k * LDB + j];
      v = (a0 + a1) + (a2 + a3);
    } else {
      v = QT[r * LDB + idxp_l[n - 1 - (j - K)]];
    }
    WT[r * LDB + j] = v;
  }
  __syncthreads();
  for (int idx = t; idx < 32 * 128; idx += 512) {
    int r = idx >> 7, c = idx & 127;
    int cl = c - bo;
    float v = 0.f;
    if (cl >= 0 && cl < n) v = WT[r * LDB + fin_l[cl]];
    Qout[(size_t)(rbase + r) * 128 + c] = v;
  }
}

// ============ K4: back-transform + outputs ============
// v2: 1024 threads, 16 waves; Q register-resident, barrier-free reflector loop.
__global__ __launch_bounds__(1024) void k_back(
    float* __restrict__ wsG, const unsigned char* __restrict__ nodemask,
    const float* __restrict__ mu, const float* __restrict__ isg,
    float* __restrict__ wsUt, float* __restrict__ wsLam,
    float* __restrict__ outEmb, float* __restrict__ outLmask) {
  const int b = blockIdx.x, t = threadIdx.x;
  float* base = wsG + (size_t)b * WS_STRIDE;
  float* Qg = base + OFF_Q1;
  float* dvg = base + OFF_DV;
  float* tg = base + OFF_TAU;
  float* og = base + OFF_ORG;
  extern __shared__ float lds[];
  float* At = lds;                 // [128][LDT]: At[c*LDT+r] = Aref[r][c]
  float* Qt = lds + 128 * LDT;     // [128][LDT]: Qt[c*LDT+r] = Q[r][c]
  __shared__ float d_[128], tau_[128];
  __shared__ unsigned char nm_[128];

  float orgnrm = og[0];
  for (int idx = t; idx < 16384; idx += 1024) {
    int r = idx >> 7, c = idx & 127;
    At[c * LDT + r] = base[idx];   // Aref transpose-staged
    Qt[c * LDT + r] = Qg[idx];
  }
  if (t < 128) {
    d_[t] = dvg[t] * orgnrm;
    tau_[t] = tg[t];
    nm_[t] = nodemask[b * 128 + t];
  }
  __syncthreads();

  // ---- register-resident back-transform ----
  const int w = t >> 6, l = t & 63;
  const int cidx = l & 7, sg = l >> 3;
  const int c = w * 8 + cidx;
  float q[16];
  #pragma unroll
  for (int k = 0; k < 4; ++k) {
    float4 v = *(const float4*)&Qt[c * LDT + 4 * sg + 32 * k];
    q[4 * k + 0] = v.x; q[4 * k + 1] = v.y; q[4 * k + 2] = v.z; q[4 * k + 3] = v.w;
  }
  for (int i = 126; i >= 0; --i) {
    float taui = tau_[i];
    if (taui == 0.0f) continue;     // uniform branch
    const int lo = i + 1;
    float a[16];
    float dot = 0.0f;
    #pragma unroll
    for (int k = 0; k < 4; ++k) {
      if (32 * k + 31 >= lo) {      // uniform chunk guard
        float4 av = *(const float4*)&At[i * LDT + 4 * sg + 32 * k];
        {
          int r = 4 * sg + 32 * k;
          float aj;
          aj = (r == lo) ? 1.0f : ((r > lo) ? av.x : 0.0f); a[4*k+0] = aj; dot += aj * q[4*k+0]; r++;
          aj = (r == lo) ? 1.0f : ((r > lo) ? av.y : 0.0f); a[4*k+1] = aj; dot += aj * q[4*k+1]; r++;
          aj = (r == lo) ? 1.0f : ((r > lo) ? av.z : 0.0f); a[4*k+2] = aj; dot += aj * q[4*k+2]; r++;
          aj = (r == lo) ? 1.0f : ((r > lo) ? av.w : 0.0f); a[4*k+3] = aj; dot += aj * q[4*k+3];
        }
      }
    }
    dot += __shfl_xor(dot, 8);
    dot += __shfl_xor(dot, 16);
    dot += __shfl_xor(dot, 32);
    float wv = taui * dot;
    #pragma unroll
    for (int k = 0; k < 4; ++k) {
      if (32 * k + 31 >= lo) {
        q[4*k+0] -= a[4*k+0] * wv;
        q[4*k+1] -= a[4*k+1] * wv;
        q[4*k+2] -= a[4*k+2] * wv;
        q[4*k+3] -= a[4*k+3] * wv;
      }
    }
  }
  #pragma unroll
  for (int k = 0; k < 4; ++k) {
    float4 v;
    v.x = q[4*k+0]; v.y = q[4*k+1]; v.z = q[4*k+2]; v.w = q[4*k+3];
    *(float4*)&Qt[c * LDT + 4 * sg + 32 * k] = v;
  }
  __syncthreads();

  // ---- outputs ----
  if (t < NL) {
    float lam = d_[t + 1];
    wsLam[b * NL + t] = lam;
    outLmask[b * NL + t] = (fabsf(lam) < 1e-4f) ? 1.f : 0.f;
  }
  for (int idx = t; idx < NL * 128; idx += 1024) {
    int ll = idx >> 7, nn2 = idx & 127;
    float lam = d_[ll + 1];
    float vv = Qt[(ll + 1) * LDT + nn2];   // Q[nn2][ll+1]
    if (fabsf(lam) < 1e-4f || nm_[nn2]) vv = 0.f;
    wsUt[(size_t)(b * NL + ll) * 128 + nn2] = vv;
  }
  for (int idx = t; idx < NL * NH; idx += 1024) {
    int ll = idx >> 7, h = idx & 127;
    float lam = d_[ll + 1];
    float sq = sqrtf(fmaxf(lam, 0.f));
    float dd = (sq - mu[h]) * isg[h];
    outEmb[(size_t)(b * NL + ll) * NH + h] = expf(-dd * dd);
  }
}

// ---------------- Xh = X*Wx + bx (masked) + nodemask passthrough ----------------
__global__ __launch_bounds__(256) void k_xh(
    const float* __restrict__ X, const unsigned char* __restrict__ nodemask,
    const float* __restrict__ Wx, const float* __restrict__ bx,
    float* __restrict__ outXh, float* __restrict__ outNm) {
  int idx = blockIdx.x * 256 + threadIdx.x;
  int h = idx & 127;
  int bn = idx >> 7;
  const float* xr = X + (size_t)bn * NDX;
  float acc = bx[h];
  #pragma unroll
  for (int d = 0; d < NDX; ++d) acc += xr[d] * Wx[d * NH + h];
  outXh[idx] = nodemask[bn] ? 0.f : acc;
  if (idx < NBATCH * NN) outNm[idx] = nodemask[idx] ? 1.f : 0.f;
}

// ---------------- Uc = (A x_d W_edge + b_edge) contracted with U ----------------
// v2: 32 groups/batch x 4 n-slices; 512 blocks -> 2 blocks/CU co-residency.
__global__ __launch_bounds__(256) void k_uc(
    const float* __restrict__ A, const unsigned char* __restrict__ nodemask,
    const float* __restrict__ We, const float* __restrict__ be,
    const float* __restrict__ wsUt, float* __restrict__ outUc) {
  int b = blockIdx.x >> 5;
  int ng = blockIdx.x & 31;
  int t = threadIdx.x;
  __shared__ float Uts[NL * 129];
  __shared__ float Ssh[NL];
  __shared__ float Wsh[NDE * NH];
  __shared__ float bsh[NH];
  __shared__ float Ar[NN * NDE];
  __shared__ float Tp[2 * NL * NDE];
  __shared__ float Ts[NL * NDE];
  for (int idx = t; idx < NL * NN; idx += 256) {
    int l = idx >> 7, n = idx & 127;
    Uts[l * 129 + n] = wsUt[(size_t)b * NL * NN + idx];
  }
  for (int idx = t; idx < NDE * NH; idx += 256) Wsh[idx] = We[idx];
  if (t < NH) bsh[t] = be[t];
  __syncthreads();
  if (t < NL) {
    float s = 0.f;
    for (int n = 0; n < NN; ++n) s += Uts[t * 129 + n];
    Ssh[t] = s;
  }
  __syncthreads();
  for (int nn = 0; nn < 4; ++nn) {
    int n = ng * 4 + nn;
    for (int idx = t; idx < NN * NDE; idx += 256)
      Ar[idx] = A[(size_t)(b * NN + n) * NN * NDE + idx];
    __syncthreads();
    {
      int l = t & 127, half = t >> 7;
      if (l < NL) {
        float a0 = 0.f, a1 = 0.f, a2 = 0.f, a3 = 0.f;
        for (int m = 64 * half; m < 64 * half + 64; ++m) {
          float u = Uts[l * 129 + m];
          a0 += Ar[m * 4 + 0] * u;
          a1 += Ar[m * 4 + 1] * u;
          a2 += Ar[m * 4 + 2] * u;
          a3 += Ar[m * 4 + 3] * u;
        }
        int base = (half * NL + l) * 4;
        Tp[base + 0] = a0; Tp[base + 1] = a1; Tp[base + 2] = a2; Tp[base + 3] = a3;
      }
    }
    __syncthreads();
    for (int idx = t; idx < NL * NDE; idx += 256) Ts[idx] = Tp[idx] + Tp[NL * NDE + idx];
    __syncthreads();
    bool mn = nodemask[b * NN + n] != 0;
    {
      int h = t & 127, lh = t >> 7;
      float w0 = Wsh[0 * NH + h], w1 = Wsh[1 * NH + h], w2 = Wsh[2 * NH + h], w3 = Wsh[3 * NH + h];
      float bb = bsh[h];
      for (int l = lh; l < NL; l += 2) {
        float v = w0 * Ts[l * 4 + 0] + w1 * Ts[l * 4 + 1] + w2 * Ts[l * 4 + 2] +
                  w3 * Ts[l * 4 + 3] + bb * Ssh[l];
        outUc[(size_t)((b * NN + n) * NL + l) * NH + h] = mn ? 0.f : v;
      }
    }
    __syncthreads();
  }
}

extern "C" void kernel_launch(void* const* d_in, const int* in_sizes, int n_in,
                              void* d_out, int out_size, void* d_ws, size_t ws_size,
                              hipStream_t stream) {
  const float* A = (const float*)d_in[0];
  const float* X = (const float*)d_in[1];
  const unsigned char* nodemask = (const unsigned char*)d_in[2];
  const float* We = (const float*)d_in[3];
  const float* be = (const float*)d_in[4];
  const float* Wx = (const float*)d_in[5];
  const float* bx = (const float*)d_in[6];
  const float* mu = (const float*)d_in[7];
  const float* isg = (const float*)d_in[8];

  float* out = (float*)d_out;
  float* outEmb = out;                   // 16*127*128
  float* outLmask = out + 260096;        // 16*127
  float* outUc = out + 262128;           // 16*128*127*128
  float* outXh = out + 33554416;         // 16*128*128
  float* outNm = out + 33816560;         // 16*128

  float* wsG = (float*)d_ws;                           // 16 * 66560 floats ≈ 4.26 MB
  float* wsUt = (float*)((char*)d_ws + 4456448);       // 16*127*128 floats
  float* wsLam = wsUt + 260096;

  size_t lds1 = (size_t)128 * LDA * sizeof(float);       // 67584
  size_t lds2 = (size_t)2 * 128 * LDT * sizeof(float);   // 135168
  size_t ldsB = (size_t)(3 * 32 * LDB + 128 * LDB) * sizeof(float);  // 115584

  k_tridiag<<<NBATCH, 512, lds1, stream>>>(A, wsG);
  k_leaves<<<NBATCH * 8, 64, 0, stream>>>(wsG);
  k_mergeA<0><<<NBATCH * 4, 1024, 0, stream>>>(wsG, OFF_Q0);
  k_mergeB<<<NBATCH * 4, 512, ldsB, stream>>>(wsG, 0, OFF_Q0, OFF_Q1);
  k_mergeA<1><<<NBATCH * 2, 1024, 0, stream>>>(wsG, OFF_Q1);
  k_mergeB<<<NBATCH * 4, 512, ldsB, stream>>>(wsG, 1, OFF_Q1, OFF_Q0);
  k_mergeA<2><<<NBATCH * 1, 1024, 0, stream>>>(wsG, OFF_Q0);
  k_mergeB<<<NBATCH * 4, 512, ldsB, stream>>>(wsG, 2, OFF_Q0, OFF_Q1);
  k_back<<<NBATCH, 1024, lds2, stream>>>(wsG, nodemask, mu, isg, wsUt, wsLam, outEmb, outLmask);
  k_xh<<<(NBATCH * NN * NH) / 256, 256, 0, stream>>>(X, nodemask, Wx, bx, outXh, outNm);
  k_uc<<<NBATCH * 32, 256, 0, stream>>>(A, nodemask, We, be, wsUt, outUc);
}

// Round 16
// 862.584 us; speedup vs baseline: 1.1230x; 1.0072x over previous
//
#include <hip/hip_runtime.h>

#define NBATCH 16
#define NN 128
#define NH 128
#define NL 127
#define NDX 11
#define NDE 4
#define LDA 132
#define LDB 129
#define LDT 132
#define WS_STRIDE 66560  // floats per batch in wsG

// per-batch workspace float offsets
#define OFF_AREF 0
#define OFF_Q0   16384
#define OFF_Q1   32768
#define OFF_S    49152
#define OFF_DV   65536
#define OFF_EV   65664
#define OFF_TAU  65792
#define OFF_ORG  65920
#define OFF_META 66048   // 512 floats of int metadata

// ---------------- LAPACK fp32 helper ports ----------------
#define EPS32 5.9604645e-8f
#define EPS232 3.5527137e-15f
#define SAFMIN32 1.17549435e-38f

__device__ __forceinline__ float ssign_(float a, float b) {
  return (b >= 0.0f) ? fabsf(a) : -fabsf(a);
}
__device__ __forceinline__ float slapy2_(float x, float y) {
  float ax = fabsf(x), ay = fabsf(y);
  float w = fmaxf(ax, ay), z = fminf(ax, ay);
  if (z == 0.0f) return w;
  float q = z / w;
  return w * sqrtf(1.0f + q * q);
}

// broadcast-read lane `src`'s value of v (uniform src -> v_readlane, scalar pipe)
__device__ __forceinline__ float rdl(float v, int src) {
  return __int_as_float(__builtin_amdgcn_readlane(__float_as_int(v), src));
}

// rsqrt-based Givens (k_leaves only; args O(1) after orgnrm scaling).
__device__ __forceinline__ void slartg_(float f, float g, float* c, float* s, float* r) {
  if (g == 0.0f) { *c = 1.0f; *s = 0.0f; *r = f; }
  else if (f == 0.0f) { *c = 0.0f; *s = (g >= 0.0f) ? 1.0f : -1.0f; *r = fabsf(g); }
  else {
    float t2 = f * f + g * g;
    float inv = rsqrtf(t2);
    if (f < 0.0f) inv = -inv;
    *c = f * inv; *s = g * inv; *r = t2 * inv;
  }
}

__device__ void slaev2_(float a, float b, float c0, float* rt1, float* rt2,
                        float* cs1, float* sn1) {
  float sm = a + c0, df = a - c0, adf = fabsf(df), tb = b + b, ab = fabsf(tb);
  float acmx, acmn;
  if (fabsf(a) > fabsf(c0)) { acmx = a; acmn = c0; } else { acmx = c0; acmn = a; }
  float rt;
  if (adf > ab) { float q = ab / adf; rt = adf * sqrtf(1.0f + q * q); }
  else if (adf < ab) { float q = adf / ab; rt = ab * sqrtf(1.0f + q * q); }
  else rt = ab * sqrtf(2.0f);
  int sgn1;
  if (sm < 0.0f) { *rt1 = 0.5f * (sm - rt); sgn1 = -1; *rt2 = (acmx / *rt1) * acmn - (b / *rt1) * b; }
  else if (sm > 0.0f) { *rt1 = 0.5f * (sm + rt); sgn1 = 1; *rt2 = (acmx / *rt1) * acmn - (b / *rt1) * b; }
  else { *rt1 = 0.5f * rt; *rt2 = -0.5f * rt; sgn1 = 1; }
  int sgn2; float cs;
  if (df >= 0.0f) { cs = df + rt; sgn2 = 1; } else { cs = df - rt; sgn2 = -1; }
  float acs = fabsf(cs);
  if (acs > ab) { float ct = -tb / cs; *sn1 = 1.0f / sqrtf(1.0f + ct * ct); *cs1 = ct * (*sn1); }
  else {
    if (ab == 0.0f) { *cs1 = 1.0f; *sn1 = 0.0f; }
    else { float tn = -cs / tb; *cs1 = 1.0f / sqrtf(1.0f + tn * tn); *sn1 = tn * (*cs1); }
  }
  if (sgn1 == sgn2) { float tn = *cs1; *cs1 = -(*sn1); *sn1 = tn; }
}

// ============ K1: Laplacian build + ssytd2 tridiagonalization ============
// v8: R10 tridiag (512 thr, 4-barrier, LDA=132) + FUSED k_xh tail blocks:
// blocks >= NBATCH compute Xh/Nm on the 240 idle CUs inside tridiag's
// 325us shadow (xh is data-independent of the eigensolver), removing
// k_xh from the serial pipeline.
__global__ __launch_bounds__(512) void k_tridiag(const float* __restrict__ A_in,
                                                 float* __restrict__ wsG,
                                                 const float* __restrict__ X,
                                                 const unsigned char* __restrict__ nodemask,
                                                 const float* __restrict__ Wx,
                                                 const float* __restrict__ bx,
                                                 float* __restrict__ outXh,
                                                 float* __restrict__ outNm) {
  const int t = threadIdx.x;
  if (blockIdx.x >= NBATCH) {
    // ---- fused Xh = X*Wx + bx (masked) + nodemask passthrough ----
    int idx = (blockIdx.x - NBATCH) * 512 + t;   // 512 blocks x 512 thr = 262144
    int h = idx & 127;
    int bn = idx >> 7;
    const float* xr = X + (size_t)bn * NDX;
    float acc = bx[h];
    #pragma unroll
    for (int d = 0; d < NDX; ++d) acc += xr[d] * Wx[d * NH + h];
    outXh[idx] = nodemask[bn] ? 0.f : acc;
    if (idx < NBATCH * NN) outNm[idx] = nodemask[idx] ? 1.f : 0.f;
    return;
  }
  const int b = blockIdx.x;
  float* Aref = wsG + (size_t)b * WS_STRIDE;
  float* dv = Aref + OFF_DV;
  float* ev = Aref + OFF_EV;
  float* tg = Aref + OFF_TAU;
  float* og = Aref + OFF_ORG;
  extern __shared__ float As[];  // [128][LDA], LDA=132
  __shared__ unsigned int maskp[128][4];
  __shared__ unsigned int Dp[128][4];
  __shared__ unsigned long long adj0_[128], adj1_[128];
  __shared__ float Dd_[128], tDs_[128];
  __shared__ float d_[128], e_[128], tau_[128];
  __shared__ alignas(16) float v_[128];
  __shared__ alignas(16) float w_[128];
  __shared__ float pmat[4][128];
  __shared__ alignas(16) float red_[16];
  __shared__ float xp[16];

  const int wid = t >> 6;        // wave id 0..7
  const int lane = t & 63;
  // ---- adjacency build: 4 threads per row, 32 m's each ----
  {
    const int r8 = t >> 2, s8 = t & 3;
    const float4* Arow = (const float4*)(A_in + (size_t)(b * 128 + r8) * 128 * 4);
    unsigned int mloc = 0; unsigned int cnt = 0;
    const int m0 = s8 * 32;
    #pragma unroll 4
    for (int mm = 0; mm < 32; ++mm) {
      float4 a = Arow[m0 + mm];
      if (a.x != 0.f || a.y != 0.f || a.z != 0.f || a.w != 0.f) { mloc |= 1u << mm; cnt++; }
    }
    maskp[r8][s8] = mloc; Dp[r8][s8] = cnt;
  }
  __syncthreads();
  if (t < 128) {
    unsigned long long b0 = (unsigned long long)maskp[t][0] |
                            ((unsigned long long)maskp[t][1] << 32);
    unsigned long long b1 = (unsigned long long)maskp[t][2] |
                            ((unsigned long long)maskp[t][3] << 32);
    unsigned int D = Dp[t][0] + Dp[t][1] + Dp[t][2] + Dp[t][3];
    adj0_[t] = b0; adj1_[t] = b1;
    float Df = (float)D;
    Dd_[t] = Df;
    tDs_[t] = 1.0f / sqrtf(fmaxf(Df, 1.0f));
  }
  __syncthreads();
  for (int idx = t; idx < 16384; idx += 512) {
    int r = idx >> 7, c = idx & 127;
    if (c <= r) {
      float adj = (float)((c < 64 ? (adj0_[r] >> c) : (adj1_[r] >> (c - 64))) & 1ull);
      float Lrc = ((c == r) ? Dd_[r] : 0.0f) - adj;
      float val = (tDs_[c] * Lrc) * tDs_[r];
      As[r * LDA + c] = val;
      As[c * LDA + r] = val;
    }
  }
  __syncthreads();

  const int rmv = t & 127;   // matvec row
  const int smv = t >> 7;    // matvec segment 0..3 (32 cols each)
  const int ucg = t & 31;    // update col-group (4 cols)
  const int urs = t >> 5;    // update row stripe 0..15

  bool usexp = false;
  for (int i = 0; i < 127; ++i) {
    const int lo = i + 1;
    // ---- xnorm2 of column i below subdiagonal ----
    float xnorm2;
    if (!usexp) {           // uniform fallback path (iter 0 / after taui==0)
      float part = 0.0f;
      if (t < 128 && t >= i + 2) { float x = As[t * LDA + i]; part = x * x; }
      if (wid < 2) {
        #pragma unroll
        for (int m = 1; m < 64; m <<= 1) part += __shfl_xor(part, m);
        if (lane == 0) red_[wid] = part;
      }
      __syncthreads();   // S1 (fallback only)
      xnorm2 = red_[0] + red_[1];
    } else {               // piggybacked: 1 LDS read + shfl tree (sum of 16)
      float s = xp[lane & 15];
      #pragma unroll
      for (int m = 1; m < 16; m <<= 1) s += __shfl_xor(s, m);
      xnorm2 = s;
    }
    float alpha = As[lo * LDA + i];   // row lo never written in phase B
    float beta, taui, scal;
    if (xnorm2 == 0.0f) { taui = 0.0f; beta = alpha; scal = 0.0f; }
    else {
      float xn = sqrtf(xnorm2);
      beta = -ssign_(slapy2_(alpha, xn), alpha);
      taui = (beta - alpha) / beta;
      scal = 1.0f / (alpha - beta);
    }
    if (t == 0) { e_[i] = beta; tau_[i] = taui; }
    if (taui != 0.0f) {    // uniform branch
      // ---- phase B: single-writer v construction ----
      if (t < 128) {
        float vv = 0.0f;
        if (t == lo) vv = 1.0f;
        else if (t > lo) { float xi = As[t * LDA + i]; vv = xi * scal; As[t * LDA + i] = vv; }
        v_[t] = vv;
      }
      __syncthreads();   // S2
      // ---- phase C: matvec partials (32-col chunk) + vpdot partial ----
      const int c0 = smv * 32;
      float acc = 0.0f;
      if (c0 + 31 >= lo && rmv >= lo) {
        const float4* Ar = (const float4*)&As[rmv * LDA + c0];
        const float4* Vr = (const float4*)&v_[c0];
        #pragma unroll
        for (int k = 0; k < 8; ++k) {
          float4 a = Ar[k], v4 = Vr[k];
          acc += a.x * v4.x + a.y * v4.y + a.z * v4.z + a.w * v4.w;
        }
      }
      pmat[smv][rmv] = acc;
      float p2 = v_[rmv] * acc;
      #pragma unroll
      for (int m = 1; m < 64; m <<= 1) p2 += __shfl_xor(p2, m);
      if (lane == 0) red_[wid] = p2;
      __syncthreads();   // S3
      // ---- phase D: w = taui*(Av); a2 via shfl-sum of red_[0..7] ----
      float vpr = red_[lane & 7];
      #pragma unroll
      for (int m = 1; m < 8; m <<= 1) vpr += __shfl_xor(vpr, m);
      float a2 = -0.5f * taui * (taui * vpr);
      if (t < 128) {
        float pv = pmat[0][t] + pmat[1][t] + pmat[2][t] + pmat[3][t];
        w_[t] = taui * pv;
      }
      __syncthreads();   // S4
      // ---- phase E: rank-2 update + next-xnorm piggyback ----
      const int uc0 = ucg * 4;
      if (uc0 + 3 >= lo) {
        float4 vc = *(const float4*)&v_[uc0];
        float4 wc = *(const float4*)&w_[uc0];
        float pcx = wc.x + a2 * vc.x;
        float pcy = wc.y + a2 * vc.y;
        float pcz = wc.z + a2 * vc.z;
        float pcw = wc.w + a2 * vc.w;
        if (uc0 < lo) {   // partial chunk: neutralize components left of lo
          if (uc0 + 0 < lo) { vc.x = 0.f; pcx = 0.f; }
          if (uc0 + 1 < lo) { vc.y = 0.f; pcy = 0.f; }
          if (uc0 + 2 < lo) { vc.z = 0.f; pcz = 0.f; }
        }
        const bool isxcol = (ucg == (lo >> 2));
        const int xc = lo & 3;
        float xpacc = 0.0f;
        #pragma unroll
        for (int k = 0; k < 8; ++k) {
          int r = urs + 16 * k;
          if (r >= lo) {
            float vr = v_[r];
            float pr = w_[r] + a2 * vr;
            float4 a = *(const float4*)&As[r * LDA + uc0];
            a.x -= vr * pcx + pr * vc.x;
            a.y -= vr * pcy + pr * vc.y;
            a.z -= vr * pcz + pr * vc.z;
            a.w -= vr * pcw + pr * vc.w;
            *(float4*)&As[r * LDA + uc0] = a;
            if (isxcol && r >= lo + 2) {
              float nc = (xc == 0) ? a.x : ((xc == 1) ? a.y : ((xc == 2) ? a.z : a.w));
              xpacc += nc * nc;
            }
          }
        }
        if (isxcol) xp[urs] = xpacc;
      }
    }
    __syncthreads();   // S5
    usexp = (taui != 0.0f);
  }
  if (t < 128) d_[t] = As[t * LDA + t];
  __syncthreads();

  {
    float mx = 0.0f;
    if (t < 128) mx = fabsf(d_[t]);
    if (t < 127) mx = fmaxf(mx, fabsf(e_[t]));
    if (wid < 2) {
      #pragma unroll
      for (int m = 1; m < 64; m <<= 1) mx = fmaxf(mx, __shfl_xor(mx, m));
      if (lane == 0) red_[wid] = mx;
    }
    __syncthreads();
  }
  float orgnrm = fmaxf(red_[0], red_[1]);
  if (orgnrm == 0.0f) orgnrm = 1.0f;
  float invnrm = 1.0f / orgnrm;
  if (t < 128) d_[t] *= invnrm;
  if (t < 127) e_[t] *= invnrm;
  __syncthreads();
  if (t == 0) {
    for (int bm = 16; bm < 128; bm += 16) {
      float ae = fabsf(e_[bm - 1]);
      d_[bm - 1] -= ae; d_[bm] -= ae;
    }
  }
  __syncthreads();
  for (int idx = t; idx < 16384; idx += 512)
    Aref[idx] = As[(idx >> 7) * LDA + (idx & 127)];
  if (t < 128) { dv[t] = d_[t]; tg[t] = tau_[t]; }
  if (t < 127) ev[t] = e_[t];
  if (t == 0) og[0] = orgnrm;
}

// ============ K2: 8 leaves x 16 batches, one block each ============
// v5: lane-register ssteqr + rsqrt slartg + ballot-parallel scans.
__global__ __launch_bounds__(64) void k_leaves(float* __restrict__ wsG) {
  int b = blockIdx.x >> 3, lf = blockIdx.x & 7;
  float* base = wsG + (size_t)b * WS_STRIDE;
  float* Qg = base + OFF_Q0;
  float* dv = base + OFF_DV;
  float* ev = base + OFF_EV;
  const int ln = threadIdx.x;
  __shared__ float zsh[16 * 17];

  const int n = 16;
  float dreg = (ln < 16) ? dv[lf * 16 + ln] : 0.f;
  float ereg = (ln < 15) ? ev[lf * 16 + ln] : 0.f;
  float csreg = 0.f, snreg = 0.f;
  float zr[16];
  #pragma unroll
  for (int c = 0; c < 16; ++c) zr[c] = (ln == c) ? 1.0f : 0.0f;

  {
    const float eps = EPS32, eps2 = EPS232, safmin = SAFMIN32;
    int nmaxit = n * 30, jtot = 0;
    int l1 = 0;
    while (l1 <= n - 1) {
      if (l1 > 0 && ln == l1 - 1) ereg = 0.0f;
      // ---- ballot outer deflation scan over m in [l1, n-2] ----
      int m;
      {
        float dn1 = __shfl_down(dreg, 1);   // d[ln+1]
        float tst = fabsf(ereg);
        bool cond = (tst == 0.0f) ||
                    (tst <= (sqrtf(fabsf(dreg)) * sqrtf(fabsf(dn1))) * eps);
        unsigned long long mask = __ballot(cond);
        unsigned long long rng = ((1ull << (n - 1)) - 1) & ~((1ull << l1) - 1);
        mask &= rng;
        m = mask ? (__ffsll(mask) - 1) : (n - 1);
        // zeroing is a no-op when the hit was tst==0 (e already 0)
        if (mask && ln == m) ereg = 0.0f;
      }
      int l = l1, lend = m;
      l1 = m + 1;
      if (lend == l) continue;
      {
        // ---- 64-lane range-max (abs) over d[l..lend], e[l..lend-1] ----
        float av = (ln >= l && ln <= lend) ? fabsf(dreg) : 0.0f;
        if (ln >= l && ln <= lend - 1) av = fmaxf(av, fabsf(ereg));
        #pragma unroll
        for (int mm = 1; mm < 64; mm <<= 1) av = fmaxf(av, __shfl_xor(av, mm));
        if (av == 0.0f) continue;
      }
      if (fabsf(rdl(dreg, lend)) < fabsf(rdl(dreg, l))) { int tsw = l; l = lend; lend = tsw; }
      if (lend > l) {
        while (true) {  // QL
          // ---- ballot split scan: lowest m2 in [l, lend-1] ----
          int m2;
          if (l != lend) {
            float dn1 = __shfl_down(dreg, 1);
            bool cond = (ereg * ereg) <= (eps2 * fabsf(dreg)) * fabsf(dn1) + safmin;
            unsigned long long mask = __ballot(cond) &
                (((1ull << lend) - 1) & ~((1ull << l) - 1));
            m2 = mask ? (__ffsll(mask) - 1) : lend;
          } else m2 = lend;
          if (m2 < lend && ln == m2) ereg = 0.0f;
          float p = rdl(dreg, l);
          if (m2 == l) { l++; if (l <= lend) continue; else break; }
          if (m2 == l + 1) {
            float rt1, rt2, c, s;
            slaev2_(rdl(dreg, l), rdl(ereg, l), rdl(dreg, l + 1), &rt1, &rt2, &c, &s);
            #pragma unroll
            for (int j = 0; j < 15; ++j) {
              if (j == l) {
                float t1 = zr[j + 1];
                zr[j + 1] = c * t1 - s * zr[j];
                zr[j] = s * t1 + c * zr[j];
              }
            }
            if (ln == l) { dreg = rt1; ereg = 0.0f; }
            if (ln == l + 1) dreg = rt2;
            l += 2; if (l <= lend) continue; else break;
          }
          if (jtot == nmaxit) break;
          jtot++;
          float g = (rdl(dreg, l + 1) - p) / (2.0f * rdl(ereg, l));
          float r = slapy2_(g, 1.0f);
          g = rdl(dreg, m2) - p + rdl(ereg, l) / (g + ssign_(r, g));
          float s = 1.0f, c = 1.0f; p = 0.0f;
          for (int i = m2 - 1; i >= l; --i) {
            float ei = rdl(ereg, i);
            float f = s * ei, bb = c * ei;
            slartg_(g, f, &c, &s, &r);
            if (i != m2 - 1 && ln == i + 1) ereg = r;
            g = rdl(dreg, i + 1) - p;
            r = (rdl(dreg, i) - g) * s + 2.0f * c * bb;
            p = s * r;
            if (ln == i + 1) dreg = g + p;
            g = c * r - bb;
            if (ln == i) { csreg = c; snreg = -s; }
          }
          #pragma unroll
          for (int j = 14; j >= 0; --j) {
            if (j <= m2 - 1 && j >= l) {
              float cj = rdl(csreg, j), sj = rdl(snreg, j);
              float t1 = zr[j + 1];
              zr[j + 1] = cj * t1 - sj * zr[j];
              zr[j] = sj * t1 + cj * zr[j];
            }
          }
          if (ln == l) { dreg = dreg - p; ereg = g; }
        }
      } else {
        while (true) {  // QR
          // ---- ballot split scan: highest m2 in [lend+1, l] ----
          int m2;
          if (l != lend) {
            float ep = __shfl_up(ereg, 1);   // e[ln-1]
            float dp = __shfl_up(dreg, 1);   // d[ln-1]
            bool cond = (ep * ep) <= (eps2 * fabsf(dreg)) * fabsf(dp) + safmin;
            unsigned long long mask = __ballot(cond) &
                (((1ull << (l + 1)) - 1) & ~((1ull << (lend + 1)) - 1));
            m2 = mask ? (63 - __clzll(mask)) : lend;
          } else m2 = lend;
          if (m2 > lend && ln == m2 - 1) ereg = 0.0f;
          float p = rdl(dreg, l);
          if (m2 == l) { l--; if (l >= lend) continue; else break; }
          if (m2 == l - 1) {
            float rt1, rt2, c, s;
            slaev2_(rdl(dreg, l - 1), rdl(ereg, l - 1), rdl(dreg, l), &rt1, &rt2, &c, &s);
            #pragma unroll
            for (int j = 0; j < 15; ++j) {
              if (j == l - 1) {
                float t1 = zr[j + 1];
                zr[j + 1] = c * t1 - s * zr[j];
                zr[j] = s * t1 + c * zr[j];
              }
            }
            if (ln == l - 1) { dreg = rt1; ereg = 0.0f; }
            if (ln == l) dreg = rt2;
            l -= 2; if (l >= lend) continue; else break;
          }
          if (jtot == nmaxit) break;
          jtot++;
          float g = (rdl(dreg, l - 1) - p) / (2.0f * rdl(ereg, l - 1));
          float r = slapy2_(g, 1.0f);
          g = rdl(dreg, m2) - p + rdl(ereg, l - 1) / (g + ssign_(r, g));
          float s = 1.0f, c = 1.0f; p = 0.0f;
          for (int i = m2; i <= l - 1; ++i) {
            float ei = rdl(ereg, i);
            float f = s * ei, bb = c * ei;
            slartg_(g, f, &c, &s, &r);
            if (i != m2 && ln == i - 1) ereg = r;
            g = rdl(dreg, i) - p;
            r = (rdl(dreg, i + 1) - g) * s + 2.0f * c * bb;
            p = s * r;
            if (ln == i) dreg = g + p;
            g = c * r - bb;
            if (ln == i) { csreg = c; snreg = s; }
          }
          #pragma unroll
          for (int j = 0; j <= 14; ++j) {
            if (j >= m2 && j <= l - 1) {
              float cj = rdl(csreg, j), sj = rdl(snreg, j);
              float t1 = zr[j + 1];
              zr[j + 1] = cj * t1 - sj * zr[j];
              zr[j] = sj * t1 + cj * zr[j];
            }
          }
          if (ln == l) dreg = dreg - p;
          if (ln == l - 1) ereg = g;
        }
      }
    }
  }

  // stage z rows to LDS for sort + band write
  if (ln < 16) {
    #pragma unroll
    for (int c = 0; c < 16; ++c) zsh[ln * 17 + c] = zr[c];
  }
  __syncthreads();
  // selection sort: d in lane registers, z column swaps row-parallel in LDS
  for (int ii = 1; ii <= n - 1; ++ii) {
    int i = ii - 1, k = i;
    float p = rdl(dreg, i);
    for (int j = ii; j <= n - 1; ++j) {
      float dj = rdl(dreg, j);
      if (dj < p) { k = j; p = dj; }
    }
    if (k != i) {
      float di = rdl(dreg, i);
      if (ln == k) dreg = di;
      if (ln == i) dreg = p;
      if (ln < 16) {
        float t1 = zsh[ln * 17 + i];
        zsh[ln * 17 + i] = zsh[ln * 17 + k];
        zsh[ln * 17 + k] = t1;
      }
    }
  }
  __syncthreads();
  if (ln < 16) dv[lf * 16 + ln] = dreg;
  // write only the 32-col merge band: cols bo..bo+31 where bo=(lf>>1)*32
  {
    const int bo = (lf >> 1) * 32;
    const int cofs = (lf & 1) * 16;   // local col offset of this leaf in band
    for (int idx = ln; idx < 16 * 32; idx += 64) {
      int rr = idx >> 5, c = idx & 31;
      int cl = c - cofs;
      float v = (cl >= 0 && cl < 16) ? zsh[rr * 17 + cl] : 0.f;
      Qg[(size_t)(lf * 16 + rr) * 128 + bo + c] = v;
    }
  }
}

// ============ K3a: merge metadata/secular per (batch, merge) ============
// v3: register bisection 36 iters.
template <int LVL>
__global__ __launch_bounds__(1024) void k_mergeA(float* __restrict__ wsG, int qoff) {
  constexpr int sh = 2 - LVL;
  constexpr int nm = 32 << LVL;     // merged size n
  constexpr int LPR = 1024 / nm;    // lanes per root: 32/16/8
  constexpr int NCH = nm / LPR;     // chunk regs per lane: 1/4/16
  int b = blockIdx.x >> sh;
  int mg = blockIdx.x & ((1 << sh) - 1);
  int bo = mg * nm, n1 = nm >> 1, n = nm;
  const int t = threadIdx.x;
  float* base = wsG + (size_t)b * WS_STRIDE;
  float* Qin = base + qoff;
  float* dvg = base + OFF_DV;
  float* evg = base + OFF_EV;
  float* Sg  = base + OFF_S;
  int* meta = (int*)(base + OFF_META);
  int* undG = meta; int* idxpG = meta + 128; int* finG = meta + 256; int* KfG = meta + 384;

  __shared__ float d_[128], z_[128], dl_[128], w_[128], zh_[128], lam_[128], tauv_[128], dnew_[128];
  __shared__ int srt_[128], indxp_[128], und_[128], anc_[128], fin_[128];
  __shared__ int gp_[128], gq_[128];
  __shared__ float gc_[128], gs_[128];
  __shared__ int sci[4];

  if (t < n) d_[t] = dvg[bo + t];
  float rho_in = evg[bo + n1 - 1];
  if (t < n) {
    float zv = (t < n1) ? Qin[(size_t)(bo + n1 - 1) * 128 + bo + t]
                        : Qin[(size_t)(bo + n1) * 128 + bo + t];
    if (rho_in < 0.0f && t >= n1) zv = -zv;
    z_[t] = zv * 0.70710678f;
  }
  __syncthreads();
  float rho = fabsf(2.0f * rho_in);
  if (t == 0) {
    int i1 = 0, i2 = n1, k = 0;
    while (i1 < n1 && i2 < n) {
      if (d_[i1] <= d_[i2]) srt_[k++] = i1++; else srt_[k++] = i2++;
    }
    while (i1 < n1) srt_[k++] = i1++;
    while (i2 < n) srt_[k++] = i2++;
    float zmax = 0.0f, dmax = 0.0f;
    for (int i = 0; i < n; ++i) {
      zmax = fmaxf(zmax, fabsf(z_[i]));
      dmax = fmaxf(dmax, fabsf(d_[i]));
    }
    float tol = 8.0f * EPS32 * fmaxf(dmax, zmax);
    int K = 0, k2 = n, full = 0, ngiv = 0;
    if (rho * zmax <= tol) full = 1;
    else {
      int pj = -1, jj = 0;
      for (; jj < n; ++jj) {
        int nj = srt_[jj];
        if (rho * fabsf(z_[nj]) <= tol) { k2--; indxp_[k2] = nj; }
        else { pj = nj; break; }
      }
      if (pj < 0) full = 1;
      else {
        for (jj = jj + 1; jj < n; ++jj) {
          int nj = srt_[jj];
          if (rho * fabsf(z_[nj]) <= tol) { k2--; indxp_[k2] = nj; }
          else {
            float s = z_[pj], c = z_[nj];
            float tauq = slapy2_(c, s);
            float tdf = d_[nj] - d_[pj];
            c /= tauq; s = -s / tauq;
            if (fabsf(tdf * c * s) <= tol) {
              z_[nj] = tauq; z_[pj] = 0.0f;
              gp_[ngiv] = pj; gq_[ngiv] = nj; gc_[ngiv] = c; gs_[ngiv] = s; ngiv++;
              float tt2 = d_[pj] * c * c + d_[nj] * s * s;
              d_[nj] = d_[pj] * s * s + d_[nj] * c * c;
              d_[pj] = tt2;
              k2--;
              int pos = k2;
              while (pos + 1 <= n - 1 && d_[pj] < d_[indxp_[pos + 1]]) {
                indxp_[pos] = indxp_[pos + 1]; pos++;
              }
              indxp_[pos] = pj;
              pj = nj;
            } else {
              dl_[K] = d_[pj]; w_[K] = z_[pj]; und_[K] = pj; K++;
              pj = nj;
            }
          }
        }
        dl_[K] = d_[pj]; w_[K] = z_[pj]; und_[K] = pj; K++;
      }
    }
    sci[0] = K; sci[1] = full; sci[2] = ngiv;
  }
  __syncthreads();
  int K = sci[0], full = sci[1], ngiv = sci[2];
  if (!full) {
    // Givens rotations applied row-parallel to global Q (same per-row op order)
    if (t < n) {
      size_t rowoff = (size_t)(bo + t) * 128 + bo;
      for (int g = 0; g < ngiv; ++g) {
        float c = gc_[g], s = gs_[g];
        float xq = Qin[rowoff + gp_[g]], yq = Qin[rowoff + gq_[g]];
        Qin[rowoff + gp_[g]] = c * xq + s * yq;
        Qin[rowoff + gq_[g]] = c * yq - s * xq;
      }
    }
    // ---- lane-group secular solve: root j = t/LPR, sub-lane sub = t%LPR ----
    const int j = t / LPR;
    const int sub = t % LPR;
    const bool act = (j < K);
    float dl_loc[NCH], w2_loc[NCH];
    float tauj_reg = 0.0f; float da_reg = 0.0f;
    if (act) {
      #pragma unroll
      for (int k = 0; k < NCH; ++k) {
        int i = sub + k * LPR;
        if (i < K) { dl_loc[k] = dl_[i]; float wi = w_[i]; w2_loc[k] = rho * wi * wi; }
        else { dl_loc[k] = 3.0e38f; w2_loc[k] = 0.0f; }   // term -> 0, no NaN
      }
      // zsum (already rho-scaled)
      float zs = 0.0f;
      #pragma unroll
      for (int k = 0; k < NCH; ++k) zs += w2_loc[k];
      #pragma unroll
      for (int m = 1; m < LPR; m <<= 1) zs += __shfl_xor(zs, m);
      // anchor decision
      int a; float lo2, hi2;
      if (j < K - 1) {
        float dj = dl_[j];
        float tm = 0.5f * (dl_[j + 1] - dj);
        float fm = 0.0f;
        #pragma unroll
        for (int k = 0; k < NCH; ++k) fm += w2_loc[k] / ((dl_loc[k] - dj) - tm);
        #pragma unroll
        for (int m = 1; m < LPR; m <<= 1) fm += __shfl_xor(fm, m);
        fm += 1.0f;
        if (fm >= 0.0f) { a = j; lo2 = 0.0f; hi2 = tm; }
        else { a = j + 1; lo2 = -tm; hi2 = 0.0f; }
      } else { a = K - 1; lo2 = 0.0f; hi2 = zs + 1e-30f; }
      float da = dl_[a];
      float sdl[NCH];
      #pragma unroll
      for (int k = 0; k < NCH; ++k) sdl[k] = dl_loc[k] - da;
      for (int it2 = 0; it2 < 36; ++it2) {
        float tc = 0.5f * (lo2 + hi2);
        float f = 0.0f;
        #pragma unroll
        for (int k = 0; k < NCH; ++k) f += w2_loc[k] / (sdl[k] - tc);
        #pragma unroll
        for (int m = 1; m < LPR; m <<= 1) f += __shfl_xor(f, m);
        f += 1.0f;
        if (f >= 0.0f) hi2 = tc; else lo2 = tc;
      }
      tauj_reg = 0.5f * (lo2 + hi2);
      da_reg = da;
      if (sub == 0) { lam_[j] = da + tauj_reg; tauv_[j] = tauj_reg; anc_[j] = a; }
    }
    __syncthreads();
    // Gu's sign-preserving z-hat (root i = j of this octet; chunk over jj)
    if (act) {
      float di = dl_[j];
      float pp = 1.0f;
      #pragma unroll
      for (int k = 0; k < NCH; ++k) {
        int jj = sub + k * LPR;
        if (jj < K && jj != j) {
          float delta_ij = (di - dl_[anc_[jj]]) - tauv_[jj];
          pp *= delta_ij / (di - dl_[jj]);
        }
      }
      #pragma unroll
      for (int m = 1; m < LPR; m <<= 1) pp *= __shfl_xor(pp, m);
      if (sub == 0) {
        float lead = (di - da_reg) - tauj_reg;
        float acc = lead * pp;
        zh_[j] = ssign_(sqrtf(fmaxf(-acc, 0.0f)), w_[j]);
      }
    }
    __syncthreads();
    // rank-1 system eigenvectors, chunked per lane, single scaled store
    if (act) {
      float sv[NCH]; float nrm = 0.0f;
      #pragma unroll
      for (int k = 0; k < NCH; ++k) {
        int i = sub + k * LPR;
        float s = 0.0f;
        if (i < K) s = zh_[i] / ((dl_loc[k] - da_reg) - tauj_reg);
        sv[k] = s; nrm += s * s;
      }
      #pragma unroll
      for (int m = 1; m < LPR; m <<= 1) nrm += __shfl_xor(nrm, m);
      nrm = 1.0f / sqrtf(nrm);
      float* scol = Sg + bo + j;
      #pragma unroll
      for (int k = 0; k < NCH; ++k) {
        int i = sub + k * LPR;
        if (i < K) scol[(size_t)(bo + i) * 128] = sv[k] * nrm;
      }
    }
    if (t == 0) {
      for (int jj = 0; jj < K; ++jj) dnew_[jj] = lam_[jj];
      for (int m = 0; m < n - K; ++m) dnew_[K + m] = d_[indxp_[n - 1 - m]];
      int i1 = 0, i2 = K, k = 0;
      while (i1 < K && i2 < n) { if (dnew_[i1] <= dnew_[i2]) fin_[k++] = i1++; else fin_[k++] = i2++; }
      while (i1 < K) fin_[k++] = i1++;
      while (i2 < n) fin_[k++] = i2++;
    }
    __syncthreads();
    if (t < n) {
      dvg[bo + t] = dnew_[fin_[t]];
      idxpG[bo + t] = indxp_[t];
      finG[bo + t] = fin_[t];
    }
    if (t < K) undG[bo + t] = und_[t];
    if (t == 0) KfG[mg] = K;
  } else {
    if (t < n) {
      dvg[bo + t] = d_[srt_[t]];
      idxpG[bo + t] = srt_[n - 1 - t];
      finG[bo + t] = t;
    }
    if (t == 0) KfG[mg] = 0;
  }
}

// ============ K3b: merge GEMM/permute, 32 rows per block ============
// v2: 512 threads (8 waves = 2/SIMD).
__global__ __launch_bounds__(512) void k_mergeB(float* __restrict__ wsG, int lvl,
                                                int qinoff, int qoutoff) {
  int b = blockIdx.x >> 2;
  int rblk = blockIdx.x & 3;
  int rbase = rblk * 32;
  int nm = 32 << lvl;
  int ln2 = 5 + lvl;
  int mg = rbase >> ln2;
  int bo = mg * nm, n = nm;
  const int t = threadIdx.x;
  float* base = wsG + (size_t)b * WS_STRIDE;
  const float* Qin = base + qinoff;
  float* Qout = base + qoutoff;
  const float* Sg = base + OFF_S;
  const int* meta = (const int*)(base + OFF_META);
  const int* undG = meta; const int* idxpG = meta + 128;
  const int* finG = meta + 256; const int* KfG = meta + 384;

  extern __shared__ float lds[];
  float* QT = lds;                 // [32][LDB]
  float* QC = QT + 32 * LDB;       // [32][LDB]
  float* WT = QC + 32 * LDB;       // [32][LDB]
  float* ST = WT + 32 * LDB;       // [128][LDB]
  __shared__ int und_l[128], idxp_l[128], fin_l[128];
  __shared__ int Ksh;

  if (t == 0) Ksh = KfG[mg];
  if (t < n) { und_l[t] = undG[bo + t]; idxp_l[t] = idxpG[bo + t]; fin_l[t] = finG[bo + t]; }
  for (int idx = t; idx < 32 * n; idx += 512) {
    int r = idx >> ln2, c = idx & (n - 1);
    QT[r * LDB + c] = Qin[(size_t)(rbase + r) * 128 + bo + c];
  }
  __syncthreads();
  int K = Ksh;
  for (int idx = t; idx < (K << 7); idx += 512) {
    int k = idx >> 7, j = idx & 127;
    ST[k * LDB + j] = Sg[(size_t)(bo + k) * 128 + bo + j];
  }
  for (int r = 0; r < 32; ++r)
    if (t < K) QC[r * LDB + t] = QT[r * LDB + und_l[t]];
  __syncthreads();
  for (int idx = t; idx < 32 * n; idx += 512) {
    int r = idx >> ln2, j = idx & (n - 1);
    float v;
    if (j < K) {
      float a0 = 0.f, a1 = 0.f, a2 = 0.f, a3 = 0.f;
      int k = 0;
      for (; k + 3 < K; k += 4) {
        a0 += QC[r * LDB + k]     * ST[k * LDB + j];
        a1 += QC[r * LDB + k + 1] * ST[(k + 1) * LDB + j];
        a2 += QC[r * LDB + k + 2] * ST[(k + 2) * LDB + j];
        a3 += QC[r * LDB + k + 3] * ST[(k + 3) * LDB + j];
      }
      for (; k < K; ++k) a0 += QC[r * LDB + k] * ST[k * LDB + j];
      v = (a0 + a1) + (a2 + a3);
    } else {
      v = QT[r * LDB + idxp_l[n - 1 - (j - K)]];
    }
    WT[r * LDB + j] = v;
  }
  __syncthreads();
  for (int idx = t; idx < 32 * 128; idx += 512) {
    int r = idx >> 7, c = idx & 127;
    int cl = c - bo;
    float v = 0.f;
    if (cl >= 0 && cl < n) v = WT[r * LDB + fin_l[cl]];
    Qout[(size_t)(rbase + r) * 128 + c] = v;
  }
}

// ============ K4: back-transform + outputs ============
// v2: 1024 threads, 16 waves; Q register-resident, barrier-free reflector loop.
__global__ __launch_bounds__(1024) void k_back(
    float* __restrict__ wsG, const unsigned char* __restrict__ nodemask,
    const float* __restrict__ mu, const float* __restrict__ isg,
    float* __restrict__ wsUt, float* __restrict__ wsLam,
    float* __restrict__ outEmb, float* __restrict__ outLmask) {
  const int b = blockIdx.x, t = threadIdx.x;
  float* base = wsG + (size_t)b * WS_STRIDE;
  float* Qg = base + OFF_Q1;
  float* dvg = base + OFF_DV;
  float* tg = base + OFF_TAU;
  float* og = base + OFF_ORG;
  extern __shared__ float lds[];
  float* At = lds;                 // [128][LDT]: At[c*LDT+r] = Aref[r][c]
  float* Qt = lds + 128 * LDT;     // [128][LDT]: Qt[c*LDT+r] = Q[r][c]
  __shared__ float d_[128], tau_[128];
  __shared__ unsigned char nm_[128];

  float orgnrm = og[0];
  for (int idx = t; idx < 16384; idx += 1024) {
    int r = idx >> 7, c = idx & 127;
    At[c * LDT + r] = base[idx];   // Aref transpose-staged
    Qt[c * LDT + r] = Qg[idx];
  }
  if (t < 128) {
    d_[t] = dvg[t] * orgnrm;
    tau_[t] = tg[t];
    nm_[t] = nodemask[b * 128 + t];
  }
  __syncthreads();

  // ---- register-resident back-transform ----
  const int w = t >> 6, l = t & 63;
  const int cidx = l & 7, sg = l >> 3;
  const int c = w * 8 + cidx;
  float q[16];
  #pragma unroll
  for (int k = 0; k < 4; ++k) {
    float4 v = *(const float4*)&Qt[c * LDT + 4 * sg + 32 * k];
    q[4 * k + 0] = v.x; q[4 * k + 1] = v.y; q[4 * k + 2] = v.z; q[4 * k + 3] = v.w;
  }
  for (int i = 126; i >= 0; --i) {
    float taui = tau_[i];
    if (taui == 0.0f) continue;     // uniform branch
    const int lo = i + 1;
    float a[16];
    float dot = 0.0f;
    #pragma unroll
    for (int k = 0; k < 4; ++k) {
      if (32 * k + 31 >= lo) {      // uniform chunk guard
        float4 av = *(const float4*)&At[i * LDT + 4 * sg + 32 * k];
        {
          int r = 4 * sg + 32 * k;
          float aj;
          aj = (r == lo) ? 1.0f : ((r > lo) ? av.x : 0.0f); a[4*k+0] = aj; dot += aj * q[4*k+0]; r++;
          aj = (r == lo) ? 1.0f : ((r > lo) ? av.y : 0.0f); a[4*k+1] = aj; dot += aj * q[4*k+1]; r++;
          aj = (r == lo) ? 1.0f : ((r > lo) ? av.z : 0.0f); a[4*k+2] = aj; dot += aj * q[4*k+2]; r++;
          aj = (r == lo) ? 1.0f : ((r > lo) ? av.w : 0.0f); a[4*k+3] = aj; dot += aj * q[4*k+3];
        }
      }
    }
    dot += __shfl_xor(dot, 8);
    dot += __shfl_xor(dot, 16);
    dot += __shfl_xor(dot, 32);
    float wv = taui * dot;
    #pragma unroll
    for (int k = 0; k < 4; ++k) {
      if (32 * k + 31 >= lo) {
        q[4*k+0] -= a[4*k+0] * wv;
        q[4*k+1] -= a[4*k+1] * wv;
        q[4*k+2] -= a[4*k+2] * wv;
        q[4*k+3] -= a[4*k+3] * wv;
      }
    }
  }
  #pragma unroll
  for (int k = 0; k < 4; ++k) {
    float4 v;
    v.x = q[4*k+0]; v.y = q[4*k+1]; v.z = q[4*k+2]; v.w = q[4*k+3];
    *(float4*)&Qt[c * LDT + 4 * sg + 32 * k] = v;
  }
  __syncthreads();

  // ---- outputs ----
  if (t < NL) {
    float lam = d_[t + 1];
    wsLam[b * NL + t] = lam;
    outLmask[b * NL + t] = (fabsf(lam) < 1e-4f) ? 1.f : 0.f;
  }
  for (int idx = t; idx < NL * 128; idx += 1024) {
    int ll = idx >> 7, nn2 = idx & 127;
    float lam = d_[ll + 1];
    float vv = Qt[(ll + 1) * LDT + nn2];   // Q[nn2][ll+1]
    if (fabsf(lam) < 1e-4f || nm_[nn2]) vv = 0.f;
    wsUt[(size_t)(b * NL + ll) * 128 + nn2] = vv;
  }
  for (int idx = t; idx < NL * NH; idx += 1024) {
    int ll = idx >> 7, h = idx & 127;
    float lam = d_[ll + 1];
    float sq = sqrtf(fmaxf(lam, 0.f));
    float dd = (sq - mu[h]) * isg[h];
    outEmb[(size_t)(b * NL + ll) * NH + h] = expf(-dd * dd);
  }
}

// ---------------- Uc = (A x_d W_edge + b_edge) contracted with U ----------------
// v2: 32 groups/batch x 4 n-slices; 512 blocks -> 2 blocks/CU co-residency.
__global__ __launch_bounds__(256) void k_uc(
    const float* __restrict__ A, const unsigned char* __restrict__ nodemask,
    const float* __restrict__ We, const float* __restrict__ be,
    const float* __restrict__ wsUt, float* __restrict__ outUc) {
  int b = blockIdx.x >> 5;
  int ng = blockIdx.x & 31;
  int t = threadIdx.x;
  __shared__ float Uts[NL * 129];
  __shared__ float Ssh[NL];
  __shared__ float Wsh[NDE * NH];
  __shared__ float bsh[NH];
  __shared__ float Ar[NN * NDE];
  __shared__ float Tp[2 * NL * NDE];
  __shared__ float Ts[NL * NDE];
  for (int idx = t; idx < NL * NN; idx += 256) {
    int l = idx >> 7, n = idx & 127;
    Uts[l * 129 + n] = wsUt[(size_t)b * NL * NN + idx];
  }
  for (int idx = t; idx < NDE * NH; idx += 256) Wsh[idx] = We[idx];
  if (t < NH) bsh[t] = be[t];
  __syncthreads();
  if (t < NL) {
    float s = 0.f;
    for (int n = 0; n < NN; ++n) s += Uts[t * 129 + n];
    Ssh[t] = s;
  }
  __syncthreads();
  for (int nn = 0; nn < 4; ++nn) {
    int n = ng * 4 + nn;
    for (int idx = t; idx < NN * NDE; idx += 256)
      Ar[idx] = A[(size_t)(b * NN + n) * NN * NDE + idx];
    __syncthreads();
    {
      int l = t & 127, half = t >> 7;
      if (l < NL) {
        float a0 = 0.f, a1 = 0.f, a2 = 0.f, a3 = 0.f;
        for (int m = 64 * half; m < 64 * half + 64; ++m) {
          float u = Uts[l * 129 + m];
          a0 += Ar[m * 4 + 0] * u;
          a1 += Ar[m * 4 + 1] * u;
          a2 += Ar[m * 4 + 2] * u;
          a3 += Ar[m * 4 + 3] * u;
        }
        int base = (half * NL + l) * 4;
        Tp[base + 0] = a0; Tp[base + 1] = a1; Tp[base + 2] = a2; Tp[base + 3] = a3;
      }
    }
    __syncthreads();
    for (int idx = t; idx < NL * NDE; idx += 256) Ts[idx] = Tp[idx] + Tp[NL * NDE + idx];
    __syncthreads();
    bool mn = nodemask[b * NN + n] != 0;
    {
      int h = t & 127, lh = t >> 7;
      float w0 = Wsh[0 * NH + h], w1 = Wsh[1 * NH + h], w2 = Wsh[2 * NH + h], w3 = Wsh[3 * NH + h];
      float bb = bsh[h];
      for (int l = lh; l < NL; l += 2) {
        float v = w0 * Ts[l * 4 + 0] + w1 * Ts[l * 4 + 1] + w2 * Ts[l * 4 + 2] +
                  w3 * Ts[l * 4 + 3] + bb * Ssh[l];
        outUc[(size_t)((b * NN + n) * NL + l) * NH + h] = mn ? 0.f : v;
      }
    }
    __syncthreads();
  }
}

extern "C" void kernel_launch(void* const* d_in, const int* in_sizes, int n_in,
                              void* d_out, int out_size, void* d_ws, size_t ws_size,
                              hipStream_t stream) {
  const float* A = (const float*)d_in[0];
  const float* X = (const float*)d_in[1];
  const unsigned char* nodemask = (const unsigned char*)d_in[2];
  const float* We = (const float*)d_in[3];
  const float* be = (const float*)d_in[4];
  const float* Wx = (const float*)d_in[5];
  const float* bx = (const float*)d_in[6];
  const float* mu = (const float*)d_in[7];
  const float* isg = (const float*)d_in[8];

  float* out = (float*)d_out;
  float* outEmb = out;                   // 16*127*128
  float* outLmask = out + 260096;        // 16*127
  float* outUc = out + 262128;           // 16*128*127*128
  float* outXh = out + 33554416;         // 16*128*128
  float* outNm = out + 33816560;         // 16*128

  float* wsG = (float*)d_ws;                           // 16 * 66560 floats ≈ 4.26 MB
  float* wsUt = (float*)((char*)d_ws + 4456448);       // 16*127*128 floats
  float* wsLam = wsUt + 260096;

  size_t lds1 = (size_t)128 * LDA * sizeof(float);       // 67584
  size_t lds2 = (size_t)2 * 128 * LDT * sizeof(float);   // 135168
  size_t ldsB = (size_t)(3 * 32 * LDB + 128 * LDB) * sizeof(float);  // 115584

  // k_tridiag grid = 16 eigensolver blocks + 512 fused-Xh blocks
  // (262144 xh elements / 512 threads).
  k_tridiag<<<NBATCH + 512, 512, lds1, stream>>>(A, wsG, X, nodemask, Wx, bx,
                                                 outXh, outNm);
  k_leaves<<<NBATCH * 8, 64, 0, stream>>>(wsG);
  k_mergeA<0><<<NBATCH * 4, 1024, 0, stream>>>(wsG, OFF_Q0);
  k_mergeB<<<NBATCH * 4, 512, ldsB, stream>>>(wsG, 0, OFF_Q0, OFF_Q1);
  k_mergeA<1><<<NBATCH * 2, 1024, 0, stream>>>(wsG, OFF_Q1);
  k_mergeB<<<NBATCH * 4, 512, ldsB, stream>>>(wsG, 1, OFF_Q1, OFF_Q0);
  k_mergeA<2><<<NBATCH * 1, 1024, 0, stream>>>(wsG, OFF_Q0);
  k_mergeB<<<NBATCH * 4, 512, ldsB, stream>>>(wsG, 2, OFF_Q0, OFF_Q1);
  k_back<<<NBATCH, 1024, lds2, stream>>>(wsG, nodemask, mu, isg, wsUt, wsLam, outEmb, outLmask);
  k_uc<<<NBATCH * 32, 256, 0, stream>>>(A, nodemask, We, be, wsUt, outUc);
}